// Round 6
// baseline (2782.061 us; speedup 1.0000x reference)
//
#include <hip/hip_runtime.h>

#define D_MODEL 1024
#define SEQ     1024
#define BATCH   4
#define NHEAD   16
#define HDIM    64
#define FF_DIM  4096
#define NLAYER  8
#define VOCAB   32000
#define ROWS    (BATCH*SEQ)
#define QKV_N   3072
#define LN_EPS  1e-5f

typedef __attribute__((ext_vector_type(4))) float   f32x4;
typedef __attribute__((ext_vector_type(8))) unsigned short u16x8;
typedef __attribute__((ext_vector_type(8))) __bf16  bf16x8;

typedef const unsigned int __attribute__((address_space(1)))* gas_t;
typedef unsigned int __attribute__((address_space(3)))* las_t;

__device__ __forceinline__ void gld16(const void* g, void* l) {
    __builtin_amdgcn_global_load_lds((gas_t)g, (las_t)l, 16, 0, 0);
}

__device__ __forceinline__ unsigned short f2bf(float f) {
    unsigned int u = __builtin_bit_cast(unsigned int, f);
    u += 0x7FFFu + ((u >> 16) & 1u);   // RNE
    return (unsigned short)(u >> 16);
}

__device__ __forceinline__ f32x4 mfma32(u16x8 a, u16x8 b, f32x4 c) {
    return __builtin_amdgcn_mfma_f32_16x16x32_bf16(
        __builtin_bit_cast(bf16x8, a), __builtin_bit_cast(bf16x8, b), c, 0, 0, 0);
}

// ---------------- embed: x = emb[tok] + pos ----------------
__global__ __launch_bounds__(256) void embed_k(
    const int* __restrict__ tok, const float* __restrict__ emb,
    const float* __restrict__ pos, float* __restrict__ x,
    unsigned short* __restrict__ xb)
{
    int bs = blockIdx.x;
    int s  = bs & (SEQ - 1);
    int tk = tok[bs];
    int c  = threadIdx.x * 4;
    float4 e = *(const float4*)(emb + (size_t)tk * D_MODEL + c);
    float4 p = *(const float4*)(pos + (size_t)s * D_MODEL + c);
    float y0 = e.x + p.x, y1 = e.y + p.y, y2 = e.z + p.z, y3 = e.w + p.w;
    size_t base = (size_t)bs * D_MODEL + c;
    *(float4*)(x + base) = make_float4(y0, y1, y2, y3);
    unsigned long long pk = (unsigned long long)f2bf(y0)
        | ((unsigned long long)f2bf(y1) << 16)
        | ((unsigned long long)f2bf(y2) << 32)
        | ((unsigned long long)f2bf(y3) << 48);
    *(unsigned long long*)(xb + base) = pk;
}

// ---------------- cast fp32 -> bf16 ----------------
__global__ __launch_bounds__(256) void cast_bf(
    const float* __restrict__ in, unsigned short* __restrict__ out, size_t n)
{
    size_t i = ((size_t)blockIdx.x * 256 + threadIdx.x) * 4;
    if (i >= n) return;
    float4 v = *(const float4*)(in + i);
    unsigned long long pk = (unsigned long long)f2bf(v.x)
        | ((unsigned long long)f2bf(v.y) << 16)
        | ((unsigned long long)f2bf(v.z) << 32)
        | ((unsigned long long)f2bf(v.w) << 48);
    *(unsigned long long*)(out + i) = pk;
}

// ---------------- concat qkv biases ----------------
__global__ __launch_bounds__(256) void bias3_k(
    const float* __restrict__ bq, const float* __restrict__ bk,
    const float* __restrict__ bv, float* __restrict__ out)
{
    int l = blockIdx.x / 3, which = blockIdx.x % 3;
    const float* src = which == 0 ? bq : (which == 1 ? bk : bv);
    int i = threadIdx.x * 4;
    float4 v = *(const float4*)(src + (size_t)l * D_MODEL + i);
    *(float4*)(out + (size_t)l * QKV_N + which * D_MODEL + i) = v;
}

// ---------------- W [K,N] fp32 -> Wt [N,K] bf16, 64x64 tiles ----------------
__global__ __launch_bounds__(256) void transpose_cast(
    const float* __restrict__ W, unsigned short* __restrict__ Wt, int K, int N)
{
    __shared__ float t[64][65];
    int n0 = blockIdx.x * 64, k0 = blockIdx.y * 64;
    int rr = threadIdx.x >> 4;          // 0..15
    int cc = (threadIdx.x & 15) * 4;    // 0..60
#pragma unroll
    for (int it = 0; it < 4; it++) {
        int r = it * 16 + rr;
        float4 v = *(const float4*)(W + (size_t)(k0 + r) * N + n0 + cc);
        t[r][cc] = v.x; t[r][cc + 1] = v.y; t[r][cc + 2] = v.z; t[r][cc + 3] = v.w;
    }
    __syncthreads();
#pragma unroll
    for (int it = 0; it < 4; it++) {
        int n = it * 16 + rr;
        unsigned long long pk = (unsigned long long)f2bf(t[cc][n])
            | ((unsigned long long)f2bf(t[cc + 1][n]) << 16)
            | ((unsigned long long)f2bf(t[cc + 2][n]) << 32)
            | ((unsigned long long)f2bf(t[cc + 3][n]) << 48);
        *(unsigned long long*)(Wt + (size_t)(n0 + n) * K + k0 + cc) = pk;
    }
}

// ---------------- fused QKV transpose: 3 x (1024x1024) in one launch ----------------
__global__ __launch_bounds__(256) void transpose_cast3(
    const float* __restrict__ Wq, const float* __restrict__ Wk,
    const float* __restrict__ Wv, unsigned short* __restrict__ Wt)
{
    __shared__ float t[64][65];
    const int which = blockIdx.z;
    const float* W = which == 0 ? Wq : (which == 1 ? Wk : Wv);
    unsigned short* out = Wt + (size_t)which * (1024 * 1024);
    int n0 = blockIdx.x * 64, k0 = blockIdx.y * 64;
    int rr = threadIdx.x >> 4;
    int cc = (threadIdx.x & 15) * 4;
#pragma unroll
    for (int it = 0; it < 4; it++) {
        int r = it * 16 + rr;
        float4 v = *(const float4*)(W + (size_t)(k0 + r) * 1024 + n0 + cc);
        t[r][cc] = v.x; t[r][cc + 1] = v.y; t[r][cc + 2] = v.z; t[r][cc + 3] = v.w;
    }
    __syncthreads();
#pragma unroll
    for (int it = 0; it < 4; it++) {
        int n = it * 16 + rr;
        unsigned long long pk = (unsigned long long)f2bf(t[cc][n])
            | ((unsigned long long)f2bf(t[cc + 1][n]) << 16)
            | ((unsigned long long)f2bf(t[cc + 2][n]) << 32)
            | ((unsigned long long)f2bf(t[cc + 3][n]) << 48);
        *(unsigned long long*)(out + (size_t)(n0 + n) * 1024 + k0 + cc) = pk;
    }
}

// ---------------- small NT GEMM (m97 128x128) with split-K support ----------------
template<int MODE>
__global__ __launch_bounds__(256, 3) void gemm_bt(
    const unsigned short* __restrict__ A, int lda,
    const unsigned short* __restrict__ Bt, int ldb,
    const float* __restrict__ bias, void* __restrict__ Cout, int N, int Klen)
{
    __shared__ unsigned short As[128 * 32];
    __shared__ unsigned short Bs[128 * 32];
    const int part = blockIdx.y;
    A  += (size_t)part * Klen;
    Bt += (size_t)part * Klen;
    int flat = blockIdx.x;
    const int bm = flat & 31, bn = flat >> 5;
    const int tid  = threadIdx.x;
    const int wid  = tid >> 6, lane = tid & 63;
    const int l16  = lane & 15, lhi = lane >> 4;
    const int wr   = wid >> 1, wc = wid & 1;

    const int srow = wid * 32 + (lane >> 2);
    const int scol = (lane & 3) * 8;
    const unsigned short* gA0 = A  + ((size_t)bm * 128 + srow) * lda + scol;
    const unsigned short* gB0 = Bt + ((size_t)bn * 128 + srow) * ldb + scol;
    unsigned short* lA = As + wid * 32 * 32;
    unsigned short* lB = Bs + wid * 32 * 32;

    f32x4 acc[4][4];
#pragma unroll
    for (int i = 0; i < 4; i++)
#pragma unroll
        for (int j = 0; j < 4; j++) acc[i][j] = (f32x4){0.f, 0.f, 0.f, 0.f};

    for (int k0 = 0; k0 < Klen; k0 += 32) {
        __syncthreads();
        gld16(gA0 + k0,                    lA);
        gld16(gA0 + k0 + 16 * (size_t)lda, lA + 16 * 32);
        gld16(gB0 + k0,                    lB);
        gld16(gB0 + k0 + 16 * (size_t)ldb, lB + 16 * 32);
        __syncthreads();
        u16x8 af[4], bfr[4];
#pragma unroll
        for (int i = 0; i < 4; i++)
            af[i] = *(const u16x8*)(As + (wr * 64 + i * 16 + l16) * 32 + lhi * 8);
#pragma unroll
        for (int i = 0; i < 4; i++)
            bfr[i] = *(const u16x8*)(Bs + (wc * 64 + i * 16 + l16) * 32 + lhi * 8);
#pragma unroll
        for (int mi = 0; mi < 4; mi++)
#pragma unroll
            for (int ni = 0; ni < 4; ni++)
                acc[mi][ni] = mfma32(af[mi], bfr[ni], acc[mi][ni]);
    }

    const size_t pofs = (size_t)part * (size_t)ROWS * N;
#pragma unroll
    for (int mi = 0; mi < 4; mi++)
#pragma unroll
        for (int ni = 0; ni < 4; ni++) {
            int row = bm * 128 + wr * 64 + mi * 16 + lhi * 4;
            int col = bn * 128 + wc * 64 + ni * 16 + l16;
            float bv = (bias && part == 0) ? bias[col] : 0.f;
#pragma unroll
            for (int j = 0; j < 4; j++) {
                float v = acc[mi][ni][j] + bv;
                size_t idx = pofs + (size_t)(row + j) * N + col;
                if constexpr (MODE == 0) {
                    ((float*)Cout)[idx] = v;
                } else if constexpr (MODE == 1) {
                    ((unsigned short*)Cout)[idx] = f2bf(v);
                } else {
                    ((unsigned short*)Cout)[idx] = f2bf(v > 0.f ? v : 0.f);
                }
            }
        }
}

// ================= 256x256 GEMM, 2 phases per K-tile =================
// BK=64, 8 waves (2Mx4N), 2 LDS dbuf (128 KiB), st_16-style XOR swizzle.
// PH_A(tile t): 16 ds_read (A-half0 + B all) | stage A(t+1) | bar,lgkm0 | 32 MFMA | bar
// PH_B(tile t):  8 ds_read (A-half1)         | stage B(t+2), vmcnt(4) | bar,lgkm0 | 32 MFMA | bar
// Invariant: entering tile t exactly B(t+1)'s 4 loads outstanding; vmcnt(4)
// at PH_B completes A(t+1),B(t+1). WAR: stage A(t+1) after t-1's last aR1
// read (t-1 PH_B barrier); stage B(t+2) after t's last bR0 read (PH_A barrier).
#define PSYNC() do { __builtin_amdgcn_s_barrier(); \
    asm volatile("s_waitcnt lgkmcnt(0)" ::: "memory"); \
    __builtin_amdgcn_sched_barrier(0); } while (0)
#define PEND() __builtin_amdgcn_s_barrier()
#define VM4()  asm volatile("s_waitcnt vmcnt(4)" ::: "memory")

#define LOADA(reg, half) do { \
    _Pragma("unroll") \
    for (int m_ = 0; m_ < 4; m_++) { \
        aF[m_][0] = *(const u16x8*)((reg) + ((half)*4 + m_) * 2048 + lane0); \
        aF[m_][1] = *(const u16x8*)((reg) + ((half)*4 + m_) * 2048 + lane1); \
    } } while (0)

#define LOADB(reg, np) do { \
    _Pragma("unroll") \
    for (int n_ = 0; n_ < 2; n_++) { \
        bF[(np)*2 + n_][0] = *(const u16x8*)((reg) + ((np)*2 + n_) * 2048 + lane0); \
        bF[(np)*2 + n_][1] = *(const u16x8*)((reg) + ((np)*2 + n_) * 2048 + lane1); \
    } } while (0)

#define MFMA8(ma, np) do { \
    __builtin_amdgcn_s_setprio(1); \
    _Pragma("unroll") \
    for (int m_ = 0; m_ < 4; m_++) \
        _Pragma("unroll") \
        for (int n_ = 0; n_ < 2; n_++) { \
            acc[(ma)+m_][(np)*2+n_] = mfma32(aF[m_][0], bF[(np)*2+n_][0], acc[(ma)+m_][(np)*2+n_]); \
            acc[(ma)+m_][(np)*2+n_] = mfma32(aF[m_][1], bF[(np)*2+n_][1], acc[(ma)+m_][(np)*2+n_]); \
        } \
    __builtin_amdgcn_s_setprio(0); \
} while (0)

// stage one 128x64 half-tile (2 x gld16). par/isB/h literals at call sites.
#define STG(base, T, h, par, isB) do { \
    const unsigned short* s_ = (base) + (size_t)((h) * 128) * K + (size_t)(T) * 64; \
    unsigned short* d_ = dst0 + (par) * 32768 + (isB) * 16384 + (h) * 8192; \
    gld16(s_, d_); gld16(s_ + (size_t)64 * K, d_ + 4096); } while (0)

template<int MODE>
__global__ __launch_bounds__(512, 2) void gemm256(
    const unsigned short* __restrict__ A, const unsigned short* __restrict__ Bt,
    const float* __restrict__ bias, void* __restrict__ Cout, int N, int K)
{
    __shared__ unsigned short lds[65536] __attribute__((aligned(128)));
    const int tid = threadIdx.x, wid = tid >> 6, lane = tid & 63;
    const int l16 = lane & 15, lhi = lane >> 4;
    const int wr = wid >> 2, wc = wid & 3;

    int flat = blockIdx.x;
    { int cpx = gridDim.x >> 3; flat = (flat & 7) * cpx + (flat >> 3); }
    const int bm = flat & 15, bn = flat >> 4;
    const int NT = K >> 6;

    const int srowL = tid >> 3;                                      // 0..63
    const int scolb = ((tid & 7) << 4) ^ (((tid >> 3) & 7) << 4);    // bytes (pre-swz src)
    const unsigned short* baseA = A  + (size_t)(bm * 256 + srowL) * K + (scolb >> 1);
    const unsigned short* baseB = Bt + (size_t)(bn * 256 + srowL) * K + (scolb >> 1);
    unsigned short* dst0 = lds + wid * 512;   // wave-uniform; HW adds lane*16B

    const int lswz  = (l16 & 7) << 4;
    const int lane0 = ((lhi * 16) ^ lswz) + l16 * 128;
    const int lane1 = ((64 + lhi * 16) ^ lswz) + l16 * 128;

    const char* aR0 = (const char*)lds + wr * 16384;
    const char* bR0 = (const char*)lds + 32768 + (wc >> 1) * 16384 + (wc & 1) * 8192;
    const char* aR1 = aR0 + 65536;
    const char* bR1 = bR0 + 65536;

    f32x4 acc[8][4];
#pragma unroll
    for (int i = 0; i < 8; i++)
#pragma unroll
        for (int j = 0; j < 4; j++) acc[i][j] = (f32x4){0.f, 0.f, 0.f, 0.f};
    u16x8 aF[4][2], bF[4][2];

    // prologue: B(0),A(0),B(1); leave B(1)'s 4 loads in flight
    STG(baseB, 0, 0, 0, 1); STG(baseB, 0, 1, 0, 1);
    STG(baseA, 0, 0, 0, 0); STG(baseA, 0, 1, 0, 0);
    STG(baseB, 1, 0, 1, 1); STG(baseB, 1, 1, 1, 1);
    VM4();
    __builtin_amdgcn_s_barrier();

    int t = 0;
    for (; t + 3 < NT; t += 2) {
        // ---- K-tile t (buf0) ----
        LOADA(aR0, 0); LOADB(bR0, 0); LOADB(bR0, 1);
        STG(baseA, t + 1, 0, 1, 0); STG(baseA, t + 1, 1, 1, 0);
        PSYNC(); MFMA8(0, 0); MFMA8(0, 1); PEND();
        LOADA(aR0, 1);
        STG(baseB, t + 2, 0, 0, 1); STG(baseB, t + 2, 1, 0, 1); VM4();
        PSYNC(); MFMA8(4, 0); MFMA8(4, 1); PEND();
        // ---- K-tile t+1 (buf1) ----
        LOADA(aR1, 0); LOADB(bR1, 0); LOADB(bR1, 1);
        STG(baseA, t + 2, 0, 0, 0); STG(baseA, t + 2, 1, 0, 0);
        PSYNC(); MFMA8(0, 0); MFMA8(0, 1); PEND();
        LOADA(aR1, 1);
        STG(baseB, t + 3, 0, 1, 1); STG(baseB, t + 3, 1, 1, 1); VM4();
        PSYNC(); MFMA8(4, 0); MFMA8(4, 1); PEND();
    }
    // ---- epilogue: tiles NT-2 (buf0), NT-1 (buf1) ----
    LOADA(aR0, 0); LOADB(bR0, 0); LOADB(bR0, 1);
    STG(baseA, t + 1, 0, 1, 0); STG(baseA, t + 1, 1, 1, 0);
    PSYNC(); MFMA8(0, 0); MFMA8(0, 1); PEND();
    LOADA(aR0, 1);
    asm volatile("s_waitcnt vmcnt(0)" ::: "memory");
    PSYNC(); MFMA8(4, 0); MFMA8(4, 1); PEND();
    LOADA(aR1, 0); LOADB(bR1, 0); LOADB(bR1, 1);
    PSYNC(); MFMA8(0, 0); MFMA8(0, 1); PEND();
    LOADA(aR1, 1);
    PSYNC(); MFMA8(4, 0); MFMA8(4, 1);

#pragma unroll
    for (int mi = 0; mi < 8; mi++)
#pragma unroll
        for (int ni = 0; ni < 4; ni++) {
            int row = bm * 256 + wr * 128 + mi * 16 + lhi * 4;
            int col = bn * 256 + wc * 64 + ni * 16 + l16;
            float bv = bias ? bias[col] : 0.f;
#pragma unroll
            for (int j = 0; j < 4; j++) {
                float v = acc[mi][ni][j] + bv;
                size_t idx = (size_t)(row + j) * N + col;
                if constexpr (MODE == 0) {
                    ((float*)Cout)[idx] = v;
                } else if constexpr (MODE == 1) {
                    ((unsigned short*)Cout)[idx] = f2bf(v);
                } else {
                    ((unsigned short*)Cout)[idx] = f2bf(v > 0.f ? v : 0.f);
                }
            }
        }
}

// ---------------- flash attention (causal), 64 q-rows/block, fused qkv input ----------------
__global__ __launch_bounds__(256, 3) void attn_fwd(
    const unsigned short* __restrict__ qkv, unsigned short* __restrict__ ctxb)
{
    __shared__ unsigned short Ks[64 * 72];
    __shared__ unsigned short Vs[64 * 72];   // transposed: Vs[d][kv]
    __shared__ unsigned short Ps[4 * 16 * 72];
    const int tid = threadIdx.x;
    const int wid = tid >> 6, lane = tid & 63;
    const int l16 = lane & 15, lhi = lane >> 4;
    const int bh  = blockIdx.y, b = bh >> 4, h = bh & 15;
    const int q0  = blockIdx.x * 64;
    const size_t rowbase = (size_t)b * SEQ;

    const int qrow = q0 + wid * 16 + l16;
    const unsigned short* qp = qkv + (rowbase + qrow) * QKV_N + h * HDIM + lhi * 8;
    u16x8 qf0 = *(const u16x8*)qp;
    u16x8 qf1 = *(const u16x8*)(qp + 32);

    f32x4 oa[4];
    float mj[4], lj[4];
#pragma unroll
    for (int i = 0; i < 4; i++) {
        oa[i] = (f32x4){0.f, 0.f, 0.f, 0.f};
        mj[i] = -1e30f; lj[i] = 0.f;
    }

    const int ntiles = blockIdx.x + 1;
    for (int kt = 0; kt < ntiles; ++kt) {
        const int kv0 = kt * 64;
        __syncthreads();
#pragma unroll
        for (int it = 0; it < 2; ++it) {
            int e = it * 256 + tid;
            int r = e >> 3, d0 = (e & 7) * 8;
            size_t goff = (rowbase + kv0 + r) * QKV_N + D_MODEL + h * HDIM + d0;
            u16x8 kk = *(const u16x8*)(qkv + goff);
            *(u16x8*)(&Ks[r * 72 + d0]) = kk;
            u16x8 vv = *(const u16x8*)(qkv + goff + D_MODEL);
#pragma unroll
            for (int j = 0; j < 8; j++) Vs[(d0 + j) * 72 + r] = vv[j];
        }
        __syncthreads();

        f32x4 sa[4];
#pragma unroll
        for (int ni = 0; ni < 4; ni++) {
            f32x4 z = (f32x4){0.f, 0.f, 0.f, 0.f};
            u16x8 k0f = *(const u16x8*)(&Ks[(ni * 16 + l16) * 72 + lhi * 8]);
            u16x8 k1f = *(const u16x8*)(&Ks[(ni * 16 + l16) * 72 + 32 + lhi * 8]);
            z = mfma32(qf0, k0f, z);
            z = mfma32(qf1, k1f, z);
            sa[ni] = z;
        }
        float tm[4] = {-1e30f, -1e30f, -1e30f, -1e30f};
#pragma unroll
        for (int ni = 0; ni < 4; ni++)
#pragma unroll
            for (int j = 0; j < 4; j++) {
                float v = sa[ni][j] * 0.125f;
                int row = q0 + wid * 16 + lhi * 4 + j;
                int col = kv0 + ni * 16 + l16;
                if (col > row) v = -1e30f;
                sa[ni][j] = v;
                tm[j] = fmaxf(tm[j], v);
            }
#pragma unroll
        for (int j = 0; j < 4; j++) {
#pragma unroll
            for (int off = 1; off < 16; off <<= 1)
                tm[j] = fmaxf(tm[j], __shfl_xor(tm[j], off));
        }
        float al[4], rs[4] = {0.f, 0.f, 0.f, 0.f};
#pragma unroll
        for (int j = 0; j < 4; j++) {
            float mn = fmaxf(mj[j], tm[j]);
            al[j] = __expf(mj[j] - mn);
            mj[j] = mn;
        }
#pragma unroll
        for (int ni = 0; ni < 4; ni++)
#pragma unroll
            for (int j = 0; j < 4; j++) {
                float p = __expf(sa[ni][j] - mj[j]);
                rs[j] += p;
                Ps[wid * 1152 + (lhi * 4 + j) * 72 + ni * 16 + l16] = f2bf(p);
            }
#pragma unroll
        for (int j = 0; j < 4; j++) {
#pragma unroll
            for (int off = 1; off < 16; off <<= 1)
                rs[j] += __shfl_xor(rs[j], off);
            lj[j] = lj[j] * al[j] + rs[j];
        }
#pragma unroll
        for (int di = 0; di < 4; di++)
#pragma unroll
            for (int j = 0; j < 4; j++) oa[di][j] *= al[j];
#pragma unroll
        for (int di = 0; di < 4; di++) {
#pragma unroll
            for (int kc = 0; kc < 2; kc++) {
                u16x8 pf = *(const u16x8*)(&Ps[wid * 1152 + l16 * 72 + kc * 32 + lhi * 8]);
                u16x8 vf = *(const u16x8*)(&Vs[(di * 16 + l16) * 72 + kc * 32 + lhi * 8]);
                oa[di] = mfma32(pf, vf, oa[di]);
            }
        }
    }
#pragma unroll
    for (int di = 0; di < 4; di++)
#pragma unroll
        for (int j = 0; j < 4; j++) {
            int row = q0 + wid * 16 + lhi * 4 + j;
            ctxb[(rowbase + row) * D_MODEL + h * HDIM + di * 16 + l16] =
                f2bf(oa[di][j] / lj[j]);
        }
}

// ---------------- fused residual(x + p0 + p1) + LayerNorm ----------------
__global__ __launch_bounds__(256) void ln3(
    float* __restrict__ x, const float* __restrict__ p0, const float* __restrict__ p1,
    const float* __restrict__ sc, const float* __restrict__ bi,
    unsigned short* __restrict__ xb)
{
    const int row = blockIdx.x;
    const int t = threadIdx.x;
    const size_t base = (size_t)row * D_MODEL + t * 4;
    float4 xv = *(const float4*)(x + base);
    float4 av = *(const float4*)(p0 + base);
    float4 bvv = *(const float4*)(p1 + base);
    float v0 = xv.x + av.x + bvv.x, v1 = xv.y + av.y + bvv.y;
    float v2 = xv.z + av.z + bvv.z, v3 = xv.w + av.w + bvv.w;
    float sum = v0 + v1 + v2 + v3;
    float sq  = v0 * v0 + v1 * v1 + v2 * v2 + v3 * v3;
#pragma unroll
    for (int off = 1; off < 64; off <<= 1) {
        sum += __shfl_xor(sum, off);
        sq  += __shfl_xor(sq, off);
    }
    __shared__ float red[8];
    int wid = t >> 6, lane = t & 63;
    if (lane == 0) { red[wid] = sum; red[4 + wid] = sq; }
    __syncthreads();
    sum = red[0] + red[1] + red[2] + red[3];
    sq  = red[4] + red[5] + red[6] + red[7];
    float mu   = sum * (1.f / D_MODEL);
    float var  = sq * (1.f / D_MODEL) - mu * mu;
    float rstd = rsqrtf(var + LN_EPS);
    int c = t * 4;
    float4 sv = *(const float4*)(sc + c);
    float4 bv = *(const float4*)(bi + c);
    float y0 = sv.x * (v0 - mu) * rstd + bv.x;
    float y1 = sv.y * (v1 - mu) * rstd + bv.y;
    float y2 = sv.z * (v2 - mu) * rstd + bv.z;
    float y3 = sv.w * (v3 - mu) * rstd + bv.w;
    *(float4*)(x + base) = make_float4(y0, y1, y2, y3);
    unsigned long long pk = (unsigned long long)f2bf(y0)
        | ((unsigned long long)f2bf(y1) << 16)
        | ((unsigned long long)f2bf(y2) << 32)
        | ((unsigned long long)f2bf(y3) << 48);
    *(unsigned long long*)(xb + base) = pk;
}

// ---------------- launcher ----------------
extern "C" void kernel_launch(void* const* d_in, const int* in_sizes, int n_in,
                              void* d_out, int out_size, void* d_ws, size_t ws_size,
                              hipStream_t stream)
{
    (void)in_sizes; (void)n_in; (void)out_size;
    const int*   tokens = (const int*)d_in[0];
    const float* emb  = (const float*)d_in[2];
    const float* pose = (const float*)d_in[3];
    const float* Wq = (const float*)d_in[4];
    const float* bq = (const float*)d_in[5];
    const float* Wk = (const float*)d_in[6];
    const float* bk = (const float*)d_in[7];
    const float* Wv = (const float*)d_in[8];
    const float* bv = (const float*)d_in[9];
    const float* Wo = (const float*)d_in[10];
    const float* bo = (const float*)d_in[11];
    const float* n1s = (const float*)d_in[12];
    const float* n1b = (const float*)d_in[13];
    const float* W1 = (const float*)d_in[14];
    const float* b1 = (const float*)d_in[15];
    const float* W2 = (const float*)d_in[16];
    const float* b2 = (const float*)d_in[17];
    const float* n2s = (const float*)d_in[18];
    const float* n2b = (const float*)d_in[19];

    char* w = (char*)d_ws;
    size_t off = 0;
    auto carve = [&](size_t bytes) -> void* {
        void* p = w + off;
        off = (off + bytes + 255) & ~(size_t)255;
        return p;
    };
    float* x   = (float*)carve((size_t)ROWS * D_MODEL * 4);
    float* tmp = (float*)carve((size_t)2 * ROWS * D_MODEL * 4);   // 2 split-K partials
    unsigned short* xb    = (unsigned short*)carve((size_t)ROWS * D_MODEL * 2);
    unsigned short* qkvb  = (unsigned short*)carve((size_t)ROWS * QKV_N * 2);
    unsigned short* cbuf  = (unsigned short*)carve((size_t)ROWS * D_MODEL * 2);
    unsigned short* hbuf  = (unsigned short*)carve((size_t)ROWS * FF_DIM * 2);
    unsigned short* wt    = (unsigned short*)carve((size_t)D_MODEL * FF_DIM * 2);
    float* bqkv = (float*)carve((size_t)NLAYER * QKV_N * 4);
    unsigned short* embb = qkvb;   // tied-head emb aliases dead qkv/ctx/h region
    float* tmp1 = tmp + (size_t)ROWS * D_MODEL;
    if (off > ws_size) return;

    bias3_k<<<NLAYER * 3, 256, 0, stream>>>(bq, bk, bv, bqkv);
    embed_k<<<ROWS, 256, 0, stream>>>(tokens, emb, pose, x, xb);

    for (int l = 0; l < NLAYER; l++) {
        const float* Wq_l = Wq + (size_t)l * D_MODEL * D_MODEL;
        const float* Wk_l = Wk + (size_t)l * D_MODEL * D_MODEL;
        const float* Wv_l = Wv + (size_t)l * D_MODEL * D_MODEL;
        const float* Wo_l = Wo + (size_t)l * D_MODEL * D_MODEL;
        const float* W1_l = W1 + (size_t)l * D_MODEL * FF_DIM;
        const float* W2_l = W2 + (size_t)l * FF_DIM * D_MODEL;

        transpose_cast3<<<dim3(16, 16, 3), 256, 0, stream>>>(Wq_l, Wk_l, Wv_l, wt);
        gemm256<1><<<(QKV_N / 256) * 16, 512, 0, stream>>>(xb, wt, bqkv + (size_t)l * QKV_N, qkvb, QKV_N, D_MODEL);

        attn_fwd<<<dim3(SEQ / 64, BATCH * NHEAD), 256, 0, stream>>>(qkvb, cbuf);

        transpose_cast<<<dim3(16, 16), 256, 0, stream>>>(Wo_l, wt, D_MODEL, D_MODEL);
        gemm_bt<0><<<dim3(256, 2), 256, 0, stream>>>(cbuf, D_MODEL, wt, D_MODEL,
                                                     bo + (size_t)l * D_MODEL, tmp, D_MODEL, D_MODEL / 2);
        ln3<<<ROWS, 256, 0, stream>>>(x, tmp, tmp1, n1s + (size_t)l * D_MODEL, n1b + (size_t)l * D_MODEL, xb);

        transpose_cast<<<dim3(64, 16), 256, 0, stream>>>(W1_l, wt, D_MODEL, FF_DIM);
        gemm256<2><<<(FF_DIM / 256) * 16, 512, 0, stream>>>(xb, wt, b1 + (size_t)l * FF_DIM, hbuf, FF_DIM, D_MODEL);
        transpose_cast<<<dim3(16, 64), 256, 0, stream>>>(W2_l, wt, FF_DIM, D_MODEL);
        gemm_bt<0><<<dim3(256, 2), 256, 0, stream>>>(hbuf, FF_DIM, wt, FF_DIM,
                                                     b2 + (size_t)l * D_MODEL, tmp, D_MODEL, FF_DIM / 2);
        ln3<<<ROWS, 256, 0, stream>>>(x, tmp, tmp1, n2s + (size_t)l * D_MODEL, n2b + (size_t)l * D_MODEL, xb);
    }

    cast_bf<<<(VOCAB * D_MODEL) / 1024, 256, 0, stream>>>(emb, embb, (size_t)VOCAB * D_MODEL);
    gemm256<0><<<(VOCAB / 256) * 16, 512, 0, stream>>>(xb, embb, nullptr, d_out, VOCAB, D_MODEL);
}

// Round 7
// 2526.279 us; speedup vs baseline: 1.1012x; 1.1012x over previous
//
#include <hip/hip_runtime.h>

#define D_MODEL 1024
#define SEQ     1024
#define BATCH   4
#define NHEAD   16
#define HDIM    64
#define FF_DIM  4096
#define NLAYER  8
#define VOCAB   32000
#define ROWS    (BATCH*SEQ)
#define QKV_N   3072
#define LN_EPS  1e-5f

typedef __attribute__((ext_vector_type(4))) float   f32x4;
typedef __attribute__((ext_vector_type(8))) unsigned short u16x8;
typedef __attribute__((ext_vector_type(8))) __bf16  bf16x8;

typedef const unsigned int __attribute__((address_space(1)))* gas_t;
typedef unsigned int __attribute__((address_space(3)))* las_t;

__device__ __forceinline__ void gld16(const void* g, void* l) {
    __builtin_amdgcn_global_load_lds((gas_t)g, (las_t)l, 16, 0, 0);
}

__device__ __forceinline__ unsigned short f2bf(float f) {
    unsigned int u = __builtin_bit_cast(unsigned int, f);
    u += 0x7FFFu + ((u >> 16) & 1u);   // RNE
    return (unsigned short)(u >> 16);
}

__device__ __forceinline__ f32x4 mfma32(u16x8 a, u16x8 b, f32x4 c) {
    return __builtin_amdgcn_mfma_f32_16x16x32_bf16(
        __builtin_bit_cast(bf16x8, a), __builtin_bit_cast(bf16x8, b), c, 0, 0, 0);
}

// ---------------- embed: x = emb[tok] + pos ----------------
__global__ __launch_bounds__(256) void embed_k(
    const int* __restrict__ tok, const float* __restrict__ emb,
    const float* __restrict__ pos, float* __restrict__ x,
    unsigned short* __restrict__ xb)
{
    int bs = blockIdx.x;
    int s  = bs & (SEQ - 1);
    int tk = tok[bs];
    int c  = threadIdx.x * 4;
    float4 e = *(const float4*)(emb + (size_t)tk * D_MODEL + c);
    float4 p = *(const float4*)(pos + (size_t)s * D_MODEL + c);
    float y0 = e.x + p.x, y1 = e.y + p.y, y2 = e.z + p.z, y3 = e.w + p.w;
    size_t base = (size_t)bs * D_MODEL + c;
    *(float4*)(x + base) = make_float4(y0, y1, y2, y3);
    unsigned long long pk = (unsigned long long)f2bf(y0)
        | ((unsigned long long)f2bf(y1) << 16)
        | ((unsigned long long)f2bf(y2) << 32)
        | ((unsigned long long)f2bf(y3) << 48);
    *(unsigned long long*)(xb + base) = pk;
}

// ---------------- cast fp32 -> bf16 ----------------
__global__ __launch_bounds__(256) void cast_bf(
    const float* __restrict__ in, unsigned short* __restrict__ out, size_t n)
{
    size_t i = ((size_t)blockIdx.x * 256 + threadIdx.x) * 4;
    if (i >= n) return;
    float4 v = *(const float4*)(in + i);
    unsigned long long pk = (unsigned long long)f2bf(v.x)
        | ((unsigned long long)f2bf(v.y) << 16)
        | ((unsigned long long)f2bf(v.z) << 32)
        | ((unsigned long long)f2bf(v.w) << 48);
    *(unsigned long long*)(out + i) = pk;
}

// ---------------- concat qkv biases ----------------
__global__ __launch_bounds__(256) void bias3_k(
    const float* __restrict__ bq, const float* __restrict__ bk,
    const float* __restrict__ bv, float* __restrict__ out)
{
    int l = blockIdx.x / 3, which = blockIdx.x % 3;
    const float* src = which == 0 ? bq : (which == 1 ? bk : bv);
    int i = threadIdx.x * 4;
    float4 v = *(const float4*)(src + (size_t)l * D_MODEL + i);
    *(float4*)(out + (size_t)l * QKV_N + which * D_MODEL + i) = v;
}

// ---------------- W [K,N] fp32 -> Wt [N,K] bf16, 64x64 tiles ----------------
__global__ __launch_bounds__(256) void transpose_cast(
    const float* __restrict__ W, unsigned short* __restrict__ Wt, int K, int N)
{
    __shared__ float t[64][65];
    int n0 = blockIdx.x * 64, k0 = blockIdx.y * 64;
    int rr = threadIdx.x >> 4;          // 0..15
    int cc = (threadIdx.x & 15) * 4;    // 0..60
#pragma unroll
    for (int it = 0; it < 4; it++) {
        int r = it * 16 + rr;
        float4 v = *(const float4*)(W + (size_t)(k0 + r) * N + n0 + cc);
        t[r][cc] = v.x; t[r][cc + 1] = v.y; t[r][cc + 2] = v.z; t[r][cc + 3] = v.w;
    }
    __syncthreads();
#pragma unroll
    for (int it = 0; it < 4; it++) {
        int n = it * 16 + rr;
        unsigned long long pk = (unsigned long long)f2bf(t[cc][n])
            | ((unsigned long long)f2bf(t[cc + 1][n]) << 16)
            | ((unsigned long long)f2bf(t[cc + 2][n]) << 32)
            | ((unsigned long long)f2bf(t[cc + 3][n]) << 48);
        *(unsigned long long*)(Wt + (size_t)(n0 + n) * K + k0 + cc) = pk;
    }
}

// ---------------- fused QKV transpose: 3 x (1024x1024) in one launch ----------------
__global__ __launch_bounds__(256) void transpose_cast3(
    const float* __restrict__ Wq, const float* __restrict__ Wk,
    const float* __restrict__ Wv, unsigned short* __restrict__ Wt)
{
    __shared__ float t[64][65];
    const int which = blockIdx.z;
    const float* W = which == 0 ? Wq : (which == 1 ? Wk : Wv);
    unsigned short* out = Wt + (size_t)which * (1024 * 1024);
    int n0 = blockIdx.x * 64, k0 = blockIdx.y * 64;
    int rr = threadIdx.x >> 4;
    int cc = (threadIdx.x & 15) * 4;
#pragma unroll
    for (int it = 0; it < 4; it++) {
        int r = it * 16 + rr;
        float4 v = *(const float4*)(W + (size_t)(k0 + r) * 1024 + n0 + cc);
        t[r][cc] = v.x; t[r][cc + 1] = v.y; t[r][cc + 2] = v.z; t[r][cc + 3] = v.w;
    }
    __syncthreads();
#pragma unroll
    for (int it = 0; it < 4; it++) {
        int n = it * 16 + rr;
        unsigned long long pk = (unsigned long long)f2bf(t[cc][n])
            | ((unsigned long long)f2bf(t[cc + 1][n]) << 16)
            | ((unsigned long long)f2bf(t[cc + 2][n]) << 32)
            | ((unsigned long long)f2bf(t[cc + 3][n]) << 48);
        *(unsigned long long*)(out + (size_t)(n0 + n) * 1024 + k0 + cc) = pk;
    }
}

// ---------------- small NT GEMM (m97 128x128) with split-K support ----------------
template<int MODE>
__global__ __launch_bounds__(256, 3) void gemm_bt(
    const unsigned short* __restrict__ A, int lda,
    const unsigned short* __restrict__ Bt, int ldb,
    const float* __restrict__ bias, void* __restrict__ Cout, int N, int Klen)
{
    __shared__ unsigned short As[128 * 32];
    __shared__ unsigned short Bs[128 * 32];
    const int part = blockIdx.y;
    A  += (size_t)part * Klen;
    Bt += (size_t)part * Klen;
    int flat = blockIdx.x;
    const int bm = flat & 31, bn = flat >> 5;
    const int tid  = threadIdx.x;
    const int wid  = tid >> 6, lane = tid & 63;
    const int l16  = lane & 15, lhi = lane >> 4;
    const int wr   = wid >> 1, wc = wid & 1;

    const int srow = wid * 32 + (lane >> 2);
    const int scol = (lane & 3) * 8;
    const unsigned short* gA0 = A  + ((size_t)bm * 128 + srow) * lda + scol;
    const unsigned short* gB0 = Bt + ((size_t)bn * 128 + srow) * ldb + scol;
    unsigned short* lA = As + wid * 32 * 32;
    unsigned short* lB = Bs + wid * 32 * 32;

    f32x4 acc[4][4];
#pragma unroll
    for (int i = 0; i < 4; i++)
#pragma unroll
        for (int j = 0; j < 4; j++) acc[i][j] = (f32x4){0.f, 0.f, 0.f, 0.f};

    for (int k0 = 0; k0 < Klen; k0 += 32) {
        __syncthreads();
        gld16(gA0 + k0,                    lA);
        gld16(gA0 + k0 + 16 * (size_t)lda, lA + 16 * 32);
        gld16(gB0 + k0,                    lB);
        gld16(gB0 + k0 + 16 * (size_t)ldb, lB + 16 * 32);
        __syncthreads();
        u16x8 af[4], bfr[4];
#pragma unroll
        for (int i = 0; i < 4; i++)
            af[i] = *(const u16x8*)(As + (wr * 64 + i * 16 + l16) * 32 + lhi * 8);
#pragma unroll
        for (int i = 0; i < 4; i++)
            bfr[i] = *(const u16x8*)(Bs + (wc * 64 + i * 16 + l16) * 32 + lhi * 8);
#pragma unroll
        for (int mi = 0; mi < 4; mi++)
#pragma unroll
            for (int ni = 0; ni < 4; ni++)
                acc[mi][ni] = mfma32(af[mi], bfr[ni], acc[mi][ni]);
    }

    const size_t pofs = (size_t)part * (size_t)ROWS * N;
#pragma unroll
    for (int mi = 0; mi < 4; mi++)
#pragma unroll
        for (int ni = 0; ni < 4; ni++) {
            int row = bm * 128 + wr * 64 + mi * 16 + lhi * 4;
            int col = bn * 128 + wc * 64 + ni * 16 + l16;
            float bv = (bias && part == 0) ? bias[col] : 0.f;
#pragma unroll
            for (int j = 0; j < 4; j++) {
                float v = acc[mi][ni][j] + bv;
                size_t idx = pofs + (size_t)(row + j) * N + col;
                if constexpr (MODE == 0) {
                    ((float*)Cout)[idx] = v;
                } else if constexpr (MODE == 1) {
                    ((unsigned short*)Cout)[idx] = f2bf(v);
                } else {
                    ((unsigned short*)Cout)[idx] = f2bf(v > 0.f ? v : 0.f);
                }
            }
        }
}

// ================= 256x256 8-phase GEMM (R4-best structure + NT store) =================
// BK=64, 8 waves (2Mx4N), 2 LDS dbuf (128 KiB), XOR swizzle (bank-conflict-free).
// MODE 0 (head) uses nontemporal C stores: C (524 MB fp32) is never re-read;
// bypassing L2/L3 keeps A/B panels cache-resident (FETCH was 5.7x compulsory).
#define PSYNC() do { __builtin_amdgcn_s_barrier(); \
    asm volatile("s_waitcnt lgkmcnt(0)" ::: "memory"); \
    __builtin_amdgcn_sched_barrier(0); } while (0)
#define PEND() __builtin_amdgcn_s_barrier()
#define VM4()  asm volatile("s_waitcnt vmcnt(4)" ::: "memory")

#define LOADA(reg, half) do { \
    _Pragma("unroll") \
    for (int m_ = 0; m_ < 4; m_++) { \
        aF[m_][0] = *(const u16x8*)((reg) + ((half)*4 + m_) * 2048 + lane0); \
        aF[m_][1] = *(const u16x8*)((reg) + ((half)*4 + m_) * 2048 + lane1); \
    } } while (0)

#define LOADB(reg, np) do { \
    _Pragma("unroll") \
    for (int n_ = 0; n_ < 2; n_++) { \
        bF[(np)*2 + n_][0] = *(const u16x8*)((reg) + ((np)*2 + n_) * 2048 + lane0); \
        bF[(np)*2 + n_][1] = *(const u16x8*)((reg) + ((np)*2 + n_) * 2048 + lane1); \
    } } while (0)

#define MFMA8(ma, np) do { \
    __builtin_amdgcn_s_setprio(1); \
    _Pragma("unroll") \
    for (int m_ = 0; m_ < 4; m_++) \
        _Pragma("unroll") \
        for (int n_ = 0; n_ < 2; n_++) { \
            acc[(ma)+m_][(np)*2+n_] = mfma32(aF[m_][0], bF[(np)*2+n_][0], acc[(ma)+m_][(np)*2+n_]); \
            acc[(ma)+m_][(np)*2+n_] = mfma32(aF[m_][1], bF[(np)*2+n_][1], acc[(ma)+m_][(np)*2+n_]); \
        } \
    __builtin_amdgcn_s_setprio(0); \
} while (0)

template<int MODE>
__global__ __launch_bounds__(512, 2) void gemm256(
    const unsigned short* __restrict__ A, const unsigned short* __restrict__ Bt,
    const float* __restrict__ bias, void* __restrict__ Cout, int N, int K)
{
    __shared__ unsigned short lds[65536] __attribute__((aligned(128)));
    const int tid = threadIdx.x, wid = tid >> 6, lane = tid & 63;
    const int l16 = lane & 15, lhi = lane >> 4;
    const int wr = wid >> 2, wc = wid & 3;

    int flat = blockIdx.x;
    { int cpx = gridDim.x >> 3; flat = (flat & 7) * cpx + (flat >> 3); }
    const int bm = flat & 15, bn = flat >> 4;
    const int NT = K >> 6;

    const int srowL = tid >> 3;                                      // 0..63
    const int scolb = ((tid & 7) << 4) ^ (((tid >> 3) & 7) << 4);    // bytes (pre-swz src)
    const unsigned short* baseA = A  + (size_t)(bm * 256 + srowL) * K + (scolb >> 1);
    const unsigned short* baseB = Bt + (size_t)(bn * 256 + srowL) * K + (scolb >> 1);
    unsigned short* dst0 = lds + wid * 512;   // wave-uniform; HW adds lane*16B

    auto stage = [&](int isB, int tile, int h) {   // one half-tile = 2 gld16
        const unsigned short* s = (isB ? baseB : baseA) + (size_t)(h * 128) * K + (size_t)tile * 64;
        unsigned short* d = dst0 + (tile & 1) * 32768 + isB * 16384 + h * 8192;
        gld16(s, d);
        gld16(s + (size_t)64 * K, d + 4096);
    };

    const int lswz  = (l16 & 7) << 4;
    const int lane0 = ((lhi * 16) ^ lswz) + l16 * 128;
    const int lane1 = ((64 + lhi * 16) ^ lswz) + l16 * 128;

    const char* aR0 = (const char*)lds + wr * 16384;
    const char* bR0 = (const char*)lds + 32768 + (wc >> 1) * 16384 + (wc & 1) * 8192;
    const char* aR1 = aR0 + 65536;
    const char* bR1 = bR0 + 65536;

    f32x4 acc[8][4];
#pragma unroll
    for (int i = 0; i < 8; i++)
#pragma unroll
        for (int j = 0; j < 4; j++) acc[i][j] = (f32x4){0.f, 0.f, 0.f, 0.f};
    u16x8 aF[4][2], bF[4][2];

    // prologue: B(0),A(0),B(1); leave B(1)'s 4 loads in flight
    stage(1, 0, 0); stage(1, 0, 1);
    stage(0, 0, 0); stage(0, 0, 1);
    stage(1, 1, 0); stage(1, 1, 1);
    VM4();
    __builtin_amdgcn_s_barrier();

    for (int t = 0; t < NT; t += 2) {
        const bool more = (t + 2) < NT;
        // ---- K-tile t (buf0) ----
        LOADA(aR0, 0); LOADB(bR0, 0); stage(0, t + 1, 0);
        PSYNC(); MFMA8(0, 0); PEND();
        LOADB(bR0, 1);                stage(0, t + 1, 1);
        PSYNC(); MFMA8(0, 1); PEND();
        LOADA(aR0, 1);                if (more) stage(1, t + 2, 0);
        PSYNC(); MFMA8(4, 0); PEND();
        if (more) { stage(1, t + 2, 1); VM4(); }
        else      { asm volatile("s_waitcnt vmcnt(0)" ::: "memory"); }
        PSYNC(); MFMA8(4, 1); PEND();
        // ---- K-tile t+1 (buf1) ----
        LOADA(aR1, 0); LOADB(bR1, 0); if (more) stage(0, t + 2, 0);
        PSYNC(); MFMA8(0, 0); PEND();
        LOADB(bR1, 1);                if (more) stage(0, t + 2, 1);
        PSYNC(); MFMA8(0, 1); PEND();
        LOADA(aR1, 1);                if (more) stage(1, t + 3, 0);
        PSYNC(); MFMA8(4, 0); PEND();
        if (more) { stage(1, t + 3, 1); VM4(); }
        PSYNC(); MFMA8(4, 1); PEND();
    }

#pragma unroll
    for (int mi = 0; mi < 8; mi++)
#pragma unroll
        for (int ni = 0; ni < 4; ni++) {
            int row = bm * 256 + wr * 128 + mi * 16 + lhi * 4;
            int col = bn * 256 + wc * 64 + ni * 16 + l16;
            float bv = bias ? bias[col] : 0.f;
#pragma unroll
            for (int j = 0; j < 4; j++) {
                float v = acc[mi][ni][j] + bv;
                size_t idx = (size_t)(row + j) * N + col;
                if constexpr (MODE == 0) {
                    __builtin_nontemporal_store(v, (float*)Cout + idx);
                } else if constexpr (MODE == 1) {
                    ((unsigned short*)Cout)[idx] = f2bf(v);
                } else {
                    ((unsigned short*)Cout)[idx] = f2bf(v > 0.f ? v : 0.f);
                }
            }
        }
}

// ---------------- flash attention (causal), 64 q-rows/block, fused qkv input ----------------
__global__ __launch_bounds__(256, 3) void attn_fwd(
    const unsigned short* __restrict__ qkv, unsigned short* __restrict__ ctxb)
{
    __shared__ unsigned short Ks[64 * 72];
    __shared__ unsigned short Vs[64 * 72];   // transposed: Vs[d][kv]
    __shared__ unsigned short Ps[4 * 16 * 72];
    const int tid = threadIdx.x;
    const int wid = tid >> 6, lane = tid & 63;
    const int l16 = lane & 15, lhi = lane >> 4;
    const int bh  = blockIdx.y, b = bh >> 4, h = bh & 15;
    const int q0  = blockIdx.x * 64;
    const size_t rowbase = (size_t)b * SEQ;

    const int qrow = q0 + wid * 16 + l16;
    const unsigned short* qp = qkv + (rowbase + qrow) * QKV_N + h * HDIM + lhi * 8;
    u16x8 qf0 = *(const u16x8*)qp;
    u16x8 qf1 = *(const u16x8*)(qp + 32);

    f32x4 oa[4];
    float mj[4], lj[4];
#pragma unroll
    for (int i = 0; i < 4; i++) {
        oa[i] = (f32x4){0.f, 0.f, 0.f, 0.f};
        mj[i] = -1e30f; lj[i] = 0.f;
    }

    const int ntiles = blockIdx.x + 1;
    for (int kt = 0; kt < ntiles; ++kt) {
        const int kv0 = kt * 64;
        __syncthreads();
#pragma unroll
        for (int it = 0; it < 2; ++it) {
            int e = it * 256 + tid;
            int r = e >> 3, d0 = (e & 7) * 8;
            size_t goff = (rowbase + kv0 + r) * QKV_N + D_MODEL + h * HDIM + d0;
            u16x8 kk = *(const u16x8*)(qkv + goff);
            *(u16x8*)(&Ks[r * 72 + d0]) = kk;
            u16x8 vv = *(const u16x8*)(qkv + goff + D_MODEL);
#pragma unroll
            for (int j = 0; j < 8; j++) Vs[(d0 + j) * 72 + r] = vv[j];
        }
        __syncthreads();

        f32x4 sa[4];
#pragma unroll
        for (int ni = 0; ni < 4; ni++) {
            f32x4 z = (f32x4){0.f, 0.f, 0.f, 0.f};
            u16x8 k0f = *(const u16x8*)(&Ks[(ni * 16 + l16) * 72 + lhi * 8]);
            u16x8 k1f = *(const u16x8*)(&Ks[(ni * 16 + l16) * 72 + 32 + lhi * 8]);
            z = mfma32(qf0, k0f, z);
            z = mfma32(qf1, k1f, z);
            sa[ni] = z;
        }
        float tm[4] = {-1e30f, -1e30f, -1e30f, -1e30f};
#pragma unroll
        for (int ni = 0; ni < 4; ni++)
#pragma unroll
            for (int j = 0; j < 4; j++) {
                float v = sa[ni][j] * 0.125f;
                int row = q0 + wid * 16 + lhi * 4 + j;
                int col = kv0 + ni * 16 + l16;
                if (col > row) v = -1e30f;
                sa[ni][j] = v;
                tm[j] = fmaxf(tm[j], v);
            }
#pragma unroll
        for (int j = 0; j < 4; j++) {
#pragma unroll
            for (int off = 1; off < 16; off <<= 1)
                tm[j] = fmaxf(tm[j], __shfl_xor(tm[j], off));
        }
        float al[4], rs[4] = {0.f, 0.f, 0.f, 0.f};
#pragma unroll
        for (int j = 0; j < 4; j++) {
            float mn = fmaxf(mj[j], tm[j]);
            al[j] = __expf(mj[j] - mn);
            mj[j] = mn;
        }
#pragma unroll
        for (int ni = 0; ni < 4; ni++)
#pragma unroll
            for (int j = 0; j < 4; j++) {
                float p = __expf(sa[ni][j] - mj[j]);
                rs[j] += p;
                Ps[wid * 1152 + (lhi * 4 + j) * 72 + ni * 16 + l16] = f2bf(p);
            }
#pragma unroll
        for (int j = 0; j < 4; j++) {
#pragma unroll
            for (int off = 1; off < 16; off <<= 1)
                rs[j] += __shfl_xor(rs[j], off);
            lj[j] = lj[j] * al[j] + rs[j];
        }
#pragma unroll
        for (int di = 0; di < 4; di++)
#pragma unroll
            for (int j = 0; j < 4; j++) oa[di][j] *= al[j];
#pragma unroll
        for (int di = 0; di < 4; di++) {
#pragma unroll
            for (int kc = 0; kc < 2; kc++) {
                u16x8 pf = *(const u16x8*)(&Ps[wid * 1152 + l16 * 72 + kc * 32 + lhi * 8]);
                u16x8 vf = *(const u16x8*)(&Vs[(di * 16 + l16) * 72 + kc * 32 + lhi * 8]);
                oa[di] = mfma32(pf, vf, oa[di]);
            }
        }
    }
#pragma unroll
    for (int di = 0; di < 4; di++)
#pragma unroll
        for (int j = 0; j < 4; j++) {
            int row = q0 + wid * 16 + lhi * 4 + j;
            ctxb[(rowbase + row) * D_MODEL + h * HDIM + di * 16 + l16] =
                f2bf(oa[di][j] / lj[j]);
        }
}

// ---------------- fused residual(x + p0 + p1) + LayerNorm ----------------
__global__ __launch_bounds__(256) void ln3(
    float* __restrict__ x, const float* __restrict__ p0, const float* __restrict__ p1,
    const float* __restrict__ sc, const float* __restrict__ bi,
    unsigned short* __restrict__ xb)
{
    const int row = blockIdx.x;
    const int t = threadIdx.x;
    const size_t base = (size_t)row * D_MODEL + t * 4;
    float4 xv = *(const float4*)(x + base);
    float4 av = *(const float4*)(p0 + base);
    float4 bvv = *(const float4*)(p1 + base);
    float v0 = xv.x + av.x + bvv.x, v1 = xv.y + av.y + bvv.y;
    float v2 = xv.z + av.z + bvv.z, v3 = xv.w + av.w + bvv.w;
    float sum = v0 + v1 + v2 + v3;
    float sq  = v0 * v0 + v1 * v1 + v2 * v2 + v3 * v3;
#pragma unroll
    for (int off = 1; off < 64; off <<= 1) {
        sum += __shfl_xor(sum, off);
        sq  += __shfl_xor(sq, off);
    }
    __shared__ float red[8];
    int wid = t >> 6, lane = t & 63;
    if (lane == 0) { red[wid] = sum; red[4 + wid] = sq; }
    __syncthreads();
    sum = red[0] + red[1] + red[2] + red[3];
    sq  = red[4] + red[5] + red[6] + red[7];
    float mu   = sum * (1.f / D_MODEL);
    float var  = sq * (1.f / D_MODEL) - mu * mu;
    float rstd = rsqrtf(var + LN_EPS);
    int c = t * 4;
    float4 sv = *(const float4*)(sc + c);
    float4 bv = *(const float4*)(bi + c);
    float y0 = sv.x * (v0 - mu) * rstd + bv.x;
    float y1 = sv.y * (v1 - mu) * rstd + bv.y;
    float y2 = sv.z * (v2 - mu) * rstd + bv.z;
    float y3 = sv.w * (v3 - mu) * rstd + bv.w;
    *(float4*)(x + base) = make_float4(y0, y1, y2, y3);
    unsigned long long pk = (unsigned long long)f2bf(y0)
        | ((unsigned long long)f2bf(y1) << 16)
        | ((unsigned long long)f2bf(y2) << 32)
        | ((unsigned long long)f2bf(y3) << 48);
    *(unsigned long long*)(xb + base) = pk;
}

// ---------------- launcher ----------------
extern "C" void kernel_launch(void* const* d_in, const int* in_sizes, int n_in,
                              void* d_out, int out_size, void* d_ws, size_t ws_size,
                              hipStream_t stream)
{
    (void)in_sizes; (void)n_in; (void)out_size;
    const int*   tokens = (const int*)d_in[0];
    const float* emb  = (const float*)d_in[2];
    const float* pose = (const float*)d_in[3];
    const float* Wq = (const float*)d_in[4];
    const float* bq = (const float*)d_in[5];
    const float* Wk = (const float*)d_in[6];
    const float* bk = (const float*)d_in[7];
    const float* Wv = (const float*)d_in[8];
    const float* bv = (const float*)d_in[9];
    const float* Wo = (const float*)d_in[10];
    const float* bo = (const float*)d_in[11];
    const float* n1s = (const float*)d_in[12];
    const float* n1b = (const float*)d_in[13];
    const float* W1 = (const float*)d_in[14];
    const float* b1 = (const float*)d_in[15];
    const float* W2 = (const float*)d_in[16];
    const float* b2 = (const float*)d_in[17];
    const float* n2s = (const float*)d_in[18];
    const float* n2b = (const float*)d_in[19];

    char* w = (char*)d_ws;
    size_t off = 0;
    auto carve = [&](size_t bytes) -> void* {
        void* p = w + off;
        off = (off + bytes + 255) & ~(size_t)255;
        return p;
    };
    float* x   = (float*)carve((size_t)ROWS * D_MODEL * 4);
    float* tmp = (float*)carve((size_t)2 * ROWS * D_MODEL * 4);   // 2 split-K partials
    unsigned short* xb    = (unsigned short*)carve((size_t)ROWS * D_MODEL * 2);
    unsigned short* qkvb  = (unsigned short*)carve((size_t)ROWS * QKV_N * 2);
    unsigned short* cbuf  = (unsigned short*)carve((size_t)ROWS * D_MODEL * 2);
    unsigned short* hbuf  = (unsigned short*)carve((size_t)ROWS * FF_DIM * 2);
    unsigned short* wt    = (unsigned short*)carve((size_t)D_MODEL * FF_DIM * 2);
    float* bqkv = (float*)carve((size_t)NLAYER * QKV_N * 4);
    unsigned short* embb = qkvb;   // tied-head emb aliases dead qkv/ctx/h region
    float* tmp1 = tmp + (size_t)ROWS * D_MODEL;
    if (off > ws_size) return;

    bias3_k<<<NLAYER * 3, 256, 0, stream>>>(bq, bk, bv, bqkv);
    embed_k<<<ROWS, 256, 0, stream>>>(tokens, emb, pose, x, xb);

    for (int l = 0; l < NLAYER; l++) {
        const float* Wq_l = Wq + (size_t)l * D_MODEL * D_MODEL;
        const float* Wk_l = Wk + (size_t)l * D_MODEL * D_MODEL;
        const float* Wv_l = Wv + (size_t)l * D_MODEL * D_MODEL;
        const float* Wo_l = Wo + (size_t)l * D_MODEL * D_MODEL;
        const float* W1_l = W1 + (size_t)l * D_MODEL * FF_DIM;
        const float* W2_l = W2 + (size_t)l * FF_DIM * D_MODEL;

        transpose_cast3<<<dim3(16, 16, 3), 256, 0, stream>>>(Wq_l, Wk_l, Wv_l, wt);
        gemm256<1><<<(QKV_N / 256) * 16, 512, 0, stream>>>(xb, wt, bqkv + (size_t)l * QKV_N, qkvb, QKV_N, D_MODEL);

        attn_fwd<<<dim3(SEQ / 64, BATCH * NHEAD), 256, 0, stream>>>(qkvb, cbuf);

        transpose_cast<<<dim3(16, 16), 256, 0, stream>>>(Wo_l, wt, D_MODEL, D_MODEL);
        gemm_bt<0><<<dim3(256, 2), 256, 0, stream>>>(cbuf, D_MODEL, wt, D_MODEL,
                                                     bo + (size_t)l * D_MODEL, tmp, D_MODEL, D_MODEL / 2);
        ln3<<<ROWS, 256, 0, stream>>>(x, tmp, tmp1, n1s + (size_t)l * D_MODEL, n1b + (size_t)l * D_MODEL, xb);

        transpose_cast<<<dim3(64, 16), 256, 0, stream>>>(W1_l, wt, D_MODEL, FF_DIM);
        gemm256<2><<<(FF_DIM / 256) * 16, 512, 0, stream>>>(xb, wt, b1 + (size_t)l * FF_DIM, hbuf, FF_DIM, D_MODEL);
        transpose_cast<<<dim3(16, 64), 256, 0, stream>>>(W2_l, wt, FF_DIM, D_MODEL);
        gemm_bt<0><<<dim3(256, 2), 256, 0, stream>>>(hbuf, FF_DIM, wt, FF_DIM,
                                                     b2 + (size_t)l * D_MODEL, tmp, D_MODEL, FF_DIM / 2);
        ln3<<<ROWS, 256, 0, stream>>>(x, tmp, tmp1, n2s + (size_t)l * D_MODEL, n2b + (size_t)l * D_MODEL, xb);
    }

    cast_bf<<<(VOCAB * D_MODEL) / 1024, 256, 0, stream>>>(emb, embb, (size_t)VOCAB * D_MODEL);
    gemm256<0><<<(VOCAB / 256) * 16, 512, 0, stream>>>(xb, embb, nullptr, d_out, VOCAB, D_MODEL);
}

// Round 8
// 2307.521 us; speedup vs baseline: 1.2056x; 1.0948x over previous
//
#include <hip/hip_runtime.h>

#define D_MODEL 1024
#define SEQ     1024
#define BATCH   4
#define NHEAD   16
#define HDIM    64
#define FF_DIM  4096
#define NLAYER  8
#define VOCAB   32000
#define ROWS    (BATCH*SEQ)
#define QKV_N   3072
#define LN_EPS  1e-5f

typedef __attribute__((ext_vector_type(4))) float   f32x4;
typedef __attribute__((ext_vector_type(8))) unsigned short u16x8;
typedef __attribute__((ext_vector_type(8))) __bf16  bf16x8;

typedef const unsigned int __attribute__((address_space(1)))* gas_t;
typedef unsigned int __attribute__((address_space(3)))* las_t;

__device__ __forceinline__ void gld16(const void* g, void* l) {
    __builtin_amdgcn_global_load_lds((gas_t)g, (las_t)l, 16, 0, 0);
}

__device__ __forceinline__ unsigned short f2bf(float f) {
    unsigned int u = __builtin_bit_cast(unsigned int, f);
    u += 0x7FFFu + ((u >> 16) & 1u);   // RNE
    return (unsigned short)(u >> 16);
}

__device__ __forceinline__ f32x4 mfma32(u16x8 a, u16x8 b, f32x4 c) {
    return __builtin_amdgcn_mfma_f32_16x16x32_bf16(
        __builtin_bit_cast(bf16x8, a), __builtin_bit_cast(bf16x8, b), c, 0, 0, 0);
}

// ---------------- embed: x = emb[tok] + pos ----------------
__global__ __launch_bounds__(256) void embed_k(
    const int* __restrict__ tok, const float* __restrict__ emb,
    const float* __restrict__ pos, float* __restrict__ x,
    unsigned short* __restrict__ xb)
{
    int bs = blockIdx.x;
    int s  = bs & (SEQ - 1);
    int tk = tok[bs];
    int c  = threadIdx.x * 4;
    float4 e = *(const float4*)(emb + (size_t)tk * D_MODEL + c);
    float4 p = *(const float4*)(pos + (size_t)s * D_MODEL + c);
    float y0 = e.x + p.x, y1 = e.y + p.y, y2 = e.z + p.z, y3 = e.w + p.w;
    size_t base = (size_t)bs * D_MODEL + c;
    *(float4*)(x + base) = make_float4(y0, y1, y2, y3);
    unsigned long long pk = (unsigned long long)f2bf(y0)
        | ((unsigned long long)f2bf(y1) << 16)
        | ((unsigned long long)f2bf(y2) << 32)
        | ((unsigned long long)f2bf(y3) << 48);
    *(unsigned long long*)(xb + base) = pk;
}

// ---------------- cast fp32 -> bf16 ----------------
__global__ __launch_bounds__(256) void cast_bf(
    const float* __restrict__ in, unsigned short* __restrict__ out, size_t n)
{
    size_t i = ((size_t)blockIdx.x * 256 + threadIdx.x) * 4;
    if (i >= n) return;
    float4 v = *(const float4*)(in + i);
    unsigned long long pk = (unsigned long long)f2bf(v.x)
        | ((unsigned long long)f2bf(v.y) << 16)
        | ((unsigned long long)f2bf(v.z) << 32)
        | ((unsigned long long)f2bf(v.w) << 48);
    *(unsigned long long*)(out + i) = pk;
}

// ---------------- concat qkv biases ----------------
__global__ __launch_bounds__(256) void bias3_k(
    const float* __restrict__ bq, const float* __restrict__ bk,
    const float* __restrict__ bv, float* __restrict__ out)
{
    int l = blockIdx.x / 3, which = blockIdx.x % 3;
    const float* src = which == 0 ? bq : (which == 1 ? bk : bv);
    int i = threadIdx.x * 4;
    float4 v = *(const float4*)(src + (size_t)l * D_MODEL + i);
    *(float4*)(out + (size_t)l * QKV_N + which * D_MODEL + i) = v;
}

// ---------------- transpose tile body (shared) ----------------
__device__ __forceinline__ void tc_tile(
    const float* __restrict__ W, unsigned short* __restrict__ Wt,
    int K, int N, int n0, int k0)
{
    __shared__ float t[64][65];
    int rr = threadIdx.x >> 4;          // 0..15
    int cc = (threadIdx.x & 15) * 4;    // 0..60
#pragma unroll
    for (int it = 0; it < 4; it++) {
        int r = it * 16 + rr;
        float4 v = *(const float4*)(W + (size_t)(k0 + r) * N + n0 + cc);
        t[r][cc] = v.x; t[r][cc + 1] = v.y; t[r][cc + 2] = v.z; t[r][cc + 3] = v.w;
    }
    __syncthreads();
#pragma unroll
    for (int it = 0; it < 4; it++) {
        int n = it * 16 + rr;
        unsigned long long pk = (unsigned long long)f2bf(t[cc][n])
            | ((unsigned long long)f2bf(t[cc + 1][n]) << 16)
            | ((unsigned long long)f2bf(t[cc + 2][n]) << 32)
            | ((unsigned long long)f2bf(t[cc + 3][n]) << 48);
        *(unsigned long long*)(Wt + (size_t)(n0 + n) * K + k0 + cc) = pk;
    }
}

// ---------------- per-tile transpose kernels (fallback path) ----------------
__global__ __launch_bounds__(256) void transpose_cast(
    const float* __restrict__ W, unsigned short* __restrict__ Wt, int K, int N)
{
    tc_tile(W, Wt, K, N, blockIdx.x * 64, blockIdx.y * 64);
}

__global__ __launch_bounds__(256) void transpose_cast3(
    const float* __restrict__ Wq, const float* __restrict__ Wk,
    const float* __restrict__ Wv, unsigned short* __restrict__ Wt)
{
    const int which = blockIdx.z;
    const float* W = which == 0 ? Wq : (which == 1 ? Wk : Wv);
    tc_tile(W, Wt + (size_t)which * (1024 * 1024), 1024, 1024,
            blockIdx.x * 64, blockIdx.y * 64);
}

// ---------------- fused per-layer transpose: Wq,Wk,Wv,Wo,W1,W2 in ONE launch ----
// wt layout (elems): [0,3M) qkv^T, [3M,4M) Wo^T, [4M,8M) W1^T, [8M,12M) W2^T
__global__ __launch_bounds__(256) void transpose_all(
    const float* __restrict__ Wq, const float* __restrict__ Wk,
    const float* __restrict__ Wv, const float* __restrict__ Wo,
    const float* __restrict__ W1, const float* __restrict__ W2,
    unsigned short* __restrict__ wt)
{
    int b = blockIdx.x;
    const float* W; unsigned short* out; int K, N, t;
    if (b < 768)       { int w = b >> 8; t = b & 255; W = w == 0 ? Wq : (w == 1 ? Wk : Wv);
                         out = wt + (size_t)w * 1048576; K = 1024; N = 1024; }
    else if (b < 1024) { t = b - 768;  W = Wo; out = wt + (size_t)3 * 1048576; K = 1024; N = 1024; }
    else if (b < 2048) { t = b - 1024; W = W1; out = wt + (size_t)4 * 1048576; K = 1024; N = 4096; }
    else               { t = b - 2048; W = W2; out = wt + (size_t)8 * 1048576; K = 4096; N = 1024; }
    int ntx = N >> 6;
    tc_tile(W, out, K, N, (t % ntx) * 64, (t / ntx) * 64);
}

// ---------------- small NT GEMM (m97 128x128) with split-K support ----------------
template<int MODE>
__global__ __launch_bounds__(256, 3) void gemm_bt(
    const unsigned short* __restrict__ A, int lda,
    const unsigned short* __restrict__ Bt, int ldb,
    const float* __restrict__ bias, void* __restrict__ Cout, int N, int Klen)
{
    __shared__ unsigned short As[128 * 32];
    __shared__ unsigned short Bs[128 * 32];
    const int part = blockIdx.y;
    A  += (size_t)part * Klen;
    Bt += (size_t)part * Klen;
    int flat = blockIdx.x;
    const int bm = flat & 31, bn = flat >> 5;
    const int tid  = threadIdx.x;
    const int wid  = tid >> 6, lane = tid & 63;
    const int l16  = lane & 15, lhi = lane >> 4;
    const int wr   = wid >> 1, wc = wid & 1;

    const int srow = wid * 32 + (lane >> 2);
    const int scol = (lane & 3) * 8;
    const unsigned short* gA0 = A  + ((size_t)bm * 128 + srow) * lda + scol;
    const unsigned short* gB0 = Bt + ((size_t)bn * 128 + srow) * ldb + scol;
    unsigned short* lA = As + wid * 32 * 32;
    unsigned short* lB = Bs + wid * 32 * 32;

    f32x4 acc[4][4];
#pragma unroll
    for (int i = 0; i < 4; i++)
#pragma unroll
        for (int j = 0; j < 4; j++) acc[i][j] = (f32x4){0.f, 0.f, 0.f, 0.f};

    for (int k0 = 0; k0 < Klen; k0 += 32) {
        __syncthreads();
        gld16(gA0 + k0,                    lA);
        gld16(gA0 + k0 + 16 * (size_t)lda, lA + 16 * 32);
        gld16(gB0 + k0,                    lB);
        gld16(gB0 + k0 + 16 * (size_t)ldb, lB + 16 * 32);
        __syncthreads();
        u16x8 af[4], bfr[4];
#pragma unroll
        for (int i = 0; i < 4; i++)
            af[i] = *(const u16x8*)(As + (wr * 64 + i * 16 + l16) * 32 + lhi * 8);
#pragma unroll
        for (int i = 0; i < 4; i++)
            bfr[i] = *(const u16x8*)(Bs + (wc * 64 + i * 16 + l16) * 32 + lhi * 8);
#pragma unroll
        for (int mi = 0; mi < 4; mi++)
#pragma unroll
            for (int ni = 0; ni < 4; ni++)
                acc[mi][ni] = mfma32(af[mi], bfr[ni], acc[mi][ni]);
    }

    const size_t pofs = (size_t)part * (size_t)ROWS * N;
#pragma unroll
    for (int mi = 0; mi < 4; mi++)
#pragma unroll
        for (int ni = 0; ni < 4; ni++) {
            int row = bm * 128 + wr * 64 + mi * 16 + lhi * 4;
            int col = bn * 128 + wc * 64 + ni * 16 + l16;
            float bv = (bias && part == 0) ? bias[col] : 0.f;
#pragma unroll
            for (int j = 0; j < 4; j++) {
                float v = acc[mi][ni][j] + bv;
                size_t idx = pofs + (size_t)(row + j) * N + col;
                if constexpr (MODE == 0) {
                    ((float*)Cout)[idx] = v;
                } else if constexpr (MODE == 1) {
                    ((unsigned short*)Cout)[idx] = f2bf(v);
                } else {
                    ((unsigned short*)Cout)[idx] = f2bf(v > 0.f ? v : 0.f);
                }
            }
        }
}

// ================= 256x256 8-phase GEMM (R4-best structure + NT store) =================
#define PSYNC() do { __builtin_amdgcn_s_barrier(); \
    asm volatile("s_waitcnt lgkmcnt(0)" ::: "memory"); \
    __builtin_amdgcn_sched_barrier(0); } while (0)
#define PEND() __builtin_amdgcn_s_barrier()
#define VM4()  asm volatile("s_waitcnt vmcnt(4)" ::: "memory")

#define LOADA(reg, half) do { \
    _Pragma("unroll") \
    for (int m_ = 0; m_ < 4; m_++) { \
        aF[m_][0] = *(const u16x8*)((reg) + ((half)*4 + m_) * 2048 + lane0); \
        aF[m_][1] = *(const u16x8*)((reg) + ((half)*4 + m_) * 2048 + lane1); \
    } } while (0)

#define LOADB(reg, np) do { \
    _Pragma("unroll") \
    for (int n_ = 0; n_ < 2; n_++) { \
        bF[(np)*2 + n_][0] = *(const u16x8*)((reg) + ((np)*2 + n_) * 2048 + lane0); \
        bF[(np)*2 + n_][1] = *(const u16x8*)((reg) + ((np)*2 + n_) * 2048 + lane1); \
    } } while (0)

#define MFMA8(ma, np) do { \
    __builtin_amdgcn_s_setprio(1); \
    _Pragma("unroll") \
    for (int m_ = 0; m_ < 4; m_++) \
        _Pragma("unroll") \
        for (int n_ = 0; n_ < 2; n_++) { \
            acc[(ma)+m_][(np)*2+n_] = mfma32(aF[m_][0], bF[(np)*2+n_][0], acc[(ma)+m_][(np)*2+n_]); \
            acc[(ma)+m_][(np)*2+n_] = mfma32(aF[m_][1], bF[(np)*2+n_][1], acc[(ma)+m_][(np)*2+n_]); \
        } \
    __builtin_amdgcn_s_setprio(0); \
} while (0)

template<int MODE>
__global__ __launch_bounds__(512, 2) void gemm256(
    const unsigned short* __restrict__ A, const unsigned short* __restrict__ Bt,
    const float* __restrict__ bias, void* __restrict__ Cout, int N, int K)
{
    __shared__ unsigned short lds[65536] __attribute__((aligned(128)));
    const int tid = threadIdx.x, wid = tid >> 6, lane = tid & 63;
    const int l16 = lane & 15, lhi = lane >> 4;
    const int wr = wid >> 2, wc = wid & 3;

    int flat = blockIdx.x;
    { int cpx = gridDim.x >> 3; flat = (flat & 7) * cpx + (flat >> 3); }
    const int bm = flat & 15, bn = flat >> 4;
    const int NT = K >> 6;

    const int srowL = tid >> 3;                                      // 0..63
    const int scolb = ((tid & 7) << 4) ^ (((tid >> 3) & 7) << 4);    // bytes (pre-swz src)
    const unsigned short* baseA = A  + (size_t)(bm * 256 + srowL) * K + (scolb >> 1);
    const unsigned short* baseB = Bt + (size_t)(bn * 256 + srowL) * K + (scolb >> 1);
    unsigned short* dst0 = lds + wid * 512;   // wave-uniform; HW adds lane*16B

    auto stage = [&](int isB, int tile, int h) {   // one half-tile = 2 gld16
        const unsigned short* s = (isB ? baseB : baseA) + (size_t)(h * 128) * K + (size_t)tile * 64;
        unsigned short* d = dst0 + (tile & 1) * 32768 + isB * 16384 + h * 8192;
        gld16(s, d);
        gld16(s + (size_t)64 * K, d + 4096);
    };

    const int lswz  = (l16 & 7) << 4;
    const int lane0 = ((lhi * 16) ^ lswz) + l16 * 128;
    const int lane1 = ((64 + lhi * 16) ^ lswz) + l16 * 128;

    const char* aR0 = (const char*)lds + wr * 16384;
    const char* bR0 = (const char*)lds + 32768 + (wc >> 1) * 16384 + (wc & 1) * 8192;
    const char* aR1 = aR0 + 65536;
    const char* bR1 = bR0 + 65536;

    f32x4 acc[8][4];
#pragma unroll
    for (int i = 0; i < 8; i++)
#pragma unroll
        for (int j = 0; j < 4; j++) acc[i][j] = (f32x4){0.f, 0.f, 0.f, 0.f};
    u16x8 aF[4][2], bF[4][2];

    // prologue: B(0),A(0),B(1); leave B(1)'s 4 loads in flight
    stage(1, 0, 0); stage(1, 0, 1);
    stage(0, 0, 0); stage(0, 0, 1);
    stage(1, 1, 0); stage(1, 1, 1);
    VM4();
    __builtin_amdgcn_s_barrier();

    for (int t = 0; t < NT; t += 2) {
        const bool more = (t + 2) < NT;
        // ---- K-tile t (buf0) ----
        LOADA(aR0, 0); LOADB(bR0, 0); stage(0, t + 1, 0);
        PSYNC(); MFMA8(0, 0); PEND();
        LOADB(bR0, 1);                stage(0, t + 1, 1);
        PSYNC(); MFMA8(0, 1); PEND();
        LOADA(aR0, 1);                if (more) stage(1, t + 2, 0);
        PSYNC(); MFMA8(4, 0); PEND();
        if (more) { stage(1, t + 2, 1); VM4(); }
        else      { asm volatile("s_waitcnt vmcnt(0)" ::: "memory"); }
        PSYNC(); MFMA8(4, 1); PEND();
        // ---- K-tile t+1 (buf1) ----
        LOADA(aR1, 0); LOADB(bR1, 0); if (more) stage(0, t + 2, 0);
        PSYNC(); MFMA8(0, 0); PEND();
        LOADB(bR1, 1);                if (more) stage(0, t + 2, 1);
        PSYNC(); MFMA8(0, 1); PEND();
        LOADA(aR1, 1);                if (more) stage(1, t + 3, 0);
        PSYNC(); MFMA8(4, 0); PEND();
        if (more) { stage(1, t + 3, 1); VM4(); }
        PSYNC(); MFMA8(4, 1); PEND();
    }

#pragma unroll
    for (int mi = 0; mi < 8; mi++)
#pragma unroll
        for (int ni = 0; ni < 4; ni++) {
            int row = bm * 256 + wr * 128 + mi * 16 + lhi * 4;
            int col = bn * 256 + wc * 64 + ni * 16 + l16;
            float bv = bias ? bias[col] : 0.f;
#pragma unroll
            for (int j = 0; j < 4; j++) {
                float v = acc[mi][ni][j] + bv;
                size_t idx = (size_t)(row + j) * N + col;
                if constexpr (MODE == 0) {
                    __builtin_nontemporal_store(v, (float*)Cout + idx);
                } else if constexpr (MODE == 1) {
                    ((unsigned short*)Cout)[idx] = f2bf(v);
                } else {
                    ((unsigned short*)Cout)[idx] = f2bf(v > 0.f ? v : 0.f);
                }
            }
        }
}

// ---------------- flash attention (causal), 64 q-rows/block, fused qkv input ----------------
__global__ __launch_bounds__(256, 3) void attn_fwd(
    const unsigned short* __restrict__ qkv, unsigned short* __restrict__ ctxb)
{
    __shared__ unsigned short Ks[64 * 72];
    __shared__ unsigned short Vs[64 * 72];   // transposed: Vs[d][kv]
    __shared__ unsigned short Ps[4 * 16 * 72];
    const int tid = threadIdx.x;
    const int wid = tid >> 6, lane = tid & 63;
    const int l16 = lane & 15, lhi = lane >> 4;
    const int bh  = blockIdx.y, b = bh >> 4, h = bh & 15;
    const int q0  = blockIdx.x * 64;
    const size_t rowbase = (size_t)b * SEQ;

    const int qrow = q0 + wid * 16 + l16;
    const unsigned short* qp = qkv + (rowbase + qrow) * QKV_N + h * HDIM + lhi * 8;
    u16x8 qf0 = *(const u16x8*)qp;
    u16x8 qf1 = *(const u16x8*)(qp + 32);

    f32x4 oa[4];
    float mj[4], lj[4];
#pragma unroll
    for (int i = 0; i < 4; i++) {
        oa[i] = (f32x4){0.f, 0.f, 0.f, 0.f};
        mj[i] = -1e30f; lj[i] = 0.f;
    }

    const int ntiles = blockIdx.x + 1;
    for (int kt = 0; kt < ntiles; ++kt) {
        const int kv0 = kt * 64;
        __syncthreads();
        // K staging: vector writes, row-major
#pragma unroll
        for (int it = 0; it < 2; ++it) {
            int e = it * 256 + tid;
            int r = e >> 3, d0 = (e & 7) * 8;
            size_t goff = (rowbase + kv0 + r) * QKV_N + D_MODEL + h * HDIM + d0;
            u16x8 kk = *(const u16x8*)(qkv + goff);
            *(u16x8*)(&Ks[r * 72 + d0]) = kk;
        }
        // V staging: 128 threads x 4 rows -> transposed via register repack,
        // 8x ds_write_b64 each (replaces 8x scalar b16 per 8 elems)
        if (tid < 128) {
            int r0 = (tid & 15) * 4, d0v = (tid >> 4) * 8;
            const unsigned short* vp = qkv + (rowbase + kv0 + r0) * QKV_N
                                       + 2 * D_MODEL + h * HDIM + d0v;
            u16x8 w0 = *(const u16x8*)vp;
            u16x8 w1 = *(const u16x8*)(vp + QKV_N);
            u16x8 w2 = *(const u16x8*)(vp + 2 * QKV_N);
            u16x8 w3 = *(const u16x8*)(vp + 3 * QKV_N);
#pragma unroll
            for (int j = 0; j < 8; j++) {
                unsigned long long pk = (unsigned long long)w0[j]
                    | ((unsigned long long)w1[j] << 16)
                    | ((unsigned long long)w2[j] << 32)
                    | ((unsigned long long)w3[j] << 48);
                *(unsigned long long*)(&Vs[(d0v + j) * 72 + r0]) = pk;
            }
        }
        __syncthreads();

        f32x4 sa[4];
#pragma unroll
        for (int ni = 0; ni < 4; ni++) {
            f32x4 z = (f32x4){0.f, 0.f, 0.f, 0.f};
            u16x8 k0f = *(const u16x8*)(&Ks[(ni * 16 + l16) * 72 + lhi * 8]);
            u16x8 k1f = *(const u16x8*)(&Ks[(ni * 16 + l16) * 72 + 32 + lhi * 8]);
            z = mfma32(qf0, k0f, z);
            z = mfma32(qf1, k1f, z);
            sa[ni] = z;
        }
        float tm[4] = {-1e30f, -1e30f, -1e30f, -1e30f};
#pragma unroll
        for (int ni = 0; ni < 4; ni++)
#pragma unroll
            for (int j = 0; j < 4; j++) {
                float v = sa[ni][j] * 0.125f;
                int row = q0 + wid * 16 + lhi * 4 + j;
                int col = kv0 + ni * 16 + l16;
                if (col > row) v = -1e30f;
                sa[ni][j] = v;
                tm[j] = fmaxf(tm[j], v);
            }
#pragma unroll
        for (int j = 0; j < 4; j++) {
#pragma unroll
            for (int off = 1; off < 16; off <<= 1)
                tm[j] = fmaxf(tm[j], __shfl_xor(tm[j], off));
        }
        float al[4], rs[4] = {0.f, 0.f, 0.f, 0.f};
#pragma unroll
        for (int j = 0; j < 4; j++) {
            float mn = fmaxf(mj[j], tm[j]);
            al[j] = __expf(mj[j] - mn);
            mj[j] = mn;
        }
#pragma unroll
        for (int ni = 0; ni < 4; ni++)
#pragma unroll
            for (int j = 0; j < 4; j++) {
                float p = __expf(sa[ni][j] - mj[j]);
                rs[j] += p;
                Ps[wid * 1152 + (lhi * 4 + j) * 72 + ni * 16 + l16] = f2bf(p);
            }
#pragma unroll
        for (int j = 0; j < 4; j++) {
#pragma unroll
            for (int off = 1; off < 16; off <<= 1)
                rs[j] += __shfl_xor(rs[j], off);
            lj[j] = lj[j] * al[j] + rs[j];
        }
#pragma unroll
        for (int di = 0; di < 4; di++)
#pragma unroll
            for (int j = 0; j < 4; j++) oa[di][j] *= al[j];
#pragma unroll
        for (int di = 0; di < 4; di++) {
#pragma unroll
            for (int kc = 0; kc < 2; kc++) {
                u16x8 pf = *(const u16x8*)(&Ps[wid * 1152 + l16 * 72 + kc * 32 + lhi * 8]);
                u16x8 vf = *(const u16x8*)(&Vs[(di * 16 + l16) * 72 + kc * 32 + lhi * 8]);
                oa[di] = mfma32(pf, vf, oa[di]);
            }
        }
    }
#pragma unroll
    for (int di = 0; di < 4; di++)
#pragma unroll
        for (int j = 0; j < 4; j++) {
            int row = q0 + wid * 16 + lhi * 4 + j;
            ctxb[(rowbase + row) * D_MODEL + h * HDIM + di * 16 + l16] =
                f2bf(oa[di][j] / lj[j]);
        }
}

// ---------------- fused residual(x + p0 + p1) + LayerNorm ----------------
__global__ __launch_bounds__(256) void ln3(
    float* __restrict__ x, const float* __restrict__ p0, const float* __restrict__ p1,
    const float* __restrict__ sc, const float* __restrict__ bi,
    unsigned short* __restrict__ xb)
{
    const int row = blockIdx.x;
    const int t = threadIdx.x;
    const size_t base = (size_t)row * D_MODEL + t * 4;
    float4 xv = *(const float4*)(x + base);
    float4 av = *(const float4*)(p0 + base);
    float4 bvv = *(const float4*)(p1 + base);
    float v0 = xv.x + av.x + bvv.x, v1 = xv.y + av.y + bvv.y;
    float v2 = xv.z + av.z + bvv.z, v3 = xv.w + av.w + bvv.w;
    float sum = v0 + v1 + v2 + v3;
    float sq  = v0 * v0 + v1 * v1 + v2 * v2 + v3 * v3;
#pragma unroll
    for (int off = 1; off < 64; off <<= 1) {
        sum += __shfl_xor(sum, off);
        sq  += __shfl_xor(sq, off);
    }
    __shared__ float red[8];
    int wid = t >> 6, lane = t & 63;
    if (lane == 0) { red[wid] = sum; red[4 + wid] = sq; }
    __syncthreads();
    sum = red[0] + red[1] + red[2] + red[3];
    sq  = red[4] + red[5] + red[6] + red[7];
    float mu   = sum * (1.f / D_MODEL);
    float var  = sq * (1.f / D_MODEL) - mu * mu;
    float rstd = rsqrtf(var + LN_EPS);
    int c = t * 4;
    float4 sv = *(const float4*)(sc + c);
    float4 bv = *(const float4*)(bi + c);
    float y0 = sv.x * (v0 - mu) * rstd + bv.x;
    float y1 = sv.y * (v1 - mu) * rstd + bv.y;
    float y2 = sv.z * (v2 - mu) * rstd + bv.z;
    float y3 = sv.w * (v3 - mu) * rstd + bv.w;
    *(float4*)(x + base) = make_float4(y0, y1, y2, y3);
    unsigned long long pk = (unsigned long long)f2bf(y0)
        | ((unsigned long long)f2bf(y1) << 16)
        | ((unsigned long long)f2bf(y2) << 32)
        | ((unsigned long long)f2bf(y3) << 48);
    *(unsigned long long*)(xb + base) = pk;
}

// ---------------- launcher ----------------
extern "C" void kernel_launch(void* const* d_in, const int* in_sizes, int n_in,
                              void* d_out, int out_size, void* d_ws, size_t ws_size,
                              hipStream_t stream)
{
    (void)in_sizes; (void)n_in; (void)out_size;
    const int*   tokens = (const int*)d_in[0];
    const float* emb  = (const float*)d_in[2];
    const float* pose = (const float*)d_in[3];
    const float* Wq = (const float*)d_in[4];
    const float* bq = (const float*)d_in[5];
    const float* Wk = (const float*)d_in[6];
    const float* bk = (const float*)d_in[7];
    const float* Wv = (const float*)d_in[8];
    const float* bv = (const float*)d_in[9];
    const float* Wo = (const float*)d_in[10];
    const float* bo = (const float*)d_in[11];
    const float* n1s = (const float*)d_in[12];
    const float* n1b = (const float*)d_in[13];
    const float* W1 = (const float*)d_in[14];
    const float* b1 = (const float*)d_in[15];
    const float* W2 = (const float*)d_in[16];
    const float* b2 = (const float*)d_in[17];
    const float* n2s = (const float*)d_in[18];
    const float* n2b = (const float*)d_in[19];

    char* w = (char*)d_ws;
    size_t off = 0;
    auto carve = [&](size_t bytes) -> void* {
        void* p = w + off;
        off = (off + bytes + 255) & ~(size_t)255;
        return p;
    };
    float* x   = (float*)carve((size_t)ROWS * D_MODEL * 4);
    float* tmp = (float*)carve((size_t)2 * ROWS * D_MODEL * 4);   // 2 split-K partials
    unsigned short* xb    = (unsigned short*)carve((size_t)ROWS * D_MODEL * 2);
    unsigned short* qkvb  = (unsigned short*)carve((size_t)ROWS * QKV_N * 2);
    unsigned short* cbuf  = (unsigned short*)carve((size_t)ROWS * D_MODEL * 2);
    unsigned short* hbuf  = (unsigned short*)carve((size_t)ROWS * FF_DIM * 2);
    size_t wt_off = off;
    unsigned short* wt = (unsigned short*)carve((size_t)12 * 1048576 * 2);  // fused: 24MB
    float* bqkv = (float*)carve((size_t)NLAYER * QKV_N * 4);
    unsigned short* embb = qkvb;   // tied-head emb aliases dead qkv/ctx/h(+wt) region
    float* tmp1 = tmp + (size_t)ROWS * D_MODEL;
    const bool fused_t = (off <= ws_size);
    if (!fused_t) {
        // fallback: 8MB wt, per-GEMM transposes
        off = wt_off;
        wt = (unsigned short*)carve((size_t)D_MODEL * FF_DIM * 2);
        bqkv = (float*)carve((size_t)NLAYER * QKV_N * 4);
        if (off > ws_size) return;
    }

    bias3_k<<<NLAYER * 3, 256, 0, stream>>>(bq, bk, bv, bqkv);
    embed_k<<<ROWS, 256, 0, stream>>>(tokens, emb, pose, x, xb);

    for (int l = 0; l < NLAYER; l++) {
        const float* Wq_l = Wq + (size_t)l * D_MODEL * D_MODEL;
        const float* Wk_l = Wk + (size_t)l * D_MODEL * D_MODEL;
        const float* Wv_l = Wv + (size_t)l * D_MODEL * D_MODEL;
        const float* Wo_l = Wo + (size_t)l * D_MODEL * D_MODEL;
        const float* W1_l = W1 + (size_t)l * D_MODEL * FF_DIM;
        const float* W2_l = W2 + (size_t)l * FF_DIM * D_MODEL;

        unsigned short* wtQKV = wt;
        unsigned short* wtWo  = fused_t ? wt + (size_t)3 * 1048576 : wt;
        unsigned short* wtW1  = fused_t ? wt + (size_t)4 * 1048576 : wt;
        unsigned short* wtW2  = fused_t ? wt + (size_t)8 * 1048576 : wt;

        if (fused_t) {
            transpose_all<<<3072, 256, 0, stream>>>(Wq_l, Wk_l, Wv_l, Wo_l, W1_l, W2_l, wt);
        } else {
            transpose_cast3<<<dim3(16, 16, 3), 256, 0, stream>>>(Wq_l, Wk_l, Wv_l, wtQKV);
        }
        gemm256<1><<<(QKV_N / 256) * 16, 512, 0, stream>>>(xb, wtQKV, bqkv + (size_t)l * QKV_N, qkvb, QKV_N, D_MODEL);

        attn_fwd<<<dim3(SEQ / 64, BATCH * NHEAD), 256, 0, stream>>>(qkvb, cbuf);

        if (!fused_t) transpose_cast<<<dim3(16, 16), 256, 0, stream>>>(Wo_l, wtWo, D_MODEL, D_MODEL);
        gemm_bt<0><<<dim3(256, 2), 256, 0, stream>>>(cbuf, D_MODEL, wtWo, D_MODEL,
                                                     bo + (size_t)l * D_MODEL, tmp, D_MODEL, D_MODEL / 2);
        ln3<<<ROWS, 256, 0, stream>>>(x, tmp, tmp1, n1s + (size_t)l * D_MODEL, n1b + (size_t)l * D_MODEL, xb);

        if (!fused_t) transpose_cast<<<dim3(64, 16), 256, 0, stream>>>(W1_l, wtW1, D_MODEL, FF_DIM);
        gemm256<2><<<(FF_DIM / 256) * 16, 512, 0, stream>>>(xb, wtW1, b1 + (size_t)l * FF_DIM, hbuf, FF_DIM, D_MODEL);
        if (!fused_t) transpose_cast<<<dim3(16, 64), 256, 0, stream>>>(W2_l, wtW2, FF_DIM, D_MODEL);
        gemm_bt<0><<<dim3(256, 2), 256, 0, stream>>>(hbuf, FF_DIM, wtW2, FF_DIM,
                                                     b2 + (size_t)l * D_MODEL, tmp, D_MODEL, FF_DIM / 2);
        ln3<<<ROWS, 256, 0, stream>>>(x, tmp, tmp1, n2s + (size_t)l * D_MODEL, n2b + (size_t)l * D_MODEL, xb);
    }

    cast_bf<<<(VOCAB * D_MODEL) / 1024, 256, 0, stream>>>(emb, embb, (size_t)VOCAB * D_MODEL);
    gemm256<0><<<(VOCAB / 256) * 16, 512, 0, stream>>>(xb, embb, nullptr, d_out, VOCAB, D_MODEL);
}

// Round 9
// 2271.625 us; speedup vs baseline: 1.2247x; 1.0158x over previous
//
#include <hip/hip_runtime.h>

#define D_MODEL 1024
#define SEQ     1024
#define BATCH   4
#define NHEAD   16
#define HDIM    64
#define FF_DIM  4096
#define NLAYER  8
#define VOCAB   32000
#define ROWS    (BATCH*SEQ)
#define QKV_N   3072
#define LN_EPS  1e-5f

typedef __attribute__((ext_vector_type(4))) float   f32x4;
typedef __attribute__((ext_vector_type(8))) unsigned short u16x8;
typedef __attribute__((ext_vector_type(8))) __bf16  bf16x8;

typedef const unsigned int __attribute__((address_space(1)))* gas_t;
typedef unsigned int __attribute__((address_space(3)))* las_t;

__device__ __forceinline__ void gld16(const void* g, void* l) {
    __builtin_amdgcn_global_load_lds((gas_t)g, (las_t)l, 16, 0, 0);
}

__device__ __forceinline__ unsigned short f2bf(float f) {
    unsigned int u = __builtin_bit_cast(unsigned int, f);
    u += 0x7FFFu + ((u >> 16) & 1u);   // RNE
    return (unsigned short)(u >> 16);
}

__device__ __forceinline__ float bf2f(unsigned short u) {
    return __builtin_bit_cast(float, (unsigned int)u << 16);
}

__device__ __forceinline__ f32x4 mfma32(u16x8 a, u16x8 b, f32x4 c) {
    return __builtin_amdgcn_mfma_f32_16x16x32_bf16(
        __builtin_bit_cast(bf16x8, a), __builtin_bit_cast(bf16x8, b), c, 0, 0, 0);
}

// ---------------- embed: x = emb[tok] + pos ----------------
__global__ __launch_bounds__(256) void embed_k(
    const int* __restrict__ tok, const float* __restrict__ emb,
    const float* __restrict__ pos, float* __restrict__ x,
    unsigned short* __restrict__ xb)
{
    int bs = blockIdx.x;
    int s  = bs & (SEQ - 1);
    int tk = tok[bs];
    int c  = threadIdx.x * 4;
    float4 e = *(const float4*)(emb + (size_t)tk * D_MODEL + c);
    float4 p = *(const float4*)(pos + (size_t)s * D_MODEL + c);
    float y0 = e.x + p.x, y1 = e.y + p.y, y2 = e.z + p.z, y3 = e.w + p.w;
    size_t base = (size_t)bs * D_MODEL + c;
    *(float4*)(x + base) = make_float4(y0, y1, y2, y3);
    unsigned long long pk = (unsigned long long)f2bf(y0)
        | ((unsigned long long)f2bf(y1) << 16)
        | ((unsigned long long)f2bf(y2) << 32)
        | ((unsigned long long)f2bf(y3) << 48);
    *(unsigned long long*)(xb + base) = pk;
}

// ---------------- cast fp32 -> bf16 ----------------
__global__ __launch_bounds__(256) void cast_bf(
    const float* __restrict__ in, unsigned short* __restrict__ out, size_t n)
{
    size_t i = ((size_t)blockIdx.x * 256 + threadIdx.x) * 4;
    if (i >= n) return;
    float4 v = *(const float4*)(in + i);
    unsigned long long pk = (unsigned long long)f2bf(v.x)
        | ((unsigned long long)f2bf(v.y) << 16)
        | ((unsigned long long)f2bf(v.z) << 32)
        | ((unsigned long long)f2bf(v.w) << 48);
    *(unsigned long long*)(out + i) = pk;
}

// ---------------- concat qkv biases ----------------
__global__ __launch_bounds__(256) void bias3_k(
    const float* __restrict__ bq, const float* __restrict__ bk,
    const float* __restrict__ bv, float* __restrict__ out)
{
    int l = blockIdx.x / 3, which = blockIdx.x % 3;
    const float* src = which == 0 ? bq : (which == 1 ? bk : bv);
    int i = threadIdx.x * 4;
    float4 v = *(const float4*)(src + (size_t)l * D_MODEL + i);
    *(float4*)(out + (size_t)l * QKV_N + which * D_MODEL + i) = v;
}

// ---------------- transpose tile body (shared) ----------------
__device__ __forceinline__ void tc_tile(
    const float* __restrict__ W, unsigned short* __restrict__ Wt,
    int K, int N, int n0, int k0)
{
    __shared__ float t[64][65];
    int rr = threadIdx.x >> 4;          // 0..15
    int cc = (threadIdx.x & 15) * 4;    // 0..60
#pragma unroll
    for (int it = 0; it < 4; it++) {
        int r = it * 16 + rr;
        float4 v = *(const float4*)(W + (size_t)(k0 + r) * N + n0 + cc);
        t[r][cc] = v.x; t[r][cc + 1] = v.y; t[r][cc + 2] = v.z; t[r][cc + 3] = v.w;
    }
    __syncthreads();
#pragma unroll
    for (int it = 0; it < 4; it++) {
        int n = it * 16 + rr;
        unsigned long long pk = (unsigned long long)f2bf(t[cc][n])
            | ((unsigned long long)f2bf(t[cc + 1][n]) << 16)
            | ((unsigned long long)f2bf(t[cc + 2][n]) << 32)
            | ((unsigned long long)f2bf(t[cc + 3][n]) << 48);
        *(unsigned long long*)(Wt + (size_t)(n0 + n) * K + k0 + cc) = pk;
    }
}

// ---------------- per-tile transpose kernels (fallback path) ----------------
__global__ __launch_bounds__(256) void transpose_cast(
    const float* __restrict__ W, unsigned short* __restrict__ Wt, int K, int N)
{
    tc_tile(W, Wt, K, N, blockIdx.x * 64, blockIdx.y * 64);
}

__global__ __launch_bounds__(256) void transpose_cast3(
    const float* __restrict__ Wq, const float* __restrict__ Wk,
    const float* __restrict__ Wv, unsigned short* __restrict__ Wt)
{
    const int which = blockIdx.z;
    const float* W = which == 0 ? Wq : (which == 1 ? Wk : Wv);
    tc_tile(W, Wt + (size_t)which * (1024 * 1024), 1024, 1024,
            blockIdx.x * 64, blockIdx.y * 64);
}

// ---------------- fused per-layer transpose: Wq,Wk,Wv,Wo,W1,W2 in ONE launch ----
// wt layout (elems): [0,3M) qkv^T, [3M,4M) Wo^T, [4M,8M) W1^T, [8M,12M) W2^T
__global__ __launch_bounds__(256) void transpose_all(
    const float* __restrict__ Wq, const float* __restrict__ Wk,
    const float* __restrict__ Wv, const float* __restrict__ Wo,
    const float* __restrict__ W1, const float* __restrict__ W2,
    unsigned short* __restrict__ wt)
{
    int b = blockIdx.x;
    const float* W; unsigned short* out; int K, N, t;
    if (b < 768)       { int w = b >> 8; t = b & 255; W = w == 0 ? Wq : (w == 1 ? Wk : Wv);
                         out = wt + (size_t)w * 1048576; K = 1024; N = 1024; }
    else if (b < 1024) { t = b - 768;  W = Wo; out = wt + (size_t)3 * 1048576; K = 1024; N = 1024; }
    else if (b < 2048) { t = b - 1024; W = W1; out = wt + (size_t)4 * 1048576; K = 1024; N = 4096; }
    else               { t = b - 2048; W = W2; out = wt + (size_t)8 * 1048576; K = 4096; N = 1024; }
    int ntx = N >> 6;
    tc_tile(W, out, K, N, (t % ntx) * 64, (t / ntx) * 64);
}

// ---------------- small NT GEMM (m97 128x128) with split-K support ----------------
// MODE 1: bf16 out; MODE 2: relu->bf16 out. Partials (split-K) always bf16.
template<int MODE>
__global__ __launch_bounds__(256, 3) void gemm_bt(
    const unsigned short* __restrict__ A, int lda,
    const unsigned short* __restrict__ Bt, int ldb,
    const float* __restrict__ bias, void* __restrict__ Cout, int N, int Klen)
{
    __shared__ unsigned short As[128 * 32];
    __shared__ unsigned short Bs[128 * 32];
    const int part = blockIdx.y;
    A  += (size_t)part * Klen;
    Bt += (size_t)part * Klen;
    int flat = blockIdx.x;
    const int bm = flat & 31, bn = flat >> 5;
    const int tid  = threadIdx.x;
    const int wid  = tid >> 6, lane = tid & 63;
    const int l16  = lane & 15, lhi = lane >> 4;
    const int wr   = wid >> 1, wc = wid & 1;

    const int srow = wid * 32 + (lane >> 2);
    const int scol = (lane & 3) * 8;
    const unsigned short* gA0 = A  + ((size_t)bm * 128 + srow) * lda + scol;
    const unsigned short* gB0 = Bt + ((size_t)bn * 128 + srow) * ldb + scol;
    unsigned short* lA = As + wid * 32 * 32;
    unsigned short* lB = Bs + wid * 32 * 32;

    f32x4 acc[4][4];
#pragma unroll
    for (int i = 0; i < 4; i++)
#pragma unroll
        for (int j = 0; j < 4; j++) acc[i][j] = (f32x4){0.f, 0.f, 0.f, 0.f};

    for (int k0 = 0; k0 < Klen; k0 += 32) {
        __syncthreads();
        gld16(gA0 + k0,                    lA);
        gld16(gA0 + k0 + 16 * (size_t)lda, lA + 16 * 32);
        gld16(gB0 + k0,                    lB);
        gld16(gB0 + k0 + 16 * (size_t)ldb, lB + 16 * 32);
        __syncthreads();
        u16x8 af[4], bfr[4];
#pragma unroll
        for (int i = 0; i < 4; i++)
            af[i] = *(const u16x8*)(As + (wr * 64 + i * 16 + l16) * 32 + lhi * 8);
#pragma unroll
        for (int i = 0; i < 4; i++)
            bfr[i] = *(const u16x8*)(Bs + (wc * 64 + i * 16 + l16) * 32 + lhi * 8);
#pragma unroll
        for (int mi = 0; mi < 4; mi++)
#pragma unroll
            for (int ni = 0; ni < 4; ni++)
                acc[mi][ni] = mfma32(af[mi], bfr[ni], acc[mi][ni]);
    }

    const size_t pofs = (size_t)part * (size_t)ROWS * N;
#pragma unroll
    for (int mi = 0; mi < 4; mi++)
#pragma unroll
        for (int ni = 0; ni < 4; ni++) {
            int row = bm * 128 + wr * 64 + mi * 16 + lhi * 4;
            int col = bn * 128 + wc * 64 + ni * 16 + l16;
            float bv = (bias && part == 0) ? bias[col] : 0.f;
#pragma unroll
            for (int j = 0; j < 4; j++) {
                float v = acc[mi][ni][j] + bv;
                size_t idx = pofs + (size_t)(row + j) * N + col;
                if constexpr (MODE == 1) {
                    ((unsigned short*)Cout)[idx] = f2bf(v);
                } else {
                    ((unsigned short*)Cout)[idx] = f2bf(v > 0.f ? v : 0.f);
                }
            }
        }
}

// ================= 256x256 8-phase GEMM (R4-best structure + NT store) =================
#define PSYNC() do { __builtin_amdgcn_s_barrier(); \
    asm volatile("s_waitcnt lgkmcnt(0)" ::: "memory"); \
    __builtin_amdgcn_sched_barrier(0); } while (0)
#define PEND() __builtin_amdgcn_s_barrier()
#define VM4()  asm volatile("s_waitcnt vmcnt(4)" ::: "memory")

#define LOADA(reg, half) do { \
    _Pragma("unroll") \
    for (int m_ = 0; m_ < 4; m_++) { \
        aF[m_][0] = *(const u16x8*)((reg) + ((half)*4 + m_) * 2048 + lane0); \
        aF[m_][1] = *(const u16x8*)((reg) + ((half)*4 + m_) * 2048 + lane1); \
    } } while (0)

#define LOADB(reg, np) do { \
    _Pragma("unroll") \
    for (int n_ = 0; n_ < 2; n_++) { \
        bF[(np)*2 + n_][0] = *(const u16x8*)((reg) + ((np)*2 + n_) * 2048 + lane0); \
        bF[(np)*2 + n_][1] = *(const u16x8*)((reg) + ((np)*2 + n_) * 2048 + lane1); \
    } } while (0)

#define MFMA8(ma, np) do { \
    __builtin_amdgcn_s_setprio(1); \
    _Pragma("unroll") \
    for (int m_ = 0; m_ < 4; m_++) \
        _Pragma("unroll") \
        for (int n_ = 0; n_ < 2; n_++) { \
            acc[(ma)+m_][(np)*2+n_] = mfma32(aF[m_][0], bF[(np)*2+n_][0], acc[(ma)+m_][(np)*2+n_]); \
            acc[(ma)+m_][(np)*2+n_] = mfma32(aF[m_][1], bF[(np)*2+n_][1], acc[(ma)+m_][(np)*2+n_]); \
        } \
    __builtin_amdgcn_s_setprio(0); \
} while (0)

template<int MODE, int SWZ>
__global__ __launch_bounds__(512, 2) void gemm256(
    const unsigned short* __restrict__ A, const unsigned short* __restrict__ Bt,
    const float* __restrict__ bias, void* __restrict__ Cout, int N, int K)
{
    __shared__ unsigned short lds[65536] __attribute__((aligned(128)));
    const int tid = threadIdx.x, wid = tid >> 6, lane = tid & 63;
    const int l16 = lane & 15, lhi = lane >> 4;
    const int wr = wid >> 2, wc = wid & 3;

    int flat = blockIdx.x;
    if constexpr (SWZ) {
        int cpx = gridDim.x >> 3; flat = (flat & 7) * cpx + (flat >> 3);
    }
    const int bm = flat & 15, bn = flat >> 4;
    const int NT = K >> 6;

    const int srowL = tid >> 3;                                      // 0..63
    const int scolb = ((tid & 7) << 4) ^ (((tid >> 3) & 7) << 4);    // bytes (pre-swz src)
    const unsigned short* baseA = A  + (size_t)(bm * 256 + srowL) * K + (scolb >> 1);
    const unsigned short* baseB = Bt + (size_t)(bn * 256 + srowL) * K + (scolb >> 1);
    unsigned short* dst0 = lds + wid * 512;   // wave-uniform; HW adds lane*16B

    auto stage = [&](int isB, int tile, int h) {   // one half-tile = 2 gld16
        const unsigned short* s = (isB ? baseB : baseA) + (size_t)(h * 128) * K + (size_t)tile * 64;
        unsigned short* d = dst0 + (tile & 1) * 32768 + isB * 16384 + h * 8192;
        gld16(s, d);
        gld16(s + (size_t)64 * K, d + 4096);
    };

    const int lswz  = (l16 & 7) << 4;
    const int lane0 = ((lhi * 16) ^ lswz) + l16 * 128;
    const int lane1 = ((64 + lhi * 16) ^ lswz) + l16 * 128;

    const char* aR0 = (const char*)lds + wr * 16384;
    const char* bR0 = (const char*)lds + 32768 + (wc >> 1) * 16384 + (wc & 1) * 8192;
    const char* aR1 = aR0 + 65536;
    const char* bR1 = bR0 + 65536;

    f32x4 acc[8][4];
#pragma unroll
    for (int i = 0; i < 8; i++)
#pragma unroll
        for (int j = 0; j < 4; j++) acc[i][j] = (f32x4){0.f, 0.f, 0.f, 0.f};
    u16x8 aF[4][2], bF[4][2];

    // prologue: B(0),A(0),B(1); leave B(1)'s 4 loads in flight
    stage(1, 0, 0); stage(1, 0, 1);
    stage(0, 0, 0); stage(0, 0, 1);
    stage(1, 1, 0); stage(1, 1, 1);
    VM4();
    __builtin_amdgcn_s_barrier();

    for (int t = 0; t < NT; t += 2) {
        const bool more = (t + 2) < NT;
        // ---- K-tile t (buf0) ----
        LOADA(aR0, 0); LOADB(bR0, 0); stage(0, t + 1, 0);
        PSYNC(); MFMA8(0, 0); PEND();
        LOADB(bR0, 1);                stage(0, t + 1, 1);
        PSYNC(); MFMA8(0, 1); PEND();
        LOADA(aR0, 1);                if (more) stage(1, t + 2, 0);
        PSYNC(); MFMA8(4, 0); PEND();
        if (more) { stage(1, t + 2, 1); VM4(); }
        else      { asm volatile("s_waitcnt vmcnt(0)" ::: "memory"); }
        PSYNC(); MFMA8(4, 1); PEND();
        // ---- K-tile t+1 (buf1) ----
        LOADA(aR1, 0); LOADB(bR1, 0); if (more) stage(0, t + 2, 0);
        PSYNC(); MFMA8(0, 0); PEND();
        LOADB(bR1, 1);                if (more) stage(0, t + 2, 1);
        PSYNC(); MFMA8(0, 1); PEND();
        LOADA(aR1, 1);                if (more) stage(1, t + 3, 0);
        PSYNC(); MFMA8(4, 0); PEND();
        if (more) { stage(1, t + 3, 1); VM4(); }
        PSYNC(); MFMA8(4, 1); PEND();
    }

#pragma unroll
    for (int mi = 0; mi < 8; mi++)
#pragma unroll
        for (int ni = 0; ni < 4; ni++) {
            int row = bm * 256 + wr * 128 + mi * 16 + lhi * 4;
            int col = bn * 256 + wc * 64 + ni * 16 + l16;
            float bv = bias ? bias[col] : 0.f;
#pragma unroll
            for (int j = 0; j < 4; j++) {
                float v = acc[mi][ni][j] + bv;
                size_t idx = (size_t)(row + j) * N + col;
                if constexpr (MODE == 0) {
                    __builtin_nontemporal_store(v, (float*)Cout + idx);
                } else if constexpr (MODE == 1) {
                    ((unsigned short*)Cout)[idx] = f2bf(v);
                } else {
                    ((unsigned short*)Cout)[idx] = f2bf(v > 0.f ? v : 0.f);
                }
            }
        }
}

// ---------------- flash attention (causal), 64 q-rows/block, fused qkv input ----------------
__global__ __launch_bounds__(256, 3) void attn_fwd(
    const unsigned short* __restrict__ qkv, unsigned short* __restrict__ ctxb)
{
    __shared__ unsigned short Ks[64 * 72];
    __shared__ unsigned short Vs[64 * 72];   // transposed: Vs[d][kv]
    __shared__ unsigned short Ps[4 * 16 * 72];
    const int tid = threadIdx.x;
    const int wid = tid >> 6, lane = tid & 63;
    const int l16 = lane & 15, lhi = lane >> 4;
    const int bh  = blockIdx.y, b = bh >> 4, h = bh & 15;
    const int q0  = blockIdx.x * 64;
    const size_t rowbase = (size_t)b * SEQ;

    const int qrow = q0 + wid * 16 + l16;
    const unsigned short* qp = qkv + (rowbase + qrow) * QKV_N + h * HDIM + lhi * 8;
    u16x8 qf0 = *(const u16x8*)qp;
    u16x8 qf1 = *(const u16x8*)(qp + 32);

    f32x4 oa[4];
    float mj[4], lj[4];
#pragma unroll
    for (int i = 0; i < 4; i++) {
        oa[i] = (f32x4){0.f, 0.f, 0.f, 0.f};
        mj[i] = -1e30f; lj[i] = 0.f;
    }

    const int ntiles = blockIdx.x + 1;
    for (int kt = 0; kt < ntiles; ++kt) {
        const int kv0 = kt * 64;
        __syncthreads();
        // K staging: vector writes, row-major
#pragma unroll
        for (int it = 0; it < 2; ++it) {
            int e = it * 256 + tid;
            int r = e >> 3, d0 = (e & 7) * 8;
            size_t goff = (rowbase + kv0 + r) * QKV_N + D_MODEL + h * HDIM + d0;
            u16x8 kk = *(const u16x8*)(qkv + goff);
            *(u16x8*)(&Ks[r * 72 + d0]) = kk;
        }
        // V staging: 128 threads x 4 rows -> transposed via register repack
        if (tid < 128) {
            int r0 = (tid & 15) * 4, d0v = (tid >> 4) * 8;
            const unsigned short* vp = qkv + (rowbase + kv0 + r0) * QKV_N
                                       + 2 * D_MODEL + h * HDIM + d0v;
            u16x8 w0 = *(const u16x8*)vp;
            u16x8 w1 = *(const u16x8*)(vp + QKV_N);
            u16x8 w2 = *(const u16x8*)(vp + 2 * QKV_N);
            u16x8 w3 = *(const u16x8*)(vp + 3 * QKV_N);
#pragma unroll
            for (int j = 0; j < 8; j++) {
                unsigned long long pk = (unsigned long long)w0[j]
                    | ((unsigned long long)w1[j] << 16)
                    | ((unsigned long long)w2[j] << 32)
                    | ((unsigned long long)w3[j] << 48);
                *(unsigned long long*)(&Vs[(d0v + j) * 72 + r0]) = pk;
            }
        }
        __syncthreads();

        f32x4 sa[4];
#pragma unroll
        for (int ni = 0; ni < 4; ni++) {
            f32x4 z = (f32x4){0.f, 0.f, 0.f, 0.f};
            u16x8 k0f = *(const u16x8*)(&Ks[(ni * 16 + l16) * 72 + lhi * 8]);
            u16x8 k1f = *(const u16x8*)(&Ks[(ni * 16 + l16) * 72 + 32 + lhi * 8]);
            z = mfma32(qf0, k0f, z);
            z = mfma32(qf1, k1f, z);
            sa[ni] = z;
        }
        float tm[4] = {-1e30f, -1e30f, -1e30f, -1e30f};
#pragma unroll
        for (int ni = 0; ni < 4; ni++)
#pragma unroll
            for (int j = 0; j < 4; j++) {
                float v = sa[ni][j] * 0.125f;
                int row = q0 + wid * 16 + lhi * 4 + j;
                int col = kv0 + ni * 16 + l16;
                if (col > row) v = -1e30f;
                sa[ni][j] = v;
                tm[j] = fmaxf(tm[j], v);
            }
#pragma unroll
        for (int j = 0; j < 4; j++) {
#pragma unroll
            for (int off = 1; off < 16; off <<= 1)
                tm[j] = fmaxf(tm[j], __shfl_xor(tm[j], off));
        }
        float al[4], rs[4] = {0.f, 0.f, 0.f, 0.f};
#pragma unroll
        for (int j = 0; j < 4; j++) {
            float mn = fmaxf(mj[j], tm[j]);
            al[j] = __expf(mj[j] - mn);
            mj[j] = mn;
        }
#pragma unroll
        for (int ni = 0; ni < 4; ni++)
#pragma unroll
            for (int j = 0; j < 4; j++) {
                float p = __expf(sa[ni][j] - mj[j]);
                rs[j] += p;
                Ps[wid * 1152 + (lhi * 4 + j) * 72 + ni * 16 + l16] = f2bf(p);
            }
#pragma unroll
        for (int j = 0; j < 4; j++) {
#pragma unroll
            for (int off = 1; off < 16; off <<= 1)
                rs[j] += __shfl_xor(rs[j], off);
            lj[j] = lj[j] * al[j] + rs[j];
        }
#pragma unroll
        for (int di = 0; di < 4; di++)
#pragma unroll
            for (int j = 0; j < 4; j++) oa[di][j] *= al[j];
#pragma unroll
        for (int di = 0; di < 4; di++) {
#pragma unroll
            for (int kc = 0; kc < 2; kc++) {
                u16x8 pf = *(const u16x8*)(&Ps[wid * 1152 + l16 * 72 + kc * 32 + lhi * 8]);
                u16x8 vf = *(const u16x8*)(&Vs[(di * 16 + l16) * 72 + kc * 32 + lhi * 8]);
                oa[di] = mfma32(pf, vf, oa[di]);
            }
        }
    }
#pragma unroll
    for (int di = 0; di < 4; di++)
#pragma unroll
        for (int j = 0; j < 4; j++) {
            int row = q0 + wid * 16 + lhi * 4 + j;
            ctxb[(rowbase + row) * D_MODEL + h * HDIM + di * 16 + l16] =
                f2bf(oa[di][j] / lj[j]);
        }
}

// ---------------- fused residual(x + p0 + p1) + LayerNorm (bf16 partials) ----------------
__global__ __launch_bounds__(256) void ln3(
    float* __restrict__ x, const unsigned short* __restrict__ p0,
    const unsigned short* __restrict__ p1,
    const float* __restrict__ sc, const float* __restrict__ bi,
    unsigned short* __restrict__ xb)
{
    const int row = blockIdx.x;
    const int t = threadIdx.x;
    const size_t base = (size_t)row * D_MODEL + t * 4;
    float4 xv = *(const float4*)(x + base);
    ushort4 au = *(const ushort4*)(p0 + base);
    ushort4 bu = *(const ushort4*)(p1 + base);
    float v0 = xv.x + bf2f(au.x) + bf2f(bu.x);
    float v1 = xv.y + bf2f(au.y) + bf2f(bu.y);
    float v2 = xv.z + bf2f(au.z) + bf2f(bu.z);
    float v3 = xv.w + bf2f(au.w) + bf2f(bu.w);
    float sum = v0 + v1 + v2 + v3;
    float sq  = v0 * v0 + v1 * v1 + v2 * v2 + v3 * v3;
#pragma unroll
    for (int off = 1; off < 64; off <<= 1) {
        sum += __shfl_xor(sum, off);
        sq  += __shfl_xor(sq, off);
    }
    __shared__ float red[8];
    int wid = t >> 6, lane = t & 63;
    if (lane == 0) { red[wid] = sum; red[4 + wid] = sq; }
    __syncthreads();
    sum = red[0] + red[1] + red[2] + red[3];
    sq  = red[4] + red[5] + red[6] + red[7];
    float mu   = sum * (1.f / D_MODEL);
    float var  = sq * (1.f / D_MODEL) - mu * mu;
    float rstd = rsqrtf(var + LN_EPS);
    int c = t * 4;
    float4 sv = *(const float4*)(sc + c);
    float4 bv = *(const float4*)(bi + c);
    float y0 = sv.x * (v0 - mu) * rstd + bv.x;
    float y1 = sv.y * (v1 - mu) * rstd + bv.y;
    float y2 = sv.z * (v2 - mu) * rstd + bv.z;
    float y3 = sv.w * (v3 - mu) * rstd + bv.w;
    *(float4*)(x + base) = make_float4(y0, y1, y2, y3);
    unsigned long long pk = (unsigned long long)f2bf(y0)
        | ((unsigned long long)f2bf(y1) << 16)
        | ((unsigned long long)f2bf(y2) << 32)
        | ((unsigned long long)f2bf(y3) << 48);
    *(unsigned long long*)(xb + base) = pk;
}

// ---------------- launcher ----------------
extern "C" void kernel_launch(void* const* d_in, const int* in_sizes, int n_in,
                              void* d_out, int out_size, void* d_ws, size_t ws_size,
                              hipStream_t stream)
{
    (void)in_sizes; (void)n_in; (void)out_size;
    const int*   tokens = (const int*)d_in[0];
    const float* emb  = (const float*)d_in[2];
    const float* pose = (const float*)d_in[3];
    const float* Wq = (const float*)d_in[4];
    const float* bq = (const float*)d_in[5];
    const float* Wk = (const float*)d_in[6];
    const float* bk = (const float*)d_in[7];
    const float* Wv = (const float*)d_in[8];
    const float* bv = (const float*)d_in[9];
    const float* Wo = (const float*)d_in[10];
    const float* bo = (const float*)d_in[11];
    const float* n1s = (const float*)d_in[12];
    const float* n1b = (const float*)d_in[13];
    const float* W1 = (const float*)d_in[14];
    const float* b1 = (const float*)d_in[15];
    const float* W2 = (const float*)d_in[16];
    const float* b2 = (const float*)d_in[17];
    const float* n2s = (const float*)d_in[18];
    const float* n2b = (const float*)d_in[19];

    char* w = (char*)d_ws;
    size_t off = 0;
    auto carve = [&](size_t bytes) -> void* {
        void* p = w + off;
        off = (off + bytes + 255) & ~(size_t)255;
        return p;
    };
    float* x = (float*)carve((size_t)ROWS * D_MODEL * 4);
    unsigned short* tmp = (unsigned short*)carve((size_t)2 * ROWS * D_MODEL * 2);  // bf16 partials
    unsigned short* xb    = (unsigned short*)carve((size_t)ROWS * D_MODEL * 2);
    unsigned short* qkvb  = (unsigned short*)carve((size_t)ROWS * QKV_N * 2);
    unsigned short* cbuf  = (unsigned short*)carve((size_t)ROWS * D_MODEL * 2);
    unsigned short* hbuf  = (unsigned short*)carve((size_t)ROWS * FF_DIM * 2);
    size_t wt_off = off;
    unsigned short* wt = (unsigned short*)carve((size_t)12 * 1048576 * 2);  // fused: 24MB
    float* bqkv = (float*)carve((size_t)NLAYER * QKV_N * 4);
    unsigned short* embb = qkvb;   // tied-head emb aliases dead qkv/ctx/h region
    unsigned short* tmp1 = tmp + (size_t)ROWS * D_MODEL;
    const bool fused_t = (off <= ws_size);
    if (!fused_t) {
        off = wt_off;
        wt = (unsigned short*)carve((size_t)D_MODEL * FF_DIM * 2);
        bqkv = (float*)carve((size_t)NLAYER * QKV_N * 4);
        if (off > ws_size) return;
    }

    bias3_k<<<NLAYER * 3, 256, 0, stream>>>(bq, bk, bv, bqkv);
    embed_k<<<ROWS, 256, 0, stream>>>(tokens, emb, pose, x, xb);

    for (int l = 0; l < NLAYER; l++) {
        const float* Wq_l = Wq + (size_t)l * D_MODEL * D_MODEL;
        const float* Wk_l = Wk + (size_t)l * D_MODEL * D_MODEL;
        const float* Wv_l = Wv + (size_t)l * D_MODEL * D_MODEL;
        const float* Wo_l = Wo + (size_t)l * D_MODEL * D_MODEL;
        const float* W1_l = W1 + (size_t)l * D_MODEL * FF_DIM;
        const float* W2_l = W2 + (size_t)l * FF_DIM * D_MODEL;

        unsigned short* wtQKV = wt;
        unsigned short* wtWo  = fused_t ? wt + (size_t)3 * 1048576 : wt;
        unsigned short* wtW1  = fused_t ? wt + (size_t)4 * 1048576 : wt;
        unsigned short* wtW2  = fused_t ? wt + (size_t)8 * 1048576 : wt;

        if (fused_t) {
            transpose_all<<<3072, 256, 0, stream>>>(Wq_l, Wk_l, Wv_l, Wo_l, W1_l, W2_l, wt);
        } else {
            transpose_cast3<<<dim3(16, 16, 3), 256, 0, stream>>>(Wq_l, Wk_l, Wv_l, wtQKV);
        }
        // QKV: 128x128 kernel, 768 blocks (3 blocks/CU) vs gemm256's 192
        gemm_bt<1><<<dim3(768, 1), 256, 0, stream>>>(xb, D_MODEL, wtQKV, D_MODEL,
                                                     bqkv + (size_t)l * QKV_N, qkvb, QKV_N, D_MODEL);

        attn_fwd<<<dim3(SEQ / 64, BATCH * NHEAD), 256, 0, stream>>>(qkvb, cbuf);

        if (!fused_t) transpose_cast<<<dim3(16, 16), 256, 0, stream>>>(Wo_l, wtWo, D_MODEL, D_MODEL);
        gemm_bt<1><<<dim3(256, 2), 256, 0, stream>>>(cbuf, D_MODEL, wtWo, D_MODEL,
                                                     bo + (size_t)l * D_MODEL, tmp, D_MODEL, D_MODEL / 2);
        ln3<<<ROWS, 256, 0, stream>>>(x, tmp, tmp1, n1s + (size_t)l * D_MODEL, n1b + (size_t)l * D_MODEL, xb);

        if (!fused_t) transpose_cast<<<dim3(64, 16), 256, 0, stream>>>(W1_l, wtW1, D_MODEL, FF_DIM);
        gemm256<2, 1><<<(FF_DIM / 256) * 16, 512, 0, stream>>>(xb, wtW1, b1 + (size_t)l * FF_DIM, hbuf, FF_DIM, D_MODEL);
        if (!fused_t) transpose_cast<<<dim3(16, 64), 256, 0, stream>>>(W2_l, wtW2, FF_DIM, D_MODEL);
        gemm_bt<1><<<dim3(256, 2), 256, 0, stream>>>(hbuf, FF_DIM, wtW2, FF_DIM,
                                                     b2 + (size_t)l * D_MODEL, tmp, D_MODEL, FF_DIM / 2);
        ln3<<<ROWS, 256, 0, stream>>>(x, tmp, tmp1, n2s + (size_t)l * D_MODEL, n2b + (size_t)l * D_MODEL, xb);
    }

    cast_bf<<<(VOCAB * D_MODEL) / 1024, 256, 0, stream>>>(emb, embb, (size_t)VOCAB * D_MODEL);
    // head: NO XCD swizzle (SWZ=0) — bm-fastest order shares B panels via L3
    gemm256<0, 0><<<(VOCAB / 256) * 16, 512, 0, stream>>>(xb, embb, nullptr, d_out, VOCAB, D_MODEL);
}

// Round 10
// 2159.437 us; speedup vs baseline: 1.2883x; 1.0520x over previous
//
#include <hip/hip_runtime.h>

#define D_MODEL 1024
#define SEQ     1024
#define BATCH   4
#define NHEAD   16
#define HDIM    64
#define FF_DIM  4096
#define NLAYER  8
#define VOCAB   32000
#define ROWS    (BATCH*SEQ)
#define QKV_N   3072
#define LN_EPS  1e-5f

typedef __attribute__((ext_vector_type(4))) float   f32x4;
typedef __attribute__((ext_vector_type(8))) unsigned short u16x8;
typedef __attribute__((ext_vector_type(8))) __bf16  bf16x8;

typedef const unsigned int __attribute__((address_space(1)))* gas_t;
typedef unsigned int __attribute__((address_space(3)))* las_t;

__device__ __forceinline__ void gld16(const void* g, void* l) {
    __builtin_amdgcn_global_load_lds((gas_t)g, (las_t)l, 16, 0, 0);
}

__device__ __forceinline__ unsigned short f2bf(float f) {
    unsigned int u = __builtin_bit_cast(unsigned int, f);
    u += 0x7FFFu + ((u >> 16) & 1u);   // RNE
    return (unsigned short)(u >> 16);
}

__device__ __forceinline__ float bf2f(unsigned short u) {
    return __builtin_bit_cast(float, (unsigned int)u << 16);
}

__device__ __forceinline__ f32x4 mfma32(u16x8 a, u16x8 b, f32x4 c) {
    return __builtin_amdgcn_mfma_f32_16x16x32_bf16(
        __builtin_bit_cast(bf16x8, a), __builtin_bit_cast(bf16x8, b), c, 0, 0, 0);
}

// ---------------- embed: x = emb[tok] + pos ----------------
__global__ __launch_bounds__(256) void embed_k(
    const int* __restrict__ tok, const float* __restrict__ emb,
    const float* __restrict__ pos, float* __restrict__ x,
    unsigned short* __restrict__ xb)
{
    int bs = blockIdx.x;
    int s  = bs & (SEQ - 1);
    int tk = tok[bs];
    int c  = threadIdx.x * 4;
    float4 e = *(const float4*)(emb + (size_t)tk * D_MODEL + c);
    float4 p = *(const float4*)(pos + (size_t)s * D_MODEL + c);
    float y0 = e.x + p.x, y1 = e.y + p.y, y2 = e.z + p.z, y3 = e.w + p.w;
    size_t base = (size_t)bs * D_MODEL + c;
    *(float4*)(x + base) = make_float4(y0, y1, y2, y3);
    unsigned long long pk = (unsigned long long)f2bf(y0)
        | ((unsigned long long)f2bf(y1) << 16)
        | ((unsigned long long)f2bf(y2) << 32)
        | ((unsigned long long)f2bf(y3) << 48);
    *(unsigned long long*)(xb + base) = pk;
}

// ---------------- cast fp32 -> bf16 ----------------
__global__ __launch_bounds__(256) void cast_bf(
    const float* __restrict__ in, unsigned short* __restrict__ out, size_t n)
{
    size_t i = ((size_t)blockIdx.x * 256 + threadIdx.x) * 4;
    if (i >= n) return;
    float4 v = *(const float4*)(in + i);
    unsigned long long pk = (unsigned long long)f2bf(v.x)
        | ((unsigned long long)f2bf(v.y) << 16)
        | ((unsigned long long)f2bf(v.z) << 32)
        | ((unsigned long long)f2bf(v.w) << 48);
    *(unsigned long long*)(out + i) = pk;
}

// ---------------- concat qkv biases ----------------
__global__ __launch_bounds__(256) void bias3_k(
    const float* __restrict__ bq, const float* __restrict__ bk,
    const float* __restrict__ bv, float* __restrict__ out)
{
    int l = blockIdx.x / 3, which = blockIdx.x % 3;
    const float* src = which == 0 ? bq : (which == 1 ? bk : bv);
    int i = threadIdx.x * 4;
    float4 v = *(const float4*)(src + (size_t)l * D_MODEL + i);
    *(float4*)(out + (size_t)l * QKV_N + which * D_MODEL + i) = v;
}

// ---------------- transpose tile body (shared) ----------------
__device__ __forceinline__ void tc_tile(
    const float* __restrict__ W, unsigned short* __restrict__ Wt,
    int K, int N, int n0, int k0)
{
    __shared__ float t[64][65];
    int rr = threadIdx.x >> 4;          // 0..15
    int cc = (threadIdx.x & 15) * 4;    // 0..60
#pragma unroll
    for (int it = 0; it < 4; it++) {
        int r = it * 16 + rr;
        float4 v = *(const float4*)(W + (size_t)(k0 + r) * N + n0 + cc);
        t[r][cc] = v.x; t[r][cc + 1] = v.y; t[r][cc + 2] = v.z; t[r][cc + 3] = v.w;
    }
    __syncthreads();
#pragma unroll
    for (int it = 0; it < 4; it++) {
        int n = it * 16 + rr;
        unsigned long long pk = (unsigned long long)f2bf(t[cc][n])
            | ((unsigned long long)f2bf(t[cc + 1][n]) << 16)
            | ((unsigned long long)f2bf(t[cc + 2][n]) << 32)
            | ((unsigned long long)f2bf(t[cc + 3][n]) << 48);
        *(unsigned long long*)(Wt + (size_t)(n0 + n) * K + k0 + cc) = pk;
    }
}

// ---------------- per-tile transpose kernels (fallback path) ----------------
__global__ __launch_bounds__(256) void transpose_cast(
    const float* __restrict__ W, unsigned short* __restrict__ Wt, int K, int N)
{
    tc_tile(W, Wt, K, N, blockIdx.x * 64, blockIdx.y * 64);
}

__global__ __launch_bounds__(256) void transpose_cast3(
    const float* __restrict__ Wq, const float* __restrict__ Wk,
    const float* __restrict__ Wv, unsigned short* __restrict__ Wt)
{
    const int which = blockIdx.z;
    const float* W = which == 0 ? Wq : (which == 1 ? Wk : Wv);
    tc_tile(W, Wt + (size_t)which * (1024 * 1024), 1024, 1024,
            blockIdx.x * 64, blockIdx.y * 64);
}

// ---------------- fused per-layer transpose: Wq,Wk,Wv,Wo,W1,W2 in ONE launch ----
// wt layout (elems): [0,3M) qkv^T, [3M,4M) Wo^T, [4M,8M) W1^T, [8M,12M) W2^T
__global__ __launch_bounds__(256) void transpose_all(
    const float* __restrict__ Wq, const float* __restrict__ Wk,
    const float* __restrict__ Wv, const float* __restrict__ Wo,
    const float* __restrict__ W1, const float* __restrict__ W2,
    unsigned short* __restrict__ wt)
{
    int b = blockIdx.x;
    const float* W; unsigned short* out; int K, N, t;
    if (b < 768)       { int w = b >> 8; t = b & 255; W = w == 0 ? Wq : (w == 1 ? Wk : Wv);
                         out = wt + (size_t)w * 1048576; K = 1024; N = 1024; }
    else if (b < 1024) { t = b - 768;  W = Wo; out = wt + (size_t)3 * 1048576; K = 1024; N = 1024; }
    else if (b < 2048) { t = b - 1024; W = W1; out = wt + (size_t)4 * 1048576; K = 1024; N = 4096; }
    else               { t = b - 2048; W = W2; out = wt + (size_t)8 * 1048576; K = 4096; N = 1024; }
    int ntx = N >> 6;
    tc_tile(W, out, K, N, (t % ntx) * 64, (t / ntx) * 64);
}

// ---------------- small NT GEMM (m97 128x128) with split-K support ----------------
// MODE 1: bf16 out; MODE 2: relu->bf16 out.
template<int MODE>
__global__ __launch_bounds__(256, 3) void gemm_bt(
    const unsigned short* __restrict__ A, int lda,
    const unsigned short* __restrict__ Bt, int ldb,
    const float* __restrict__ bias, void* __restrict__ Cout, int N, int Klen)
{
    __shared__ unsigned short As[128 * 32];
    __shared__ unsigned short Bs[128 * 32];
    const int part = blockIdx.y;
    A  += (size_t)part * Klen;
    Bt += (size_t)part * Klen;
    int flat = blockIdx.x;
    const int bm = flat & 31, bn = flat >> 5;
    const int tid  = threadIdx.x;
    const int wid  = tid >> 6, lane = tid & 63;
    const int l16  = lane & 15, lhi = lane >> 4;
    const int wr   = wid >> 1, wc = wid & 1;

    const int srow = wid * 32 + (lane >> 2);
    const int scol = (lane & 3) * 8;
    const unsigned short* gA0 = A  + ((size_t)bm * 128 + srow) * lda + scol;
    const unsigned short* gB0 = Bt + ((size_t)bn * 128 + srow) * ldb + scol;
    unsigned short* lA = As + wid * 32 * 32;
    unsigned short* lB = Bs + wid * 32 * 32;

    f32x4 acc[4][4];
#pragma unroll
    for (int i = 0; i < 4; i++)
#pragma unroll
        for (int j = 0; j < 4; j++) acc[i][j] = (f32x4){0.f, 0.f, 0.f, 0.f};

    for (int k0 = 0; k0 < Klen; k0 += 32) {
        __syncthreads();
        gld16(gA0 + k0,                    lA);
        gld16(gA0 + k0 + 16 * (size_t)lda, lA + 16 * 32);
        gld16(gB0 + k0,                    lB);
        gld16(gB0 + k0 + 16 * (size_t)ldb, lB + 16 * 32);
        __syncthreads();
        u16x8 af[4], bfr[4];
#pragma unroll
        for (int i = 0; i < 4; i++)
            af[i] = *(const u16x8*)(As + (wr * 64 + i * 16 + l16) * 32 + lhi * 8);
#pragma unroll
        for (int i = 0; i < 4; i++)
            bfr[i] = *(const u16x8*)(Bs + (wc * 64 + i * 16 + l16) * 32 + lhi * 8);
#pragma unroll
        for (int mi = 0; mi < 4; mi++)
#pragma unroll
            for (int ni = 0; ni < 4; ni++)
                acc[mi][ni] = mfma32(af[mi], bfr[ni], acc[mi][ni]);
    }

    const size_t pofs = (size_t)part * (size_t)ROWS * N;
#pragma unroll
    for (int mi = 0; mi < 4; mi++)
#pragma unroll
        for (int ni = 0; ni < 4; ni++) {
            int row = bm * 128 + wr * 64 + mi * 16 + lhi * 4;
            int col = bn * 128 + wc * 64 + ni * 16 + l16;
            float bv = (bias && part == 0) ? bias[col] : 0.f;
#pragma unroll
            for (int j = 0; j < 4; j++) {
                float v = acc[mi][ni][j] + bv;
                size_t idx = pofs + (size_t)(row + j) * N + col;
                if constexpr (MODE == 1) {
                    ((unsigned short*)Cout)[idx] = f2bf(v);
                } else {
                    ((unsigned short*)Cout)[idx] = f2bf(v > 0.f ? v : 0.f);
                }
            }
        }
}

// ================= 256x256 8-phase GEMM (R4-best structure + NT store) =================
#define PSYNC() do { __builtin_amdgcn_s_barrier(); \
    asm volatile("s_waitcnt lgkmcnt(0)" ::: "memory"); \
    __builtin_amdgcn_sched_barrier(0); } while (0)
#define PEND() __builtin_amdgcn_s_barrier()
#define VM4()  asm volatile("s_waitcnt vmcnt(4)" ::: "memory")

#define LOADA(reg, half) do { \
    _Pragma("unroll") \
    for (int m_ = 0; m_ < 4; m_++) { \
        aF[m_][0] = *(const u16x8*)((reg) + ((half)*4 + m_) * 2048 + lane0); \
        aF[m_][1] = *(const u16x8*)((reg) + ((half)*4 + m_) * 2048 + lane1); \
    } } while (0)

#define LOADB(reg, np) do { \
    _Pragma("unroll") \
    for (int n_ = 0; n_ < 2; n_++) { \
        bF[(np)*2 + n_][0] = *(const u16x8*)((reg) + ((np)*2 + n_) * 2048 + lane0); \
        bF[(np)*2 + n_][1] = *(const u16x8*)((reg) + ((np)*2 + n_) * 2048 + lane1); \
    } } while (0)

#define MFMA8(ma, np) do { \
    __builtin_amdgcn_s_setprio(1); \
    _Pragma("unroll") \
    for (int m_ = 0; m_ < 4; m_++) \
        _Pragma("unroll") \
        for (int n_ = 0; n_ < 2; n_++) { \
            acc[(ma)+m_][(np)*2+n_] = mfma32(aF[m_][0], bF[(np)*2+n_][0], acc[(ma)+m_][(np)*2+n_]); \
            acc[(ma)+m_][(np)*2+n_] = mfma32(aF[m_][1], bF[(np)*2+n_][1], acc[(ma)+m_][(np)*2+n_]); \
        } \
    __builtin_amdgcn_s_setprio(0); \
} while (0)

template<int MODE, int SWZ>
__global__ __launch_bounds__(512, 2) void gemm256(
    const unsigned short* __restrict__ A, const unsigned short* __restrict__ Bt,
    const float* __restrict__ bias, void* __restrict__ Cout, int N, int K)
{
    __shared__ unsigned short lds[65536] __attribute__((aligned(128)));
    const int tid = threadIdx.x, wid = tid >> 6, lane = tid & 63;
    const int l16 = lane & 15, lhi = lane >> 4;
    const int wr = wid >> 2, wc = wid & 3;

    int flat = blockIdx.x;
    if constexpr (SWZ) {
        int cpx = gridDim.x >> 3; flat = (flat & 7) * cpx + (flat >> 3);
    }
    const int bm = flat & 15, bn = flat >> 4;
    const int NT = K >> 6;

    const int srowL = tid >> 3;                                      // 0..63
    const int scolb = ((tid & 7) << 4) ^ (((tid >> 3) & 7) << 4);    // bytes (pre-swz src)
    const unsigned short* baseA = A  + (size_t)(bm * 256 + srowL) * K + (scolb >> 1);
    const unsigned short* baseB = Bt + (size_t)(bn * 256 + srowL) * K + (scolb >> 1);
    unsigned short* dst0 = lds + wid * 512;   // wave-uniform; HW adds lane*16B

    auto stage = [&](int isB, int tile, int h) {   // one half-tile = 2 gld16
        const unsigned short* s = (isB ? baseB : baseA) + (size_t)(h * 128) * K + (size_t)tile * 64;
        unsigned short* d = dst0 + (tile & 1) * 32768 + isB * 16384 + h * 8192;
        gld16(s, d);
        gld16(s + (size_t)64 * K, d + 4096);
    };

    const int lswz  = (l16 & 7) << 4;
    const int lane0 = ((lhi * 16) ^ lswz) + l16 * 128;
    const int lane1 = ((64 + lhi * 16) ^ lswz) + l16 * 128;

    const char* aR0 = (const char*)lds + wr * 16384;
    const char* bR0 = (const char*)lds + 32768 + (wc >> 1) * 16384 + (wc & 1) * 8192;
    const char* aR1 = aR0 + 65536;
    const char* bR1 = bR0 + 65536;

    f32x4 acc[8][4];
#pragma unroll
    for (int i = 0; i < 8; i++)
#pragma unroll
        for (int j = 0; j < 4; j++) acc[i][j] = (f32x4){0.f, 0.f, 0.f, 0.f};
    u16x8 aF[4][2], bF[4][2];

    // prologue: B(0),A(0),B(1); leave B(1)'s 4 loads in flight
    stage(1, 0, 0); stage(1, 0, 1);
    stage(0, 0, 0); stage(0, 0, 1);
    stage(1, 1, 0); stage(1, 1, 1);
    VM4();
    __builtin_amdgcn_s_barrier();

    for (int t = 0; t < NT; t += 2) {
        const bool more = (t + 2) < NT;
        // ---- K-tile t (buf0) ----
        LOADA(aR0, 0); LOADB(bR0, 0); stage(0, t + 1, 0);
        PSYNC(); MFMA8(0, 0); PEND();
        LOADB(bR0, 1);                stage(0, t + 1, 1);
        PSYNC(); MFMA8(0, 1); PEND();
        LOADA(aR0, 1);                if (more) stage(1, t + 2, 0);
        PSYNC(); MFMA8(4, 0); PEND();
        if (more) { stage(1, t + 2, 1); VM4(); }
        else      { asm volatile("s_waitcnt vmcnt(0)" ::: "memory"); }
        PSYNC(); MFMA8(4, 1); PEND();
        // ---- K-tile t+1 (buf1) ----
        LOADA(aR1, 0); LOADB(bR1, 0); if (more) stage(0, t + 2, 0);
        PSYNC(); MFMA8(0, 0); PEND();
        LOADB(bR1, 1);                if (more) stage(0, t + 2, 1);
        PSYNC(); MFMA8(0, 1); PEND();
        LOADA(aR1, 1);                if (more) stage(1, t + 3, 0);
        PSYNC(); MFMA8(4, 0); PEND();
        if (more) { stage(1, t + 3, 1); VM4(); }
        PSYNC(); MFMA8(4, 1); PEND();
    }

#pragma unroll
    for (int mi = 0; mi < 8; mi++)
#pragma unroll
        for (int ni = 0; ni < 4; ni++) {
            int row = bm * 256 + wr * 128 + mi * 16 + lhi * 4;
            int col = bn * 256 + wc * 64 + ni * 16 + l16;
            float bv = bias ? bias[col] : 0.f;
#pragma unroll
            for (int j = 0; j < 4; j++) {
                float v = acc[mi][ni][j] + bv;
                size_t idx = (size_t)(row + j) * N + col;
                if constexpr (MODE == 0) {
                    __builtin_nontemporal_store(v, (float*)Cout + idx);
                } else if constexpr (MODE == 1) {
                    ((unsigned short*)Cout)[idx] = f2bf(v);
                } else {
                    ((unsigned short*)Cout)[idx] = f2bf(v > 0.f ? v : 0.f);
                }
            }
        }
}

// ---------------- flash attention (causal), PAIRED q-tiles for triangle balance ----
// Block p handles q-tiles p and 15-p: constant 17 tile-computes per block,
// one shared K/V staging pass (16-p tiles). Grid (8, B*H) = 512 blocks.
__global__ __launch_bounds__(256, 3) void attn_fwd(
    const unsigned short* __restrict__ qkv, unsigned short* __restrict__ ctxb)
{
    __shared__ unsigned short Ks[64 * 72];
    __shared__ unsigned short Vs[64 * 72];   // transposed: Vs[d][kv]
    __shared__ unsigned short Ps[4 * 16 * 72];
    const int tid = threadIdx.x;
    const int wid = tid >> 6, lane = tid & 63;
    const int l16 = lane & 15, lhi = lane >> 4;
    const int bh  = blockIdx.y, b = bh >> 4, h = bh & 15;
    const int p   = blockIdx.x;          // 0..7
    const int qA0 = p * 64;
    const int qB0 = (15 - p) * 64;
    const size_t rowbase = (size_t)b * SEQ;

    const unsigned short* qpA = qkv + (rowbase + qA0 + wid * 16 + l16) * QKV_N + h * HDIM + lhi * 8;
    u16x8 qAf0 = *(const u16x8*)qpA;
    u16x8 qAf1 = *(const u16x8*)(qpA + 32);
    const unsigned short* qpB = qkv + (rowbase + qB0 + wid * 16 + l16) * QKV_N + h * HDIM + lhi * 8;
    u16x8 qBf0 = *(const u16x8*)qpB;
    u16x8 qBf1 = *(const u16x8*)(qpB + 32);

    f32x4 oaA[4], oaB[4];
    float mjA[4], ljA[4], mjB[4], ljB[4];
#pragma unroll
    for (int i = 0; i < 4; i++) {
        oaA[i] = (f32x4){0.f, 0.f, 0.f, 0.f};
        oaB[i] = (f32x4){0.f, 0.f, 0.f, 0.f};
        mjA[i] = -1e30f; ljA[i] = 0.f;
        mjB[i] = -1e30f; ljB[i] = 0.f;
    }

    // one online-softmax + PV update for a staged K/V tile
    auto update = [&](u16x8 qf0, u16x8 qf1, f32x4 (&oa)[4],
                      float (&mj)[4], float (&lj)[4], int q0, int kv0) {
        f32x4 sa[4];
#pragma unroll
        for (int ni = 0; ni < 4; ni++) {
            f32x4 z = (f32x4){0.f, 0.f, 0.f, 0.f};
            u16x8 k0f = *(const u16x8*)(&Ks[(ni * 16 + l16) * 72 + lhi * 8]);
            u16x8 k1f = *(const u16x8*)(&Ks[(ni * 16 + l16) * 72 + 32 + lhi * 8]);
            z = mfma32(qf0, k0f, z);
            z = mfma32(qf1, k1f, z);
            sa[ni] = z;
        }
        float tm[4] = {-1e30f, -1e30f, -1e30f, -1e30f};
#pragma unroll
        for (int ni = 0; ni < 4; ni++)
#pragma unroll
            for (int j = 0; j < 4; j++) {
                float v = sa[ni][j] * 0.125f;
                int row = q0 + wid * 16 + lhi * 4 + j;
                int col = kv0 + ni * 16 + l16;
                if (col > row) v = -1e30f;
                sa[ni][j] = v;
                tm[j] = fmaxf(tm[j], v);
            }
#pragma unroll
        for (int j = 0; j < 4; j++) {
#pragma unroll
            for (int off = 1; off < 16; off <<= 1)
                tm[j] = fmaxf(tm[j], __shfl_xor(tm[j], off));
        }
        float al[4], rs[4] = {0.f, 0.f, 0.f, 0.f};
#pragma unroll
        for (int j = 0; j < 4; j++) {
            float mn = fmaxf(mj[j], tm[j]);
            al[j] = __expf(mj[j] - mn);
            mj[j] = mn;
        }
#pragma unroll
        for (int ni = 0; ni < 4; ni++)
#pragma unroll
            for (int j = 0; j < 4; j++) {
                float pv = __expf(sa[ni][j] - mj[j]);
                rs[j] += pv;
                Ps[wid * 1152 + (lhi * 4 + j) * 72 + ni * 16 + l16] = f2bf(pv);
            }
#pragma unroll
        for (int j = 0; j < 4; j++) {
#pragma unroll
            for (int off = 1; off < 16; off <<= 1)
                rs[j] += __shfl_xor(rs[j], off);
            lj[j] = lj[j] * al[j] + rs[j];
        }
#pragma unroll
        for (int di = 0; di < 4; di++)
#pragma unroll
            for (int j = 0; j < 4; j++) oa[di][j] *= al[j];
#pragma unroll
        for (int di = 0; di < 4; di++) {
#pragma unroll
            for (int kc = 0; kc < 2; kc++) {
                u16x8 pf = *(const u16x8*)(&Ps[wid * 1152 + l16 * 72 + kc * 32 + lhi * 8]);
                u16x8 vf = *(const u16x8*)(&Vs[(di * 16 + l16) * 72 + kc * 32 + lhi * 8]);
                oa[di] = mfma32(pf, vf, oa[di]);
            }
        }
    };

    const int ntB = 16 - p;   // kv tiles 0..15-p (covers both q-tiles)
    for (int kt = 0; kt < ntB; ++kt) {
        const int kv0 = kt * 64;
        __syncthreads();
        // K staging: vector writes, row-major
#pragma unroll
        for (int it = 0; it < 2; ++it) {
            int e = it * 256 + tid;
            int r = e >> 3, d0 = (e & 7) * 8;
            size_t goff = (rowbase + kv0 + r) * QKV_N + D_MODEL + h * HDIM + d0;
            u16x8 kk = *(const u16x8*)(qkv + goff);
            *(u16x8*)(&Ks[r * 72 + d0]) = kk;
        }
        // V staging: 128 threads x 4 rows -> transposed via register repack
        if (tid < 128) {
            int r0 = (tid & 15) * 4, d0v = (tid >> 4) * 8;
            const unsigned short* vp = qkv + (rowbase + kv0 + r0) * QKV_N
                                       + 2 * D_MODEL + h * HDIM + d0v;
            u16x8 w0 = *(const u16x8*)vp;
            u16x8 w1 = *(const u16x8*)(vp + QKV_N);
            u16x8 w2 = *(const u16x8*)(vp + 2 * QKV_N);
            u16x8 w3 = *(const u16x8*)(vp + 3 * QKV_N);
#pragma unroll
            for (int j = 0; j < 8; j++) {
                unsigned long long pk = (unsigned long long)w0[j]
                    | ((unsigned long long)w1[j] << 16)
                    | ((unsigned long long)w2[j] << 32)
                    | ((unsigned long long)w3[j] << 48);
                *(unsigned long long*)(&Vs[(d0v + j) * 72 + r0]) = pk;
            }
        }
        __syncthreads();

        if (kt <= p) update(qAf0, qAf1, oaA, mjA, ljA, qA0, kv0);  // block-uniform
        update(qBf0, qBf1, oaB, mjB, ljB, qB0, kv0);
    }

#pragma unroll
    for (int di = 0; di < 4; di++)
#pragma unroll
        for (int j = 0; j < 4; j++) {
            int rowA = qA0 + wid * 16 + lhi * 4 + j;
            ctxb[(rowbase + rowA) * D_MODEL + h * HDIM + di * 16 + l16] =
                f2bf(oaA[di][j] / ljA[j]);
            int rowB = qB0 + wid * 16 + lhi * 4 + j;
            ctxb[(rowbase + rowB) * D_MODEL + h * HDIM + di * 16 + l16] =
                f2bf(oaB[di][j] / ljB[j]);
        }
}

// ---------------- fused residual(x + p0 + p1) + LayerNorm (bf16 partials) ----------------
__global__ __launch_bounds__(256) void ln3(
    float* __restrict__ x, const unsigned short* __restrict__ p0,
    const unsigned short* __restrict__ p1,
    const float* __restrict__ sc, const float* __restrict__ bi,
    unsigned short* __restrict__ xb)
{
    const int row = blockIdx.x;
    const int t = threadIdx.x;
    const size_t base = (size_t)row * D_MODEL + t * 4;
    float4 xv = *(const float4*)(x + base);
    ushort4 au = *(const ushort4*)(p0 + base);
    ushort4 bu = *(const ushort4*)(p1 + base);
    float v0 = xv.x + bf2f(au.x) + bf2f(bu.x);
    float v1 = xv.y + bf2f(au.y) + bf2f(bu.y);
    float v2 = xv.z + bf2f(au.z) + bf2f(bu.z);
    float v3 = xv.w + bf2f(au.w) + bf2f(bu.w);
    float sum = v0 + v1 + v2 + v3;
    float sq  = v0 * v0 + v1 * v1 + v2 * v2 + v3 * v3;
#pragma unroll
    for (int off = 1; off < 64; off <<= 1) {
        sum += __shfl_xor(sum, off);
        sq  += __shfl_xor(sq, off);
    }
    __shared__ float red[8];
    int wid = t >> 6, lane = t & 63;
    if (lane == 0) { red[wid] = sum; red[4 + wid] = sq; }
    __syncthreads();
    sum = red[0] + red[1] + red[2] + red[3];
    sq  = red[4] + red[5] + red[6] + red[7];
    float mu   = sum * (1.f / D_MODEL);
    float var  = sq * (1.f / D_MODEL) - mu * mu;
    float rstd = rsqrtf(var + LN_EPS);
    int c = t * 4;
    float4 sv = *(const float4*)(sc + c);
    float4 bv = *(const float4*)(bi + c);
    float y0 = sv.x * (v0 - mu) * rstd + bv.x;
    float y1 = sv.y * (v1 - mu) * rstd + bv.y;
    float y2 = sv.z * (v2 - mu) * rstd + bv.z;
    float y3 = sv.w * (v3 - mu) * rstd + bv.w;
    *(float4*)(x + base) = make_float4(y0, y1, y2, y3);
    unsigned long long pk = (unsigned long long)f2bf(y0)
        | ((unsigned long long)f2bf(y1) << 16)
        | ((unsigned long long)f2bf(y2) << 32)
        | ((unsigned long long)f2bf(y3) << 48);
    *(unsigned long long*)(xb + base) = pk;
}

// ---------------- launcher ----------------
extern "C" void kernel_launch(void* const* d_in, const int* in_sizes, int n_in,
                              void* d_out, int out_size, void* d_ws, size_t ws_size,
                              hipStream_t stream)
{
    (void)in_sizes; (void)n_in; (void)out_size;
    const int*   tokens = (const int*)d_in[0];
    const float* emb  = (const float*)d_in[2];
    const float* pose = (const float*)d_in[3];
    const float* Wq = (const float*)d_in[4];
    const float* bq = (const float*)d_in[5];
    const float* Wk = (const float*)d_in[6];
    const float* bk = (const float*)d_in[7];
    const float* Wv = (const float*)d_in[8];
    const float* bv = (const float*)d_in[9];
    const float* Wo = (const float*)d_in[10];
    const float* bo = (const float*)d_in[11];
    const float* n1s = (const float*)d_in[12];
    const float* n1b = (const float*)d_in[13];
    const float* W1 = (const float*)d_in[14];
    const float* b1 = (const float*)d_in[15];
    const float* W2 = (const float*)d_in[16];
    const float* b2 = (const float*)d_in[17];
    const float* n2s = (const float*)d_in[18];
    const float* n2b = (const float*)d_in[19];

    char* w = (char*)d_ws;
    size_t off = 0;
    auto carve = [&](size_t bytes) -> void* {
        void* p = w + off;
        off = (off + bytes + 255) & ~(size_t)255;
        return p;
    };
    float* x = (float*)carve((size_t)ROWS * D_MODEL * 4);
    unsigned short* tmp = (unsigned short*)carve((size_t)2 * ROWS * D_MODEL * 2);  // bf16 partials
    unsigned short* xb    = (unsigned short*)carve((size_t)ROWS * D_MODEL * 2);
    unsigned short* qkvb  = (unsigned short*)carve((size_t)ROWS * QKV_N * 2);
    unsigned short* cbuf  = (unsigned short*)carve((size_t)ROWS * D_MODEL * 2);
    unsigned short* hbuf  = (unsigned short*)carve((size_t)ROWS * FF_DIM * 2);
    size_t wt_off = off;
    unsigned short* wt = (unsigned short*)carve((size_t)12 * 1048576 * 2);  // fused: 24MB
    float* bqkv = (float*)carve((size_t)NLAYER * QKV_N * 4);
    unsigned short* embb = qkvb;   // tied-head emb aliases dead qkv/ctx/h region
    unsigned short* tmp1 = tmp + (size_t)ROWS * D_MODEL;
    const bool fused_t = (off <= ws_size);
    if (!fused_t) {
        off = wt_off;
        wt = (unsigned short*)carve((size_t)D_MODEL * FF_DIM * 2);
        bqkv = (float*)carve((size_t)NLAYER * QKV_N * 4);
        if (off > ws_size) return;
    }

    bias3_k<<<NLAYER * 3, 256, 0, stream>>>(bq, bk, bv, bqkv);
    embed_k<<<ROWS, 256, 0, stream>>>(tokens, emb, pose, x, xb);

    for (int l = 0; l < NLAYER; l++) {
        const float* Wq_l = Wq + (size_t)l * D_MODEL * D_MODEL;
        const float* Wk_l = Wk + (size_t)l * D_MODEL * D_MODEL;
        const float* Wv_l = Wv + (size_t)l * D_MODEL * D_MODEL;
        const float* Wo_l = Wo + (size_t)l * D_MODEL * D_MODEL;
        const float* W1_l = W1 + (size_t)l * D_MODEL * FF_DIM;
        const float* W2_l = W2 + (size_t)l * FF_DIM * D_MODEL;

        unsigned short* wtQKV = wt;
        unsigned short* wtWo  = fused_t ? wt + (size_t)3 * 1048576 : wt;
        unsigned short* wtW1  = fused_t ? wt + (size_t)4 * 1048576 : wt;
        unsigned short* wtW2  = fused_t ? wt + (size_t)8 * 1048576 : wt;

        if (fused_t) {
            transpose_all<<<3072, 256, 0, stream>>>(Wq_l, Wk_l, Wv_l, Wo_l, W1_l, W2_l, wt);
        } else {
            transpose_cast3<<<dim3(16, 16, 3), 256, 0, stream>>>(Wq_l, Wk_l, Wv_l, wtQKV);
        }
        gemm_bt<1><<<dim3(768, 1), 256, 0, stream>>>(xb, D_MODEL, wtQKV, D_MODEL,
                                                     bqkv + (size_t)l * QKV_N, qkvb, QKV_N, D_MODEL);

        attn_fwd<<<dim3(8, BATCH * NHEAD), 256, 0, stream>>>(qkvb, cbuf);

        if (!fused_t) transpose_cast<<<dim3(16, 16), 256, 0, stream>>>(Wo_l, wtWo, D_MODEL, D_MODEL);
        gemm_bt<1><<<dim3(256, 2), 256, 0, stream>>>(cbuf, D_MODEL, wtWo, D_MODEL,
                                                     bo + (size_t)l * D_MODEL, tmp, D_MODEL, D_MODEL / 2);
        ln3<<<ROWS, 256, 0, stream>>>(x, tmp, tmp1, n1s + (size_t)l * D_MODEL, n1b + (size_t)l * D_MODEL, xb);

        if (!fused_t) transpose_cast<<<dim3(64, 16), 256, 0, stream>>>(W1_l, wtW1, D_MODEL, FF_DIM);
        gemm256<2, 1><<<(FF_DIM / 256) * 16, 512, 0, stream>>>(xb, wtW1, b1 + (size_t)l * FF_DIM, hbuf, FF_DIM, D_MODEL);
        if (!fused_t) transpose_cast<<<dim3(16, 64), 256, 0, stream>>>(W2_l, wtW2, FF_DIM, D_MODEL);
        gemm_bt<1><<<dim3(256, 2), 256, 0, stream>>>(hbuf, FF_DIM, wtW2, FF_DIM,
                                                     b2 + (size_t)l * D_MODEL, tmp, D_MODEL, FF_DIM / 2);
        ln3<<<ROWS, 256, 0, stream>>>(x, tmp, tmp1, n2s + (size_t)l * D_MODEL, n2b + (size_t)l * D_MODEL, xb);
    }

    cast_bf<<<(VOCAB * D_MODEL) / 1024, 256, 0, stream>>>(emb, embb, (size_t)VOCAB * D_MODEL);
    // head: NO XCD swizzle — bm-fastest order shares B panels via L3
    gemm256<0, 0><<<(VOCAB / 256) * 16, 512, 0, stream>>>(xb, embb, nullptr, d_out, VOCAB, D_MODEL);
}

// Round 11
// 2110.552 us; speedup vs baseline: 1.3182x; 1.0232x over previous
//
#include <hip/hip_runtime.h>

#define D_MODEL 1024
#define SEQ     1024
#define BATCH   4
#define NHEAD   16
#define HDIM    64
#define FF_DIM  4096
#define NLAYER  8
#define VOCAB   32000
#define ROWS    (BATCH*SEQ)
#define QKV_N   3072
#define LN_EPS  1e-5f

typedef __attribute__((ext_vector_type(4))) float   f32x4;
typedef __attribute__((ext_vector_type(8))) unsigned short u16x8;
typedef __attribute__((ext_vector_type(8))) __bf16  bf16x8;

typedef const unsigned int __attribute__((address_space(1)))* gas_t;
typedef unsigned int __attribute__((address_space(3)))* las_t;

__device__ __forceinline__ void gld16(const void* g, void* l) {
    __builtin_amdgcn_global_load_lds((gas_t)g, (las_t)l, 16, 0, 0);
}

__device__ __forceinline__ unsigned short f2bf(float f) {
    unsigned int u = __builtin_bit_cast(unsigned int, f);
    u += 0x7FFFu + ((u >> 16) & 1u);   // RNE
    return (unsigned short)(u >> 16);
}

__device__ __forceinline__ float bf2f(unsigned short u) {
    return __builtin_bit_cast(float, (unsigned int)u << 16);
}

__device__ __forceinline__ f32x4 mfma32(u16x8 a, u16x8 b, f32x4 c) {
    return __builtin_amdgcn_mfma_f32_16x16x32_bf16(
        __builtin_bit_cast(bf16x8, a), __builtin_bit_cast(bf16x8, b), c, 0, 0, 0);
}

// ---------------- embed: x = emb[tok] + pos ----------------
__global__ __launch_bounds__(256) void embed_k(
    const int* __restrict__ tok, const float* __restrict__ emb,
    const float* __restrict__ pos, float* __restrict__ x,
    unsigned short* __restrict__ xb)
{
    int bs = blockIdx.x;
    int s  = bs & (SEQ - 1);
    int tk = tok[bs];
    int c  = threadIdx.x * 4;
    float4 e = *(const float4*)(emb + (size_t)tk * D_MODEL + c);
    float4 p = *(const float4*)(pos + (size_t)s * D_MODEL + c);
    float y0 = e.x + p.x, y1 = e.y + p.y, y2 = e.z + p.z, y3 = e.w + p.w;
    size_t base = (size_t)bs * D_MODEL + c;
    *(float4*)(x + base) = make_float4(y0, y1, y2, y3);
    unsigned long long pk = (unsigned long long)f2bf(y0)
        | ((unsigned long long)f2bf(y1) << 16)
        | ((unsigned long long)f2bf(y2) << 32)
        | ((unsigned long long)f2bf(y3) << 48);
    *(unsigned long long*)(xb + base) = pk;
}

// ---------------- cast fp32 -> bf16 ----------------
__global__ __launch_bounds__(256) void cast_bf(
    const float* __restrict__ in, unsigned short* __restrict__ out, size_t n)
{
    size_t i = ((size_t)blockIdx.x * 256 + threadIdx.x) * 4;
    if (i >= n) return;
    float4 v = *(const float4*)(in + i);
    unsigned long long pk = (unsigned long long)f2bf(v.x)
        | ((unsigned long long)f2bf(v.y) << 16)
        | ((unsigned long long)f2bf(v.z) << 32)
        | ((unsigned long long)f2bf(v.w) << 48);
    *(unsigned long long*)(out + i) = pk;
}

// ---------------- concat qkv biases ----------------
__global__ __launch_bounds__(256) void bias3_k(
    const float* __restrict__ bq, const float* __restrict__ bk,
    const float* __restrict__ bv, float* __restrict__ out)
{
    int l = blockIdx.x / 3, which = blockIdx.x % 3;
    const float* src = which == 0 ? bq : (which == 1 ? bk : bv);
    int i = threadIdx.x * 4;
    float4 v = *(const float4*)(src + (size_t)l * D_MODEL + i);
    *(float4*)(out + (size_t)l * QKV_N + which * D_MODEL + i) = v;
}

// ---------------- transpose tile body (shared) ----------------
__device__ __forceinline__ void tc_tile(
    const float* __restrict__ W, unsigned short* __restrict__ Wt,
    int K, int N, int n0, int k0)
{
    __shared__ float t[64][65];
    int rr = threadIdx.x >> 4;          // 0..15
    int cc = (threadIdx.x & 15) * 4;    // 0..60
#pragma unroll
    for (int it = 0; it < 4; it++) {
        int r = it * 16 + rr;
        float4 v = *(const float4*)(W + (size_t)(k0 + r) * N + n0 + cc);
        t[r][cc] = v.x; t[r][cc + 1] = v.y; t[r][cc + 2] = v.z; t[r][cc + 3] = v.w;
    }
    __syncthreads();
#pragma unroll
    for (int it = 0; it < 4; it++) {
        int n = it * 16 + rr;
        unsigned long long pk = (unsigned long long)f2bf(t[cc][n])
            | ((unsigned long long)f2bf(t[cc + 1][n]) << 16)
            | ((unsigned long long)f2bf(t[cc + 2][n]) << 32)
            | ((unsigned long long)f2bf(t[cc + 3][n]) << 48);
        *(unsigned long long*)(Wt + (size_t)(n0 + n) * K + k0 + cc) = pk;
    }
}

// ---------------- per-tile transpose kernels (fallback path) ----------------
__global__ __launch_bounds__(256) void transpose_cast(
    const float* __restrict__ W, unsigned short* __restrict__ Wt, int K, int N)
{
    tc_tile(W, Wt, K, N, blockIdx.x * 64, blockIdx.y * 64);
}

__global__ __launch_bounds__(256) void transpose_cast3(
    const float* __restrict__ Wq, const float* __restrict__ Wk,
    const float* __restrict__ Wv, unsigned short* __restrict__ Wt)
{
    const int which = blockIdx.z;
    const float* W = which == 0 ? Wq : (which == 1 ? Wk : Wv);
    tc_tile(W, Wt + (size_t)which * (1024 * 1024), 1024, 1024,
            blockIdx.x * 64, blockIdx.y * 64);
}

// ---------------- fused per-layer transpose: Wq,Wk,Wv,Wo,W1,W2 in ONE launch ----
__global__ __launch_bounds__(256) void transpose_all(
    const float* __restrict__ Wq, const float* __restrict__ Wk,
    const float* __restrict__ Wv, const float* __restrict__ Wo,
    const float* __restrict__ W1, const float* __restrict__ W2,
    unsigned short* __restrict__ wt)
{
    int b = blockIdx.x;
    const float* W; unsigned short* out; int K, N, t;
    if (b < 768)       { int w = b >> 8; t = b & 255; W = w == 0 ? Wq : (w == 1 ? Wk : Wv);
                         out = wt + (size_t)w * 1048576; K = 1024; N = 1024; }
    else if (b < 1024) { t = b - 768;  W = Wo; out = wt + (size_t)3 * 1048576; K = 1024; N = 1024; }
    else if (b < 2048) { t = b - 1024; W = W1; out = wt + (size_t)4 * 1048576; K = 1024; N = 4096; }
    else               { t = b - 2048; W = W2; out = wt + (size_t)8 * 1048576; K = 4096; N = 1024; }
    int ntx = N >> 6;
    tc_tile(W, out, K, N, (t % ntx) * 64, (t / ntx) * 64);
}

// ---------------- small NT GEMM (m97 128x128) with split-K support ----------------
// MODE 1: bf16 out; MODE 2: relu->bf16 out.
template<int MODE>
__global__ __launch_bounds__(256, 3) void gemm_bt(
    const unsigned short* __restrict__ A, int lda,
    const unsigned short* __restrict__ Bt, int ldb,
    const float* __restrict__ bias, void* __restrict__ Cout, int N, int Klen)
{
    __shared__ unsigned short As[128 * 32];
    __shared__ unsigned short Bs[128 * 32];
    const int part = blockIdx.y;
    A  += (size_t)part * Klen;
    Bt += (size_t)part * Klen;
    int flat = blockIdx.x;
    const int bm = flat & 31, bn = flat >> 5;
    const int tid  = threadIdx.x;
    const int wid  = tid >> 6, lane = tid & 63;
    const int l16  = lane & 15, lhi = lane >> 4;
    const int wr   = wid >> 1, wc = wid & 1;

    const int srow = wid * 32 + (lane >> 2);
    const int scol = (lane & 3) * 8;
    const unsigned short* gA0 = A  + ((size_t)bm * 128 + srow) * lda + scol;
    const unsigned short* gB0 = Bt + ((size_t)bn * 128 + srow) * ldb + scol;
    unsigned short* lA = As + wid * 32 * 32;
    unsigned short* lB = Bs + wid * 32 * 32;

    f32x4 acc[4][4];
#pragma unroll
    for (int i = 0; i < 4; i++)
#pragma unroll
        for (int j = 0; j < 4; j++) acc[i][j] = (f32x4){0.f, 0.f, 0.f, 0.f};

    for (int k0 = 0; k0 < Klen; k0 += 32) {
        __syncthreads();
        gld16(gA0 + k0,                    lA);
        gld16(gA0 + k0 + 16 * (size_t)lda, lA + 16 * 32);
        gld16(gB0 + k0,                    lB);
        gld16(gB0 + k0 + 16 * (size_t)ldb, lB + 16 * 32);
        __syncthreads();
        u16x8 af[4], bfr[4];
#pragma unroll
        for (int i = 0; i < 4; i++)
            af[i] = *(const u16x8*)(As + (wr * 64 + i * 16 + l16) * 32 + lhi * 8);
#pragma unroll
        for (int i = 0; i < 4; i++)
            bfr[i] = *(const u16x8*)(Bs + (wc * 64 + i * 16 + l16) * 32 + lhi * 8);
#pragma unroll
        for (int mi = 0; mi < 4; mi++)
#pragma unroll
            for (int ni = 0; ni < 4; ni++)
                acc[mi][ni] = mfma32(af[mi], bfr[ni], acc[mi][ni]);
    }

    const size_t pofs = (size_t)part * (size_t)ROWS * N;
    // epilogue: j-then-ni order so 4 stores cover 128B contiguous per row
#pragma unroll
    for (int mi = 0; mi < 4; mi++) {
        float bv[4];
#pragma unroll
        for (int ni = 0; ni < 4; ni++)
            bv[ni] = (bias && part == 0) ? bias[bn * 128 + wc * 64 + ni * 16 + l16] : 0.f;
#pragma unroll
        for (int j = 0; j < 4; j++) {
            int row = bm * 128 + wr * 64 + mi * 16 + lhi * 4 + j;
#pragma unroll
            for (int ni = 0; ni < 4; ni++) {
                int col = bn * 128 + wc * 64 + ni * 16 + l16;
                float v = acc[mi][ni][j] + bv[ni];
                size_t idx = pofs + (size_t)row * N + col;
                if constexpr (MODE == 1) {
                    ((unsigned short*)Cout)[idx] = f2bf(v);
                } else {
                    ((unsigned short*)Cout)[idx] = f2bf(v > 0.f ? v : 0.f);
                }
            }
        }
    }
}

// ================= 256x256 8-phase GEMM (R4-best structure + NT store) =================
#define PSYNC() do { __builtin_amdgcn_s_barrier(); \
    asm volatile("s_waitcnt lgkmcnt(0)" ::: "memory"); \
    __builtin_amdgcn_sched_barrier(0); } while (0)
#define PEND() __builtin_amdgcn_s_barrier()
#define VM4()  asm volatile("s_waitcnt vmcnt(4)" ::: "memory")

#define LOADA(reg, half) do { \
    _Pragma("unroll") \
    for (int m_ = 0; m_ < 4; m_++) { \
        aF[m_][0] = *(const u16x8*)((reg) + ((half)*4 + m_) * 2048 + lane0); \
        aF[m_][1] = *(const u16x8*)((reg) + ((half)*4 + m_) * 2048 + lane1); \
    } } while (0)

#define LOADB(reg, np) do { \
    _Pragma("unroll") \
    for (int n_ = 0; n_ < 2; n_++) { \
        bF[(np)*2 + n_][0] = *(const u16x8*)((reg) + ((np)*2 + n_) * 2048 + lane0); \
        bF[(np)*2 + n_][1] = *(const u16x8*)((reg) + ((np)*2 + n_) * 2048 + lane1); \
    } } while (0)

#define MFMA8(ma, np) do { \
    __builtin_amdgcn_s_setprio(1); \
    _Pragma("unroll") \
    for (int m_ = 0; m_ < 4; m_++) \
        _Pragma("unroll") \
        for (int n_ = 0; n_ < 2; n_++) { \
            acc[(ma)+m_][(np)*2+n_] = mfma32(aF[m_][0], bF[(np)*2+n_][0], acc[(ma)+m_][(np)*2+n_]); \
            acc[(ma)+m_][(np)*2+n_] = mfma32(aF[m_][1], bF[(np)*2+n_][1], acc[(ma)+m_][(np)*2+n_]); \
        } \
    __builtin_amdgcn_s_setprio(0); \
} while (0)

template<int MODE, int SWZ>
__global__ __launch_bounds__(512, 2) void gemm256(
    const unsigned short* __restrict__ A, const unsigned short* __restrict__ Bt,
    const float* __restrict__ bias, void* __restrict__ Cout, int N, int K)
{
    __shared__ unsigned short lds[65536] __attribute__((aligned(128)));
    const int tid = threadIdx.x, wid = tid >> 6, lane = tid & 63;
    const int l16 = lane & 15, lhi = lane >> 4;
    const int wr = wid >> 2, wc = wid & 3;

    int flat = blockIdx.x;
    if constexpr (SWZ) {
        int cpx = gridDim.x >> 3; flat = (flat & 7) * cpx + (flat >> 3);
    }
    const int bm = flat & 15, bn = flat >> 4;
    const int NT = K >> 6;

    const int srowL = tid >> 3;                                      // 0..63
    const int scolb = ((tid & 7) << 4) ^ (((tid >> 3) & 7) << 4);    // bytes (pre-swz src)
    const unsigned short* baseA = A  + (size_t)(bm * 256 + srowL) * K + (scolb >> 1);
    const unsigned short* baseB = Bt + (size_t)(bn * 256 + srowL) * K + (scolb >> 1);
    unsigned short* dst0 = lds + wid * 512;   // wave-uniform; HW adds lane*16B

    auto stage = [&](int isB, int tile, int h) {   // one half-tile = 2 gld16
        const unsigned short* s = (isB ? baseB : baseA) + (size_t)(h * 128) * K + (size_t)tile * 64;
        unsigned short* d = dst0 + (tile & 1) * 32768 + isB * 16384 + h * 8192;
        gld16(s, d);
        gld16(s + (size_t)64 * K, d + 4096);
    };

    const int lswz  = (l16 & 7) << 4;
    const int lane0 = ((lhi * 16) ^ lswz) + l16 * 128;
    const int lane1 = ((64 + lhi * 16) ^ lswz) + l16 * 128;

    const char* aR0 = (const char*)lds + wr * 16384;
    const char* bR0 = (const char*)lds + 32768 + (wc >> 1) * 16384 + (wc & 1) * 8192;
    const char* aR1 = aR0 + 65536;
    const char* bR1 = bR0 + 65536;

    f32x4 acc[8][4];
#pragma unroll
    for (int i = 0; i < 8; i++)
#pragma unroll
        for (int j = 0; j < 4; j++) acc[i][j] = (f32x4){0.f, 0.f, 0.f, 0.f};
    u16x8 aF[4][2], bF[4][2];

    // prologue: B(0),A(0),B(1); leave B(1)'s 4 loads in flight
    stage(1, 0, 0); stage(1, 0, 1);
    stage(0, 0, 0); stage(0, 0, 1);
    stage(1, 1, 0); stage(1, 1, 1);
    VM4();
    __builtin_amdgcn_s_barrier();

    for (int t = 0; t < NT; t += 2) {
        const bool more = (t + 2) < NT;
        // ---- K-tile t (buf0) ----
        LOADA(aR0, 0); LOADB(bR0, 0); stage(0, t + 1, 0);
        PSYNC(); MFMA8(0, 0); PEND();
        LOADB(bR0, 1);                stage(0, t + 1, 1);
        PSYNC(); MFMA8(0, 1); PEND();
        LOADA(aR0, 1);                if (more) stage(1, t + 2, 0);
        PSYNC(); MFMA8(4, 0); PEND();
        if (more) { stage(1, t + 2, 1); VM4(); }
        else      { asm volatile("s_waitcnt vmcnt(0)" ::: "memory"); }
        PSYNC(); MFMA8(4, 1); PEND();
        // ---- K-tile t+1 (buf1) ----
        LOADA(aR1, 0); LOADB(bR1, 0); if (more) stage(0, t + 2, 0);
        PSYNC(); MFMA8(0, 0); PEND();
        LOADB(bR1, 1);                if (more) stage(0, t + 2, 1);
        PSYNC(); MFMA8(0, 1); PEND();
        LOADA(aR1, 1);                if (more) stage(1, t + 3, 0);
        PSYNC(); MFMA8(4, 0); PEND();
        if (more) { stage(1, t + 3, 1); VM4(); }
        PSYNC(); MFMA8(4, 1); PEND();
    }

    // epilogue: j-then-ni order -> 4 consecutive stores cover one full line
#pragma unroll
    for (int mi = 0; mi < 8; mi++) {
        float bv[4];
#pragma unroll
        for (int ni = 0; ni < 4; ni++)
            bv[ni] = bias ? bias[bn * 256 + wc * 64 + ni * 16 + l16] : 0.f;
#pragma unroll
        for (int j = 0; j < 4; j++) {
            int row = bm * 256 + wr * 128 + mi * 16 + lhi * 4 + j;
#pragma unroll
            for (int ni = 0; ni < 4; ni++) {
                int col = bn * 256 + wc * 64 + ni * 16 + l16;
                float v = acc[mi][ni][j] + bv[ni];
                size_t idx = (size_t)row * N + col;
                if constexpr (MODE == 0) {
                    __builtin_nontemporal_store(v, (float*)Cout + idx);
                } else if constexpr (MODE == 1) {
                    ((unsigned short*)Cout)[idx] = f2bf(v);
                } else {
                    ((unsigned short*)Cout)[idx] = f2bf(v > 0.f ? v : 0.f);
                }
            }
        }
    }
}

// ---------------- flash attention (causal), PAIRED q-tiles for triangle balance ----
__global__ __launch_bounds__(256, 3) void attn_fwd(
    const unsigned short* __restrict__ qkv, unsigned short* __restrict__ ctxb)
{
    __shared__ unsigned short Ks[64 * 72];
    __shared__ unsigned short Vs[64 * 72];   // transposed: Vs[d][kv]
    __shared__ unsigned short Ps[4 * 16 * 72];
    const int tid = threadIdx.x;
    const int wid = tid >> 6, lane = tid & 63;
    const int l16 = lane & 15, lhi = lane >> 4;
    const int bh  = blockIdx.y, b = bh >> 4, h = bh & 15;
    const int p   = blockIdx.x;          // 0..7
    const int qA0 = p * 64;
    const int qB0 = (15 - p) * 64;
    const size_t rowbase = (size_t)b * SEQ;

    const unsigned short* qpA = qkv + (rowbase + qA0 + wid * 16 + l16) * QKV_N + h * HDIM + lhi * 8;
    u16x8 qAf0 = *(const u16x8*)qpA;
    u16x8 qAf1 = *(const u16x8*)(qpA + 32);
    const unsigned short* qpB = qkv + (rowbase + qB0 + wid * 16 + l16) * QKV_N + h * HDIM + lhi * 8;
    u16x8 qBf0 = *(const u16x8*)qpB;
    u16x8 qBf1 = *(const u16x8*)(qpB + 32);

    f32x4 oaA[4], oaB[4];
    float mjA[4], ljA[4], mjB[4], ljB[4];
#pragma unroll
    for (int i = 0; i < 4; i++) {
        oaA[i] = (f32x4){0.f, 0.f, 0.f, 0.f};
        oaB[i] = (f32x4){0.f, 0.f, 0.f, 0.f};
        mjA[i] = -1e30f; ljA[i] = 0.f;
        mjB[i] = -1e30f; ljB[i] = 0.f;
    }

    auto update = [&](u16x8 qf0, u16x8 qf1, f32x4 (&oa)[4],
                      float (&mj)[4], float (&lj)[4], int q0, int kv0) {
        f32x4 sa[4];
        __builtin_amdgcn_s_setprio(1);
#pragma unroll
        for (int ni = 0; ni < 4; ni++) {
            f32x4 z = (f32x4){0.f, 0.f, 0.f, 0.f};
            u16x8 k0f = *(const u16x8*)(&Ks[(ni * 16 + l16) * 72 + lhi * 8]);
            u16x8 k1f = *(const u16x8*)(&Ks[(ni * 16 + l16) * 72 + 32 + lhi * 8]);
            z = mfma32(qf0, k0f, z);
            z = mfma32(qf1, k1f, z);
            sa[ni] = z;
        }
        __builtin_amdgcn_s_setprio(0);
        float tm[4] = {-1e30f, -1e30f, -1e30f, -1e30f};
#pragma unroll
        for (int ni = 0; ni < 4; ni++)
#pragma unroll
            for (int j = 0; j < 4; j++) {
                float v = sa[ni][j] * 0.125f;
                int row = q0 + wid * 16 + lhi * 4 + j;
                int col = kv0 + ni * 16 + l16;
                if (col > row) v = -1e30f;
                sa[ni][j] = v;
                tm[j] = fmaxf(tm[j], v);
            }
#pragma unroll
        for (int j = 0; j < 4; j++) {
#pragma unroll
            for (int off = 1; off < 16; off <<= 1)
                tm[j] = fmaxf(tm[j], __shfl_xor(tm[j], off));
        }
        float al[4], rs[4] = {0.f, 0.f, 0.f, 0.f};
#pragma unroll
        for (int j = 0; j < 4; j++) {
            float mn = fmaxf(mj[j], tm[j]);
            al[j] = __expf(mj[j] - mn);
            mj[j] = mn;
        }
#pragma unroll
        for (int ni = 0; ni < 4; ni++)
#pragma unroll
            for (int j = 0; j < 4; j++) {
                float pv = __expf(sa[ni][j] - mj[j]);
                rs[j] += pv;
                Ps[wid * 1152 + (lhi * 4 + j) * 72 + ni * 16 + l16] = f2bf(pv);
            }
#pragma unroll
        for (int j = 0; j < 4; j++) {
#pragma unroll
            for (int off = 1; off < 16; off <<= 1)
                rs[j] += __shfl_xor(rs[j], off);
            lj[j] = lj[j] * al[j] + rs[j];
        }
#pragma unroll
        for (int di = 0; di < 4; di++)
#pragma unroll
            for (int j = 0; j < 4; j++) oa[di][j] *= al[j];
        __builtin_amdgcn_s_setprio(1);
#pragma unroll
        for (int di = 0; di < 4; di++) {
#pragma unroll
            for (int kc = 0; kc < 2; kc++) {
                u16x8 pf = *(const u16x8*)(&Ps[wid * 1152 + l16 * 72 + kc * 32 + lhi * 8]);
                u16x8 vf = *(const u16x8*)(&Vs[(di * 16 + l16) * 72 + kc * 32 + lhi * 8]);
                oa[di] = mfma32(pf, vf, oa[di]);
            }
        }
        __builtin_amdgcn_s_setprio(0);
    };

    const int ntB = 16 - p;   // kv tiles 0..15-p (covers both q-tiles)
    for (int kt = 0; kt < ntB; ++kt) {
        const int kv0 = kt * 64;
        __syncthreads();
        // K staging: vector writes, row-major
#pragma unroll
        for (int it = 0; it < 2; ++it) {
            int e = it * 256 + tid;
            int r = e >> 3, d0 = (e & 7) * 8;
            size_t goff = (rowbase + kv0 + r) * QKV_N + D_MODEL + h * HDIM + d0;
            u16x8 kk = *(const u16x8*)(qkv + goff);
            *(u16x8*)(&Ks[r * 72 + d0]) = kk;
        }
        // V staging: 128 threads x 4 rows -> transposed via register repack
        if (tid < 128) {
            int r0 = (tid & 15) * 4, d0v = (tid >> 4) * 8;
            const unsigned short* vp = qkv + (rowbase + kv0 + r0) * QKV_N
                                       + 2 * D_MODEL + h * HDIM + d0v;
            u16x8 w0 = *(const u16x8*)vp;
            u16x8 w1 = *(const u16x8*)(vp + QKV_N);
            u16x8 w2 = *(const u16x8*)(vp + 2 * QKV_N);
            u16x8 w3 = *(const u16x8*)(vp + 3 * QKV_N);
#pragma unroll
            for (int j = 0; j < 8; j++) {
                unsigned long long pk = (unsigned long long)w0[j]
                    | ((unsigned long long)w1[j] << 16)
                    | ((unsigned long long)w2[j] << 32)
                    | ((unsigned long long)w3[j] << 48);
                *(unsigned long long*)(&Vs[(d0v + j) * 72 + r0]) = pk;
            }
        }
        __syncthreads();

        if (kt <= p) update(qAf0, qAf1, oaA, mjA, ljA, qA0, kv0);  // block-uniform
        update(qBf0, qBf1, oaB, mjB, ljB, qB0, kv0);
    }

#pragma unroll
    for (int di = 0; di < 4; di++)
#pragma unroll
        for (int j = 0; j < 4; j++) {
            int rowA = qA0 + wid * 16 + lhi * 4 + j;
            ctxb[(rowbase + rowA) * D_MODEL + h * HDIM + di * 16 + l16] =
                f2bf(oaA[di][j] / ljA[j]);
            int rowB = qB0 + wid * 16 + lhi * 4 + j;
            ctxb[(rowbase + rowB) * D_MODEL + h * HDIM + di * 16 + l16] =
                f2bf(oaB[di][j] / ljB[j]);
        }
}

// ---------------- fused residual(x + p0 + p1) + LayerNorm (bf16 partials) ----------------
__global__ __launch_bounds__(256) void ln3(
    float* __restrict__ x, const unsigned short* __restrict__ p0,
    const unsigned short* __restrict__ p1,
    const float* __restrict__ sc, const float* __restrict__ bi,
    unsigned short* __restrict__ xb)
{
    const int row = blockIdx.x;
    const int t = threadIdx.x;
    const size_t base = (size_t)row * D_MODEL + t * 4;
    float4 xv = *(const float4*)(x + base);
    ushort4 au = *(const ushort4*)(p0 + base);
    ushort4 bu = *(const ushort4*)(p1 + base);
    float v0 = xv.x + bf2f(au.x) + bf2f(bu.x);
    float v1 = xv.y + bf2f(au.y) + bf2f(bu.y);
    float v2 = xv.z + bf2f(au.z) + bf2f(bu.z);
    float v3 = xv.w + bf2f(au.w) + bf2f(bu.w);
    float sum = v0 + v1 + v2 + v3;
    float sq  = v0 * v0 + v1 * v1 + v2 * v2 + v3 * v3;
#pragma unroll
    for (int off = 1; off < 64; off <<= 1) {
        sum += __shfl_xor(sum, off);
        sq  += __shfl_xor(sq, off);
    }
    __shared__ float red[8];
    int wid = t >> 6, lane = t & 63;
    if (lane == 0) { red[wid] = sum; red[4 + wid] = sq; }
    __syncthreads();
    sum = red[0] + red[1] + red[2] + red[3];
    sq  = red[4] + red[5] + red[6] + red[7];
    float mu   = sum * (1.f / D_MODEL);
    float var  = sq * (1.f / D_MODEL) - mu * mu;
    float rstd = rsqrtf(var + LN_EPS);
    int c = t * 4;
    float4 sv = *(const float4*)(sc + c);
    float4 bv = *(const float4*)(bi + c);
    float y0 = sv.x * (v0 - mu) * rstd + bv.x;
    float y1 = sv.y * (v1 - mu) * rstd + bv.y;
    float y2 = sv.z * (v2 - mu) * rstd + bv.z;
    float y3 = sv.w * (v3 - mu) * rstd + bv.w;
    *(float4*)(x + base) = make_float4(y0, y1, y2, y3);
    unsigned long long pk = (unsigned long long)f2bf(y0)
        | ((unsigned long long)f2bf(y1) << 16)
        | ((unsigned long long)f2bf(y2) << 32)
        | ((unsigned long long)f2bf(y3) << 48);
    *(unsigned long long*)(xb + base) = pk;
}

// ---------------- launcher ----------------
extern "C" void kernel_launch(void* const* d_in, const int* in_sizes, int n_in,
                              void* d_out, int out_size, void* d_ws, size_t ws_size,
                              hipStream_t stream)
{
    (void)in_sizes; (void)n_in; (void)out_size;
    const int*   tokens = (const int*)d_in[0];
    const float* emb  = (const float*)d_in[2];
    const float* pose = (const float*)d_in[3];
    const float* Wq = (const float*)d_in[4];
    const float* bq = (const float*)d_in[5];
    const float* Wk = (const float*)d_in[6];
    const float* bk = (const float*)d_in[7];
    const float* Wv = (const float*)d_in[8];
    const float* bv = (const float*)d_in[9];
    const float* Wo = (const float*)d_in[10];
    const float* bo = (const float*)d_in[11];
    const float* n1s = (const float*)d_in[12];
    const float* n1b = (const float*)d_in[13];
    const float* W1 = (const float*)d_in[14];
    const float* b1 = (const float*)d_in[15];
    const float* W2 = (const float*)d_in[16];
    const float* b2 = (const float*)d_in[17];
    const float* n2s = (const float*)d_in[18];
    const float* n2b = (const float*)d_in[19];

    char* w = (char*)d_ws;
    size_t off = 0;
    auto carve = [&](size_t bytes) -> void* {
        void* p = w + off;
        off = (off + bytes + 255) & ~(size_t)255;
        return p;
    };
    float* x = (float*)carve((size_t)ROWS * D_MODEL * 4);
    unsigned short* tmp = (unsigned short*)carve((size_t)2 * ROWS * D_MODEL * 2);  // bf16 partials
    unsigned short* xb    = (unsigned short*)carve((size_t)ROWS * D_MODEL * 2);
    unsigned short* qkvb  = (unsigned short*)carve((size_t)ROWS * QKV_N * 2);
    unsigned short* cbuf  = (unsigned short*)carve((size_t)ROWS * D_MODEL * 2);
    unsigned short* hbuf  = (unsigned short*)carve((size_t)ROWS * FF_DIM * 2);
    size_t wt_off = off;
    unsigned short* wt = (unsigned short*)carve((size_t)12 * 1048576 * 2);  // fused: 24MB
    float* bqkv = (float*)carve((size_t)NLAYER * QKV_N * 4);
    unsigned short* embb = qkvb;   // tied-head emb aliases dead qkv/ctx/h region
    unsigned short* tmp1 = tmp + (size_t)ROWS * D_MODEL;
    const bool fused_t = (off <= ws_size);
    if (!fused_t) {
        off = wt_off;
        wt = (unsigned short*)carve((size_t)D_MODEL * FF_DIM * 2);
        bqkv = (float*)carve((size_t)NLAYER * QKV_N * 4);
        if (off > ws_size) return;
    }

    bias3_k<<<NLAYER * 3, 256, 0, stream>>>(bq, bk, bv, bqkv);
    embed_k<<<ROWS, 256, 0, stream>>>(tokens, emb, pose, x, xb);

    for (int l = 0; l < NLAYER; l++) {
        const float* Wq_l = Wq + (size_t)l * D_MODEL * D_MODEL;
        const float* Wk_l = Wk + (size_t)l * D_MODEL * D_MODEL;
        const float* Wv_l = Wv + (size_t)l * D_MODEL * D_MODEL;
        const float* Wo_l = Wo + (size_t)l * D_MODEL * D_MODEL;
        const float* W1_l = W1 + (size_t)l * D_MODEL * FF_DIM;
        const float* W2_l = W2 + (size_t)l * FF_DIM * D_MODEL;

        unsigned short* wtQKV = wt;
        unsigned short* wtWo  = fused_t ? wt + (size_t)3 * 1048576 : wt;
        unsigned short* wtW1  = fused_t ? wt + (size_t)4 * 1048576 : wt;
        unsigned short* wtW2  = fused_t ? wt + (size_t)8 * 1048576 : wt;

        if (fused_t) {
            transpose_all<<<3072, 256, 0, stream>>>(Wq_l, Wk_l, Wv_l, Wo_l, W1_l, W2_l, wt);
        } else {
            transpose_cast3<<<dim3(16, 16, 3), 256, 0, stream>>>(Wq_l, Wk_l, Wv_l, wtQKV);
        }
        gemm_bt<1><<<dim3(768, 1), 256, 0, stream>>>(xb, D_MODEL, wtQKV, D_MODEL,
                                                     bqkv + (size_t)l * QKV_N, qkvb, QKV_N, D_MODEL);

        attn_fwd<<<dim3(8, BATCH * NHEAD), 256, 0, stream>>>(qkvb, cbuf);

        if (!fused_t) transpose_cast<<<dim3(16, 16), 256, 0, stream>>>(Wo_l, wtWo, D_MODEL, D_MODEL);
        gemm_bt<1><<<dim3(256, 2), 256, 0, stream>>>(cbuf, D_MODEL, wtWo, D_MODEL,
                                                     bo + (size_t)l * D_MODEL, tmp, D_MODEL, D_MODEL / 2);
        ln3<<<ROWS, 256, 0, stream>>>(x, tmp, tmp1, n1s + (size_t)l * D_MODEL, n1b + (size_t)l * D_MODEL, xb);

        if (!fused_t) transpose_cast<<<dim3(64, 16), 256, 0, stream>>>(W1_l, wtW1, D_MODEL, FF_DIM);
        gemm256<2, 1><<<(FF_DIM / 256) * 16, 512, 0, stream>>>(xb, wtW1, b1 + (size_t)l * FF_DIM, hbuf, FF_DIM, D_MODEL);
        if (!fused_t) transpose_cast<<<dim3(16, 64), 256, 0, stream>>>(W2_l, wtW2, FF_DIM, D_MODEL);
        gemm_bt<1><<<dim3(256, 2), 256, 0, stream>>>(hbuf, FF_DIM, wtW2, FF_DIM,
                                                     b2 + (size_t)l * D_MODEL, tmp, D_MODEL, FF_DIM / 2);
        ln3<<<ROWS, 256, 0, stream>>>(x, tmp, tmp1, n2s + (size_t)l * D_MODEL, n2b + (size_t)l * D_MODEL, xb);
    }

    cast_bf<<<(VOCAB * D_MODEL) / 1024, 256, 0, stream>>>(emb, embb, (size_t)VOCAB * D_MODEL);
    // head: NO XCD swizzle — bm-fastest order shares B panels via L3
    gemm256<0, 0><<<(VOCAB / 256) * 16, 512, 0, stream>>>(xb, embb, nullptr, d_out, VOCAB, D_MODEL);
}

// Round 12
// 2057.844 us; speedup vs baseline: 1.3519x; 1.0256x over previous
//
#include <hip/hip_runtime.h>

#define D_MODEL 1024
#define SEQ     1024
#define BATCH   4
#define NHEAD   16
#define HDIM    64
#define FF_DIM  4096
#define NLAYER  8
#define VOCAB   32000
#define ROWS    (BATCH*SEQ)
#define QKV_N   3072
#define LN_EPS  1e-5f

typedef __attribute__((ext_vector_type(4))) float   f32x4;
typedef __attribute__((ext_vector_type(8))) unsigned short u16x8;
typedef __attribute__((ext_vector_type(8))) __bf16  bf16x8;

typedef const unsigned int __attribute__((address_space(1)))* gas_t;
typedef unsigned int __attribute__((address_space(3)))* las_t;

__device__ __forceinline__ void gld16(const void* g, void* l) {
    __builtin_amdgcn_global_load_lds((gas_t)g, (las_t)l, 16, 0, 0);
}

__device__ __forceinline__ unsigned short f2bf(float f) {
    unsigned int u = __builtin_bit_cast(unsigned int, f);
    u += 0x7FFFu + ((u >> 16) & 1u);   // RNE
    return (unsigned short)(u >> 16);
}

__device__ __forceinline__ float bf2f(unsigned short u) {
    return __builtin_bit_cast(float, (unsigned int)u << 16);
}

__device__ __forceinline__ f32x4 mfma32(u16x8 a, u16x8 b, f32x4 c) {
    return __builtin_amdgcn_mfma_f32_16x16x32_bf16(
        __builtin_bit_cast(bf16x8, a), __builtin_bit_cast(bf16x8, b), c, 0, 0, 0);
}

// ---------------- embed: xb = bf16(emb[tok] + pos) ----------------
__global__ __launch_bounds__(256) void embed_k(
    const int* __restrict__ tok, const float* __restrict__ emb,
    const float* __restrict__ pos, unsigned short* __restrict__ xb)
{
    int bs = blockIdx.x;
    int s  = bs & (SEQ - 1);
    int tk = tok[bs];
    int c  = threadIdx.x * 4;
    float4 e = *(const float4*)(emb + (size_t)tk * D_MODEL + c);
    float4 p = *(const float4*)(pos + (size_t)s * D_MODEL + c);
    float y0 = e.x + p.x, y1 = e.y + p.y, y2 = e.z + p.z, y3 = e.w + p.w;
    size_t base = (size_t)bs * D_MODEL + c;
    unsigned long long pk = (unsigned long long)f2bf(y0)
        | ((unsigned long long)f2bf(y1) << 16)
        | ((unsigned long long)f2bf(y2) << 32)
        | ((unsigned long long)f2bf(y3) << 48);
    *(unsigned long long*)(xb + base) = pk;
}

// ---------------- cast fp32 -> bf16 ----------------
__global__ __launch_bounds__(256) void cast_bf(
    const float* __restrict__ in, unsigned short* __restrict__ out, size_t n)
{
    size_t i = ((size_t)blockIdx.x * 256 + threadIdx.x) * 4;
    if (i >= n) return;
    float4 v = *(const float4*)(in + i);
    unsigned long long pk = (unsigned long long)f2bf(v.x)
        | ((unsigned long long)f2bf(v.y) << 16)
        | ((unsigned long long)f2bf(v.z) << 32)
        | ((unsigned long long)f2bf(v.w) << 48);
    *(unsigned long long*)(out + i) = pk;
}

// ---------------- concat qkv biases ----------------
__global__ __launch_bounds__(256) void bias3_k(
    const float* __restrict__ bq, const float* __restrict__ bk,
    const float* __restrict__ bv, float* __restrict__ out)
{
    int l = blockIdx.x / 3, which = blockIdx.x % 3;
    const float* src = which == 0 ? bq : (which == 1 ? bk : bv);
    int i = threadIdx.x * 4;
    float4 v = *(const float4*)(src + (size_t)l * D_MODEL + i);
    *(float4*)(out + (size_t)l * QKV_N + which * D_MODEL + i) = v;
}

// ---------------- transpose tile body (shared) ----------------
__device__ __forceinline__ void tc_tile(
    const float* __restrict__ W, unsigned short* __restrict__ Wt,
    int K, int N, int n0, int k0)
{
    __shared__ float t[64][65];
    int rr = threadIdx.x >> 4;          // 0..15
    int cc = (threadIdx.x & 15) * 4;    // 0..60
#pragma unroll
    for (int it = 0; it < 4; it++) {
        int r = it * 16 + rr;
        float4 v = *(const float4*)(W + (size_t)(k0 + r) * N + n0 + cc);
        t[r][cc] = v.x; t[r][cc + 1] = v.y; t[r][cc + 2] = v.z; t[r][cc + 3] = v.w;
    }
    __syncthreads();
#pragma unroll
    for (int it = 0; it < 4; it++) {
        int n = it * 16 + rr;
        unsigned long long pk = (unsigned long long)f2bf(t[cc][n])
            | ((unsigned long long)f2bf(t[cc + 1][n]) << 16)
            | ((unsigned long long)f2bf(t[cc + 2][n]) << 32)
            | ((unsigned long long)f2bf(t[cc + 3][n]) << 48);
        *(unsigned long long*)(Wt + (size_t)(n0 + n) * K + k0 + cc) = pk;
    }
}

// ---------------- per-tile transpose kernels (fallback path) ----------------
__global__ __launch_bounds__(256) void transpose_cast(
    const float* __restrict__ W, unsigned short* __restrict__ Wt, int K, int N)
{
    tc_tile(W, Wt, K, N, blockIdx.x * 64, blockIdx.y * 64);
}

__global__ __launch_bounds__(256) void transpose_cast3(
    const float* __restrict__ Wq, const float* __restrict__ Wk,
    const float* __restrict__ Wv, unsigned short* __restrict__ Wt)
{
    const int which = blockIdx.z;
    const float* W = which == 0 ? Wq : (which == 1 ? Wk : Wv);
    tc_tile(W, Wt + (size_t)which * (1024 * 1024), 1024, 1024,
            blockIdx.x * 64, blockIdx.y * 64);
}

// ---------------- fused per-layer transpose: Wq,Wk,Wv,Wo,W1,W2 in ONE launch ----
__global__ __launch_bounds__(256) void transpose_all(
    const float* __restrict__ Wq, const float* __restrict__ Wk,
    const float* __restrict__ Wv, const float* __restrict__ Wo,
    const float* __restrict__ W1, const float* __restrict__ W2,
    unsigned short* __restrict__ wt)
{
    int b = blockIdx.x;
    const float* W; unsigned short* out; int K, N, t;
    if (b < 768)       { int w = b >> 8; t = b & 255; W = w == 0 ? Wq : (w == 1 ? Wk : Wv);
                         out = wt + (size_t)w * 1048576; K = 1024; N = 1024; }
    else if (b < 1024) { t = b - 768;  W = Wo; out = wt + (size_t)3 * 1048576; K = 1024; N = 1024; }
    else if (b < 2048) { t = b - 1024; W = W1; out = wt + (size_t)4 * 1048576; K = 1024; N = 4096; }
    else               { t = b - 2048; W = W2; out = wt + (size_t)8 * 1048576; K = 4096; N = 1024; }
    int ntx = N >> 6;
    tc_tile(W, out, K, N, (t % ntx) * 64, (t / ntx) * 64);
}

// ---------------- small NT GEMM (m97 128x128) with split-K support ----------------
// MODE 1: bf16 out; MODE 2: relu->bf16 out.
template<int MODE>
__global__ __launch_bounds__(256, 3) void gemm_bt(
    const unsigned short* __restrict__ A, int lda,
    const unsigned short* __restrict__ Bt, int ldb,
    const float* __restrict__ bias, void* __restrict__ Cout, int N, int Klen)
{
    __shared__ unsigned short As[128 * 32];
    __shared__ unsigned short Bs[128 * 32];
    const int part = blockIdx.y;
    A  += (size_t)part * Klen;
    Bt += (size_t)part * Klen;
    int flat = blockIdx.x;
    const int bm = flat & 31, bn = flat >> 5;
    const int tid  = threadIdx.x;
    const int wid  = tid >> 6, lane = tid & 63;
    const int l16  = lane & 15, lhi = lane >> 4;
    const int wr   = wid >> 1, wc = wid & 1;

    const int srow = wid * 32 + (lane >> 2);
    const int scol = (lane & 3) * 8;
    const unsigned short* gA0 = A  + ((size_t)bm * 128 + srow) * lda + scol;
    const unsigned short* gB0 = Bt + ((size_t)bn * 128 + srow) * ldb + scol;
    unsigned short* lA = As + wid * 32 * 32;
    unsigned short* lB = Bs + wid * 32 * 32;

    f32x4 acc[4][4];
#pragma unroll
    for (int i = 0; i < 4; i++)
#pragma unroll
        for (int j = 0; j < 4; j++) acc[i][j] = (f32x4){0.f, 0.f, 0.f, 0.f};

    for (int k0 = 0; k0 < Klen; k0 += 32) {
        __syncthreads();
        gld16(gA0 + k0,                    lA);
        gld16(gA0 + k0 + 16 * (size_t)lda, lA + 16 * 32);
        gld16(gB0 + k0,                    lB);
        gld16(gB0 + k0 + 16 * (size_t)ldb, lB + 16 * 32);
        __syncthreads();
        u16x8 af[4], bfr[4];
#pragma unroll
        for (int i = 0; i < 4; i++)
            af[i] = *(const u16x8*)(As + (wr * 64 + i * 16 + l16) * 32 + lhi * 8);
#pragma unroll
        for (int i = 0; i < 4; i++)
            bfr[i] = *(const u16x8*)(Bs + (wc * 64 + i * 16 + l16) * 32 + lhi * 8);
#pragma unroll
        for (int mi = 0; mi < 4; mi++)
#pragma unroll
            for (int ni = 0; ni < 4; ni++)
                acc[mi][ni] = mfma32(af[mi], bfr[ni], acc[mi][ni]);
    }

    const size_t pofs = (size_t)part * (size_t)ROWS * N;
    // epilogue: j-then-ni order so 4 stores cover 128B contiguous per row
#pragma unroll
    for (int mi = 0; mi < 4; mi++) {
        float bv[4];
#pragma unroll
        for (int ni = 0; ni < 4; ni++)
            bv[ni] = (bias && part == 0) ? bias[bn * 128 + wc * 64 + ni * 16 + l16] : 0.f;
#pragma unroll
        for (int j = 0; j < 4; j++) {
            int row = bm * 128 + wr * 64 + mi * 16 + lhi * 4 + j;
#pragma unroll
            for (int ni = 0; ni < 4; ni++) {
                int col = bn * 128 + wc * 64 + ni * 16 + l16;
                float v = acc[mi][ni][j] + bv[ni];
                size_t idx = pofs + (size_t)row * N + col;
                if constexpr (MODE == 1) {
                    ((unsigned short*)Cout)[idx] = f2bf(v);
                } else {
                    ((unsigned short*)Cout)[idx] = f2bf(v > 0.f ? v : 0.f);
                }
            }
        }
    }
}

// ================= 256x256 8-phase GEMM (R4-best structure + NT store) =================
#define PSYNC() do { __builtin_amdgcn_s_barrier(); \
    asm volatile("s_waitcnt lgkmcnt(0)" ::: "memory"); \
    __builtin_amdgcn_sched_barrier(0); } while (0)
#define PEND() __builtin_amdgcn_s_barrier()
#define VM4()  asm volatile("s_waitcnt vmcnt(4)" ::: "memory")

#define LOADA(reg, half) do { \
    _Pragma("unroll") \
    for (int m_ = 0; m_ < 4; m_++) { \
        aF[m_][0] = *(const u16x8*)((reg) + ((half)*4 + m_) * 2048 + lane0); \
        aF[m_][1] = *(const u16x8*)((reg) + ((half)*4 + m_) * 2048 + lane1); \
    } } while (0)

#define LOADB(reg, np) do { \
    _Pragma("unroll") \
    for (int n_ = 0; n_ < 2; n_++) { \
        bF[(np)*2 + n_][0] = *(const u16x8*)((reg) + ((np)*2 + n_) * 2048 + lane0); \
        bF[(np)*2 + n_][1] = *(const u16x8*)((reg) + ((np)*2 + n_) * 2048 + lane1); \
    } } while (0)

#define MFMA8(ma, np) do { \
    __builtin_amdgcn_s_setprio(1); \
    _Pragma("unroll") \
    for (int m_ = 0; m_ < 4; m_++) \
        _Pragma("unroll") \
        for (int n_ = 0; n_ < 2; n_++) { \
            acc[(ma)+m_][(np)*2+n_] = mfma32(aF[m_][0], bF[(np)*2+n_][0], acc[(ma)+m_][(np)*2+n_]); \
            acc[(ma)+m_][(np)*2+n_] = mfma32(aF[m_][1], bF[(np)*2+n_][1], acc[(ma)+m_][(np)*2+n_]); \
        } \
    __builtin_amdgcn_s_setprio(0); \
} while (0)

template<int MODE, int SWZ>
__global__ __launch_bounds__(512, 2) void gemm256(
    const unsigned short* __restrict__ A, const unsigned short* __restrict__ Bt,
    const float* __restrict__ bias, void* __restrict__ Cout, int N, int K)
{
    __shared__ unsigned short lds[65536] __attribute__((aligned(128)));
    const int tid = threadIdx.x, wid = tid >> 6, lane = tid & 63;
    const int l16 = lane & 15, lhi = lane >> 4;
    const int wr = wid >> 2, wc = wid & 3;

    int flat = blockIdx.x;
    if constexpr (SWZ) {
        int cpx = gridDim.x >> 3; flat = (flat & 7) * cpx + (flat >> 3);
    }
    const int bm = flat & 15, bn = flat >> 4;
    const int NT = K >> 6;

    const int srowL = tid >> 3;                                      // 0..63
    const int scolb = ((tid & 7) << 4) ^ (((tid >> 3) & 7) << 4);    // bytes (pre-swz src)
    const unsigned short* baseA = A  + (size_t)(bm * 256 + srowL) * K + (scolb >> 1);
    const unsigned short* baseB = Bt + (size_t)(bn * 256 + srowL) * K + (scolb >> 1);
    unsigned short* dst0 = lds + wid * 512;   // wave-uniform; HW adds lane*16B

    auto stage = [&](int isB, int tile, int h) {   // one half-tile = 2 gld16
        const unsigned short* s = (isB ? baseB : baseA) + (size_t)(h * 128) * K + (size_t)tile * 64;
        unsigned short* d = dst0 + (tile & 1) * 32768 + isB * 16384 + h * 8192;
        gld16(s, d);
        gld16(s + (size_t)64 * K, d + 4096);
    };

    const int lswz  = (l16 & 7) << 4;
    const int lane0 = ((lhi * 16) ^ lswz) + l16 * 128;
    const int lane1 = ((64 + lhi * 16) ^ lswz) + l16 * 128;

    const char* aR0 = (const char*)lds + wr * 16384;
    const char* bR0 = (const char*)lds + 32768 + (wc >> 1) * 16384 + (wc & 1) * 8192;
    const char* aR1 = aR0 + 65536;
    const char* bR1 = bR0 + 65536;

    f32x4 acc[8][4];
#pragma unroll
    for (int i = 0; i < 8; i++)
#pragma unroll
        for (int j = 0; j < 4; j++) acc[i][j] = (f32x4){0.f, 0.f, 0.f, 0.f};
    u16x8 aF[4][2], bF[4][2];

    // prologue: B(0),A(0),B(1); leave B(1)'s 4 loads in flight
    stage(1, 0, 0); stage(1, 0, 1);
    stage(0, 0, 0); stage(0, 0, 1);
    stage(1, 1, 0); stage(1, 1, 1);
    VM4();
    __builtin_amdgcn_s_barrier();

    for (int t = 0; t < NT; t += 2) {
        const bool more = (t + 2) < NT;
        // ---- K-tile t (buf0) ----
        LOADA(aR0, 0); LOADB(bR0, 0); stage(0, t + 1, 0);
        PSYNC(); MFMA8(0, 0); PEND();
        LOADB(bR0, 1);                stage(0, t + 1, 1);
        PSYNC(); MFMA8(0, 1); PEND();
        LOADA(aR0, 1);                if (more) stage(1, t + 2, 0);
        PSYNC(); MFMA8(4, 0); PEND();
        if (more) { stage(1, t + 2, 1); VM4(); }
        else      { asm volatile("s_waitcnt vmcnt(0)" ::: "memory"); }
        PSYNC(); MFMA8(4, 1); PEND();
        // ---- K-tile t+1 (buf1) ----
        LOADA(aR1, 0); LOADB(bR1, 0); if (more) stage(0, t + 2, 0);
        PSYNC(); MFMA8(0, 0); PEND();
        LOADB(bR1, 1);                if (more) stage(0, t + 2, 1);
        PSYNC(); MFMA8(0, 1); PEND();
        LOADA(aR1, 1);                if (more) stage(1, t + 3, 0);
        PSYNC(); MFMA8(4, 0); PEND();
        if (more) { stage(1, t + 3, 1); VM4(); }
        PSYNC(); MFMA8(4, 1); PEND();
    }

    // epilogue: j-then-ni order -> 4 consecutive stores cover one full line
#pragma unroll
    for (int mi = 0; mi < 8; mi++) {
        float bv[4];
#pragma unroll
        for (int ni = 0; ni < 4; ni++)
            bv[ni] = bias ? bias[bn * 256 + wc * 64 + ni * 16 + l16] : 0.f;
#pragma unroll
        for (int j = 0; j < 4; j++) {
            int row = bm * 256 + wr * 128 + mi * 16 + lhi * 4 + j;
#pragma unroll
            for (int ni = 0; ni < 4; ni++) {
                int col = bn * 256 + wc * 64 + ni * 16 + l16;
                float v = acc[mi][ni][j] + bv[ni];
                size_t idx = (size_t)row * N + col;
                if constexpr (MODE == 0) {
                    __builtin_nontemporal_store(v, (float*)Cout + idx);
                } else if constexpr (MODE == 1) {
                    ((unsigned short*)Cout)[idx] = f2bf(v);
                } else {
                    ((unsigned short*)Cout)[idx] = f2bf(v > 0.f ? v : 0.f);
                }
            }
        }
    }
}

// ---------------- flash attention (causal), PAIRED q-tiles for triangle balance ----
__global__ __launch_bounds__(256, 3) void attn_fwd(
    const unsigned short* __restrict__ qkv, unsigned short* __restrict__ ctxb)
{
    __shared__ unsigned short Ks[64 * 72];
    __shared__ unsigned short Vs[64 * 72];   // transposed: Vs[d][kv]
    __shared__ unsigned short Ps[4 * 16 * 72];
    const int tid = threadIdx.x;
    const int wid = tid >> 6, lane = tid & 63;
    const int l16 = lane & 15, lhi = lane >> 4;
    const int bh  = blockIdx.y, b = bh >> 4, h = bh & 15;
    const int p   = blockIdx.x;          // 0..7
    const int qA0 = p * 64;
    const int qB0 = (15 - p) * 64;
    const size_t rowbase = (size_t)b * SEQ;

    const unsigned short* qpA = qkv + (rowbase + qA0 + wid * 16 + l16) * QKV_N + h * HDIM + lhi * 8;
    u16x8 qAf0 = *(const u16x8*)qpA;
    u16x8 qAf1 = *(const u16x8*)(qpA + 32);
    const unsigned short* qpB = qkv + (rowbase + qB0 + wid * 16 + l16) * QKV_N + h * HDIM + lhi * 8;
    u16x8 qBf0 = *(const u16x8*)qpB;
    u16x8 qBf1 = *(const u16x8*)(qpB + 32);

    f32x4 oaA[4], oaB[4];
    float mjA[4], ljA[4], mjB[4], ljB[4];
#pragma unroll
    for (int i = 0; i < 4; i++) {
        oaA[i] = (f32x4){0.f, 0.f, 0.f, 0.f};
        oaB[i] = (f32x4){0.f, 0.f, 0.f, 0.f};
        mjA[i] = -1e30f; ljA[i] = 0.f;
        mjB[i] = -1e30f; ljB[i] = 0.f;
    }

    auto update = [&](u16x8 qf0, u16x8 qf1, f32x4 (&oa)[4],
                      float (&mj)[4], float (&lj)[4], int q0, int kv0) {
        f32x4 sa[4];
        __builtin_amdgcn_s_setprio(1);
#pragma unroll
        for (int ni = 0; ni < 4; ni++) {
            f32x4 z = (f32x4){0.f, 0.f, 0.f, 0.f};
            u16x8 k0f = *(const u16x8*)(&Ks[(ni * 16 + l16) * 72 + lhi * 8]);
            u16x8 k1f = *(const u16x8*)(&Ks[(ni * 16 + l16) * 72 + 32 + lhi * 8]);
            z = mfma32(qf0, k0f, z);
            z = mfma32(qf1, k1f, z);
            sa[ni] = z;
        }
        __builtin_amdgcn_s_setprio(0);
        float tm[4] = {-1e30f, -1e30f, -1e30f, -1e30f};
#pragma unroll
        for (int ni = 0; ni < 4; ni++)
#pragma unroll
            for (int j = 0; j < 4; j++) {
                float v = sa[ni][j] * 0.125f;
                int row = q0 + wid * 16 + lhi * 4 + j;
                int col = kv0 + ni * 16 + l16;
                if (col > row) v = -1e30f;
                sa[ni][j] = v;
                tm[j] = fmaxf(tm[j], v);
            }
#pragma unroll
        for (int j = 0; j < 4; j++) {
#pragma unroll
            for (int off = 1; off < 16; off <<= 1)
                tm[j] = fmaxf(tm[j], __shfl_xor(tm[j], off));
        }
        float al[4], rs[4] = {0.f, 0.f, 0.f, 0.f};
#pragma unroll
        for (int j = 0; j < 4; j++) {
            float mn = fmaxf(mj[j], tm[j]);
            al[j] = __expf(mj[j] - mn);
            mj[j] = mn;
        }
#pragma unroll
        for (int ni = 0; ni < 4; ni++)
#pragma unroll
            for (int j = 0; j < 4; j++) {
                float pv = __expf(sa[ni][j] - mj[j]);
                rs[j] += pv;
                Ps[wid * 1152 + (lhi * 4 + j) * 72 + ni * 16 + l16] = f2bf(pv);
            }
#pragma unroll
        for (int j = 0; j < 4; j++) {
#pragma unroll
            for (int off = 1; off < 16; off <<= 1)
                rs[j] += __shfl_xor(rs[j], off);
            lj[j] = lj[j] * al[j] + rs[j];
        }
#pragma unroll
        for (int di = 0; di < 4; di++)
#pragma unroll
            for (int j = 0; j < 4; j++) oa[di][j] *= al[j];
        __builtin_amdgcn_s_setprio(1);
#pragma unroll
        for (int di = 0; di < 4; di++) {
#pragma unroll
            for (int kc = 0; kc < 2; kc++) {
                u16x8 pf = *(const u16x8*)(&Ps[wid * 1152 + l16 * 72 + kc * 32 + lhi * 8]);
                u16x8 vf = *(const u16x8*)(&Vs[(di * 16 + l16) * 72 + kc * 32 + lhi * 8]);
                oa[di] = mfma32(pf, vf, oa[di]);
            }
        }
        __builtin_amdgcn_s_setprio(0);
    };

    const int ntB = 16 - p;   // kv tiles 0..15-p (covers both q-tiles)
    for (int kt = 0; kt < ntB; ++kt) {
        const int kv0 = kt * 64;
        __syncthreads();
        // K staging: vector writes, row-major
#pragma unroll
        for (int it = 0; it < 2; ++it) {
            int e = it * 256 + tid;
            int r = e >> 3, d0 = (e & 7) * 8;
            size_t goff = (rowbase + kv0 + r) * QKV_N + D_MODEL + h * HDIM + d0;
            u16x8 kk = *(const u16x8*)(qkv + goff);
            *(u16x8*)(&Ks[r * 72 + d0]) = kk;
        }
        // V staging: 128 threads x 4 rows -> transposed via register repack
        if (tid < 128) {
            int r0 = (tid & 15) * 4, d0v = (tid >> 4) * 8;
            const unsigned short* vp = qkv + (rowbase + kv0 + r0) * QKV_N
                                       + 2 * D_MODEL + h * HDIM + d0v;
            u16x8 w0 = *(const u16x8*)vp;
            u16x8 w1 = *(const u16x8*)(vp + QKV_N);
            u16x8 w2 = *(const u16x8*)(vp + 2 * QKV_N);
            u16x8 w3 = *(const u16x8*)(vp + 3 * QKV_N);
#pragma unroll
            for (int j = 0; j < 8; j++) {
                unsigned long long pk = (unsigned long long)w0[j]
                    | ((unsigned long long)w1[j] << 16)
                    | ((unsigned long long)w2[j] << 32)
                    | ((unsigned long long)w3[j] << 48);
                *(unsigned long long*)(&Vs[(d0v + j) * 72 + r0]) = pk;
            }
        }
        __syncthreads();

        if (kt <= p) update(qAf0, qAf1, oaA, mjA, ljA, qA0, kv0);  // block-uniform
        update(qBf0, qBf1, oaB, mjB, ljB, qB0, kv0);
    }

#pragma unroll
    for (int di = 0; di < 4; di++)
#pragma unroll
        for (int j = 0; j < 4; j++) {
            int rowA = qA0 + wid * 16 + lhi * 4 + j;
            ctxb[(rowbase + rowA) * D_MODEL + h * HDIM + di * 16 + l16] =
                f2bf(oaA[di][j] / ljA[j]);
            int rowB = qB0 + wid * 16 + lhi * 4 + j;
            ctxb[(rowbase + rowB) * D_MODEL + h * HDIM + di * 16 + l16] =
                f2bf(oaB[di][j] / ljB[j]);
        }
}

// ------- fused residual(xb + p0 + p1) + LayerNorm, bf16 in-place residual -------
__global__ __launch_bounds__(256) void ln3(
    unsigned short* __restrict__ xb, const unsigned short* __restrict__ p0,
    const unsigned short* __restrict__ p1,
    const float* __restrict__ sc, const float* __restrict__ bi)
{
    const int row = blockIdx.x;
    const int t = threadIdx.x;
    const size_t base = (size_t)row * D_MODEL + t * 4;
    ushort4 xu = *(const ushort4*)(xb + base);
    ushort4 au = *(const ushort4*)(p0 + base);
    ushort4 bu = *(const ushort4*)(p1 + base);
    float v0 = bf2f(xu.x) + bf2f(au.x) + bf2f(bu.x);
    float v1 = bf2f(xu.y) + bf2f(au.y) + bf2f(bu.y);
    float v2 = bf2f(xu.z) + bf2f(au.z) + bf2f(bu.z);
    float v3 = bf2f(xu.w) + bf2f(au.w) + bf2f(bu.w);
    float sum = v0 + v1 + v2 + v3;
    float sq  = v0 * v0 + v1 * v1 + v2 * v2 + v3 * v3;
#pragma unroll
    for (int off = 1; off < 64; off <<= 1) {
        sum += __shfl_xor(sum, off);
        sq  += __shfl_xor(sq, off);
    }
    __shared__ float red[8];
    int wid = t >> 6, lane = t & 63;
    if (lane == 0) { red[wid] = sum; red[4 + wid] = sq; }
    __syncthreads();
    sum = red[0] + red[1] + red[2] + red[3];
    sq  = red[4] + red[5] + red[6] + red[7];
    float mu   = sum * (1.f / D_MODEL);
    float var  = sq * (1.f / D_MODEL) - mu * mu;
    float rstd = rsqrtf(var + LN_EPS);
    int c = t * 4;
    float4 sv = *(const float4*)(sc + c);
    float4 bv = *(const float4*)(bi + c);
    float y0 = sv.x * (v0 - mu) * rstd + bv.x;
    float y1 = sv.y * (v1 - mu) * rstd + bv.y;
    float y2 = sv.z * (v2 - mu) * rstd + bv.z;
    float y3 = sv.w * (v3 - mu) * rstd + bv.w;
    unsigned long long pk = (unsigned long long)f2bf(y0)
        | ((unsigned long long)f2bf(y1) << 16)
        | ((unsigned long long)f2bf(y2) << 32)
        | ((unsigned long long)f2bf(y3) << 48);
    *(unsigned long long*)(xb + base) = pk;
}

// ---------------- launcher ----------------
extern "C" void kernel_launch(void* const* d_in, const int* in_sizes, int n_in,
                              void* d_out, int out_size, void* d_ws, size_t ws_size,
                              hipStream_t stream)
{
    (void)in_sizes; (void)n_in; (void)out_size;
    const int*   tokens = (const int*)d_in[0];
    const float* emb  = (const float*)d_in[2];
    const float* pose = (const float*)d_in[3];
    const float* Wq = (const float*)d_in[4];
    const float* bq = (const float*)d_in[5];
    const float* Wk = (const float*)d_in[6];
    const float* bk = (const float*)d_in[7];
    const float* Wv = (const float*)d_in[8];
    const float* bv = (const float*)d_in[9];
    const float* Wo = (const float*)d_in[10];
    const float* bo = (const float*)d_in[11];
    const float* n1s = (const float*)d_in[12];
    const float* n1b = (const float*)d_in[13];
    const float* W1 = (const float*)d_in[14];
    const float* b1 = (const float*)d_in[15];
    const float* W2 = (const float*)d_in[16];
    const float* b2 = (const float*)d_in[17];
    const float* n2s = (const float*)d_in[18];
    const float* n2b = (const float*)d_in[19];

    char* w = (char*)d_ws;
    size_t off = 0;
    auto carve = [&](size_t bytes) -> void* {
        void* p = w + off;
        off = (off + bytes + 255) & ~(size_t)255;
        return p;
    };
    unsigned short* tmp = (unsigned short*)carve((size_t)2 * ROWS * D_MODEL * 2);  // bf16 partials
    unsigned short* xb    = (unsigned short*)carve((size_t)ROWS * D_MODEL * 2);   // bf16 residual
    unsigned short* qkvb  = (unsigned short*)carve((size_t)ROWS * QKV_N * 2);
    unsigned short* cbuf  = (unsigned short*)carve((size_t)ROWS * D_MODEL * 2);
    unsigned short* hbuf  = (unsigned short*)carve((size_t)ROWS * FF_DIM * 2);
    size_t wt_off = off;
    unsigned short* wt = (unsigned short*)carve((size_t)12 * 1048576 * 2);  // fused: 24MB
    float* bqkv = (float*)carve((size_t)NLAYER * QKV_N * 4);
    unsigned short* embb = qkvb;   // tied-head emb aliases dead qkv/ctx/h region
    unsigned short* tmp1 = tmp + (size_t)ROWS * D_MODEL;
    const bool fused_t = (off <= ws_size);
    if (!fused_t) {
        off = wt_off;
        wt = (unsigned short*)carve((size_t)D_MODEL * FF_DIM * 2);
        bqkv = (float*)carve((size_t)NLAYER * QKV_N * 4);
        if (off > ws_size) return;
    }

    bias3_k<<<NLAYER * 3, 256, 0, stream>>>(bq, bk, bv, bqkv);
    embed_k<<<ROWS, 256, 0, stream>>>(tokens, emb, pose, xb);

    for (int l = 0; l < NLAYER; l++) {
        const float* Wq_l = Wq + (size_t)l * D_MODEL * D_MODEL;
        const float* Wk_l = Wk + (size_t)l * D_MODEL * D_MODEL;
        const float* Wv_l = Wv + (size_t)l * D_MODEL * D_MODEL;
        const float* Wo_l = Wo + (size_t)l * D_MODEL * D_MODEL;
        const float* W1_l = W1 + (size_t)l * D_MODEL * FF_DIM;
        const float* W2_l = W2 + (size_t)l * FF_DIM * D_MODEL;

        unsigned short* wtQKV = wt;
        unsigned short* wtWo  = fused_t ? wt + (size_t)3 * 1048576 : wt;
        unsigned short* wtW1  = fused_t ? wt + (size_t)4 * 1048576 : wt;
        unsigned short* wtW2  = fused_t ? wt + (size_t)8 * 1048576 : wt;

        if (fused_t) {
            transpose_all<<<3072, 256, 0, stream>>>(Wq_l, Wk_l, Wv_l, Wo_l, W1_l, W2_l, wt);
        } else {
            transpose_cast3<<<dim3(16, 16, 3), 256, 0, stream>>>(Wq_l, Wk_l, Wv_l, wtQKV);
        }
        gemm_bt<1><<<dim3(768, 1), 256, 0, stream>>>(xb, D_MODEL, wtQKV, D_MODEL,
                                                     bqkv + (size_t)l * QKV_N, qkvb, QKV_N, D_MODEL);

        attn_fwd<<<dim3(8, BATCH * NHEAD), 256, 0, stream>>>(qkvb, cbuf);

        if (!fused_t) transpose_cast<<<dim3(16, 16), 256, 0, stream>>>(Wo_l, wtWo, D_MODEL, D_MODEL);
        gemm_bt<1><<<dim3(256, 2), 256, 0, stream>>>(cbuf, D_MODEL, wtWo, D_MODEL,
                                                     bo + (size_t)l * D_MODEL, tmp, D_MODEL, D_MODEL / 2);
        ln3<<<ROWS, 256, 0, stream>>>(xb, tmp, tmp1, n1s + (size_t)l * D_MODEL, n1b + (size_t)l * D_MODEL);

        if (!fused_t) transpose_cast<<<dim3(64, 16), 256, 0, stream>>>(W1_l, wtW1, D_MODEL, FF_DIM);
        gemm256<2, 1><<<(FF_DIM / 256) * 16, 512, 0, stream>>>(xb, wtW1, b1 + (size_t)l * FF_DIM, hbuf, FF_DIM, D_MODEL);
        if (!fused_t) transpose_cast<<<dim3(16, 64), 256, 0, stream>>>(W2_l, wtW2, FF_DIM, D_MODEL);
        gemm_bt<1><<<dim3(256, 2), 256, 0, stream>>>(hbuf, FF_DIM, wtW2, FF_DIM,
                                                     b2 + (size_t)l * D_MODEL, tmp, D_MODEL, FF_DIM / 2);
        ln3<<<ROWS, 256, 0, stream>>>(xb, tmp, tmp1, n2s + (size_t)l * D_MODEL, n2b + (size_t)l * D_MODEL);
    }

    cast_bf<<<(VOCAB * D_MODEL) / 1024, 256, 0, stream>>>(emb, embb, (size_t)VOCAB * D_MODEL);
    // head: NO XCD swizzle — bm-fastest order shares B panels via L3
    gemm256<0, 0><<<(VOCAB / 256) * 16, 512, 0, stream>>>(xb, embb, nullptr, d_out, VOCAB, D_MODEL);
}